// Round 16
// baseline (722.619 us; speedup 1.0000x reference)
//
#include <hip/hip_runtime.h>
#include <hip/hip_bf16.h>
#include <math.h>

// Problem constants
constexpr int Bn = 4, Tn = 2048, Dn = 1024, Hn = 16, DKn = 48, DVn = 96, In = 3072;
constexpr int BT = Bn * Tn;               // 8192
constexpr int HDK = Hn * DKn;             // 768
constexpr int HDV = Hn * DVn;             // 1536
constexpr int QKVC = 2 * HDK + HDV;       // 3072
constexpr int CC = 64;                    // chunk length
constexpr int NC = Tn / CC;               // 32 chunks per (b,h)

using bf16 = __hip_bfloat16;
typedef __attribute__((ext_vector_type(8))) short bf16x8;
typedef __attribute__((ext_vector_type(4))) float f32x4;

// ---- Workspace layout (byte offsets) ----
constexpr size_t WO_HBF   = 0;              // h/h2 bf16 [8192][1024]     16 MB
constexpr size_t WO_QKVR  = 16777216;       // raw qkv 48MB; then A/B; then attn; then act
constexpr size_t WO_OSC   = 16777216;       // attn bf16 [8192][1536] (ends 41.9MB < St 45.1MB)
constexpr size_t WO_ACT   = 16777216;       // mlp act bf16 [8192][3072]
constexpr size_t WO_A     = 16777216;       // A bf16 [2048][48][48]  9.4 MB
constexpr size_t WO_B     = 26214400;       // B bf16 [2048][48][96]  18.9 MB (ends 45.1MB)
constexpr size_t WO_ST    = 45088768;       // St bf16 [2048][96][48] 18.9 MB (ends 64.0MB)
constexpr size_t WO_QKVC  = 67108864;       // conv'd qkv bf16 [8192][3072] 48 MB; later upb
constexpr size_t WO_GATE  = 117440512;      // gate bf16 [8192][1536]     24 MB
constexpr size_t WO_X1    = 142606336;      // x1 fp32 [8192][1024]       32 MB
constexpr size_t WO_BA    = 176160768;      // ba fp32 [8192][32]         1 MB
constexpr size_t WO_GC    = 177209344;      // Gc fp32 [64][2048]         0.5 MB
constexpr size_t WO_T     = 177733632;      // T bf16 [2048][64][64]      16.8 MB
constexpr size_t WO_UV    = 194510848;      // Uv bf16 [2048][64][96]     25.2 MB
constexpr size_t WO_WB    = 219676672;      // bf16 weights ~31.5 MB
// bf16-element offsets inside WB:
constexpr size_t WB_QKVT = 0;              // [3072][1024]  (+GT contiguous => [4608][1024])
constexpr size_t WB_GT   = 3145728;        // [1536][1024]
constexpr size_t WB_OT   = 4718592;        // [1024][1536]
constexpr size_t WB_GATET= 6291456;        // [3072][1024]  (+UPT contiguous => [6144][1024])
constexpr size_t WB_UPT  = 9437184;        // [3072][1024]
constexpr size_t WB_DOWNT= 12582912;       // [1024][3072]
constexpr size_t WB_ABT  = 15728640;       // [32][1024]

__device__ __forceinline__ float sigmoidf_(float x) { return 1.f / (1.f + __expf(-x)); }
__device__ __forceinline__ float siluf(float x) { return x * sigmoidf_(x); }

__device__ __forceinline__ void glds16(const void* g, void* l) {
  __builtin_amdgcn_global_load_lds((const __attribute__((address_space(1))) void*)g,
                                   (__attribute__((address_space(3))) void*)l, 16, 0, 0);
}

__device__ __forceinline__ f32x4 mfma16(bf16x8 a, bf16x8 b, f32x4 c) {
  return __builtin_amdgcn_mfma_f32_16x16x32_bf16(a, b, c, 0, 0, 0);
}

__device__ __forceinline__ bf16x8 scale8(bf16x8 a, float s) {
  bf16x8 r;
#pragma unroll
  for (int e = 0; e < 8; e++) {
    float f = __bfloat162float(__ushort_as_bfloat16((unsigned short)a[e])) * s;
    r[e] = (short)__bfloat16_as_ushort(__float2bfloat16(f));
  }
  return r;
}

__device__ __forceinline__ float b2f(short u) {
  return __bfloat162float(__ushort_as_bfloat16((unsigned short)u));
}
__device__ __forceinline__ short f2b(float f) {
  return (short)__bfloat16_as_ushort(__float2bfloat16(f));
}

// ---------------- merged transpose-cast: 10 weights in one launch ----------------
struct TcastArgs {
  const float* src[10];
  bf16* dst[10];
  int R[10], C[10], gxw[10], t0[10];
};

__global__ void tcast_all(TcastArgs a) {
  __shared__ float t[32][33];
  int bid = blockIdx.x;
  int i = 0;
#pragma unroll
  for (int k = 1; k < 10; k++) if (bid >= a.t0[k]) i = k;
  int lt = bid - a.t0[i];
  int gxw = a.gxw[i];
  int bx = lt % gxw, by = lt / gxw;
  const float* in = a.src[i];
  bf16* out = a.dst[i];
  int R = a.R[i], C = a.C[i];
  int tx = threadIdx.x, ty = threadIdx.y;
  int c0 = bx * 32, r0 = by * 32;
#pragma unroll
  for (int j = 0; j < 4; j++) {
    int r = ty + j * 8;
    float v = (c0 + tx < C) ? in[(size_t)(r0 + r) * C + c0 + tx] : 0.f;
    t[r][tx] = v;
  }
  __syncthreads();
#pragma unroll
  for (int j = 0; j < 4; j++) {
    int cc = ty + j * 8;
    if (c0 + cc < C) out[(size_t)(c0 + cc) * R + r0 + tx] = __float2bfloat16(t[tx][cc]);
  }
}

// ---------------- RMSNorm -> bf16 out ----------------
__global__ void rmsnorm_bf_k(const float* __restrict__ x, const float* __restrict__ w,
                             bf16* __restrict__ y) {
  int row = blockIdx.x;
  const float4* xr = (const float4*)(x + (size_t)row * Dn);
  int tid = threadIdx.x;
  float4 v = xr[tid];
  float ss = v.x * v.x + v.y * v.y + v.z * v.z + v.w * v.w;
  for (int m = 32; m >= 1; m >>= 1) ss += __shfl_xor(ss, m, 64);
  __shared__ float wsum[4];
  if ((tid & 63) == 0) wsum[tid >> 6] = ss;
  __syncthreads();
  ss = wsum[0] + wsum[1] + wsum[2] + wsum[3];
  float rs = rsqrtf(ss * (1.f / Dn) + 1e-5f);
  float4 wv = ((const float4*)w)[tid];
  bf16* yr = y + (size_t)row * Dn + tid * 4;
  yr[0] = __float2bfloat16(v.x * rs * wv.x);
  yr[1] = __float2bfloat16(v.y * rs * wv.y);
  yr[2] = __float2bfloat16(v.z * rs * wv.z);
  yr[3] = __float2bfloat16(v.w * rs * wv.w);
}

// ---------------- 256x256 8-wave MFMA GEMM, 4-buffer pipeline + reg-dbuf frags ----------------
// Per virtual tile v: {vmcnt(4); barrier; ds_read v+1 frags -> other regs; MFMA v; STAGE v+3}.
// mode 10: col<3072 -> C0 ld 3072 raw, else C1 ld 1536 raw.
// mode 11: col<3072 -> silu -> C0 ld 3072, else raw -> C1 ld 3072.
#define AS256(bi) (lds + (bi) * 8192)
#define BS256(bi) (lds + 32768 + (bi) * 8192)
#define STAGE256(bi, k0) do { \
    glds16(gA0 + (k0), AS256(bi) + w * 512); \
    glds16(gA1 + (k0), AS256(bi) + 4096 + w * 512); \
    glds16(gB0 + (k0), BS256(bi) + w * 512); \
    glds16(gB1 + (k0), BS256(bi) + 4096 + w * 512); \
  } while (0)
#define LOADFRAG256(dstA, dstB, bi) do { \
    _Pragma("unroll") \
    for (int m_ = 0; m_ < 8; m_++) \
      dstA[m_] = *(const bf16x8*)(AS256(bi) + (wr * 128 + m_ * 16 + l15) * 32 + slot * 8); \
    _Pragma("unroll") \
    for (int n_ = 0; n_ < 4; n_++) \
      dstB[n_] = *(const bf16x8*)(BS256(bi) + (wc * 64 + n_ * 16 + l15) * 32 + slot * 8); \
  } while (0)
#define MFMA256(srcA, srcB) do { \
    __builtin_amdgcn_s_setprio(1); \
    _Pragma("unroll") \
    for (int m_ = 0; m_ < 8; m_++) \
      _Pragma("unroll") \
      for (int n_ = 0; n_ < 4; n_++) \
        acc[m_][n_] = mfma16(srcA[m_], srcB[n_], acc[m_][n_]); \
    __builtin_amdgcn_s_setprio(0); \
  } while (0)

__global__ __launch_bounds__(512, 2) void gemm256(
    const bf16* __restrict__ A, const bf16* __restrict__ Bt,
    bf16* __restrict__ C0, bf16* __restrict__ C1,
    int gx, int N, int K, int mode) {
  __shared__ bf16 lds[65536];
  int nb = gx * 32;
  int q8 = nb >> 3;
  int bid = blockIdx.x;
  int sw = (bid & 7) * q8 + (bid >> 3);     // bijective XCD swizzle (nb%8==0)
  int by = sw & 31, bx = sw >> 5;           // M fastest within XCD -> B-panel L2 reuse
  int bm = by * 256, bn = bx * 256;
  int tid = threadIdx.x;
  int lane = tid & 63, w = tid >> 6;
  int l15 = lane & 15, lq = lane >> 4;
  int wr = w >> 2, wc = w & 3;
  int arow0 = tid >> 2;
  int srcq = (tid & 3) ^ ((arow0 >> 1) & 3);
  const bf16* gA0 = A + (size_t)(bm + arow0) * K + srcq * 8;
  const bf16* gA1 = A + (size_t)(bm + 128 + arow0) * K + srcq * 8;
  const bf16* gB0 = Bt + (size_t)(bn + arow0) * K + srcq * 8;
  const bf16* gB1 = Bt + (size_t)(bn + 128 + arow0) * K + srcq * 8;
  int slot = lq ^ ((l15 >> 1) & 3);         // frag-read swizzle (matches store)
  f32x4 acc[8][4];
#pragma unroll
  for (int m = 0; m < 8; m++)
#pragma unroll
    for (int n = 0; n < 4; n++) acc[m][n] = (f32x4){0.f, 0.f, 0.f, 0.f};
  int NT = K >> 5;
  STAGE256(0, 0);
  STAGE256(1, 32);
  STAGE256(2, 64);
  bf16x8 afA[8], bfA[4], afB[8], bfB[4];
  asm volatile("s_waitcnt vmcnt(8)" ::: "memory");
  __builtin_amdgcn_s_barrier();
  LOADFRAG256(afA, bfA, 0);
  for (int t = 0; t < NT; t += 2) {
    // ---- virtual tile v = t: compute regs A, prefetch tile t+1 into regs B ----
    if (t + 2 < NT) { asm volatile("s_waitcnt vmcnt(4)" ::: "memory"); }
    else            { asm volatile("s_waitcnt vmcnt(0)" ::: "memory"); }
    __builtin_amdgcn_s_barrier();
    if (t + 1 < NT) { int b1 = (t + 1) & 3; LOADFRAG256(afB, bfB, b1); }
    MFMA256(afA, bfA);
    if (t + 3 < NT) STAGE256((t + 3) & 3, (t + 3) * 32);
    // ---- virtual tile v = t+1: compute regs B, prefetch tile t+2 into regs A ----
    if (t + 1 < NT) {
      if (t + 3 < NT) { asm volatile("s_waitcnt vmcnt(4)" ::: "memory"); }
      else            { asm volatile("s_waitcnt vmcnt(0)" ::: "memory"); }
      __builtin_amdgcn_s_barrier();
      if (t + 2 < NT) { int b2 = (t + 2) & 3; LOADFRAG256(afA, bfA, b2); }
      MFMA256(afB, bfB);
      if (t + 4 < NT) STAGE256((t + 4) & 3, (t + 4) * 32);
    }
  }
  // ---- epilogue: LDS-coalesced C write ----
  __syncthreads();   // all K-loop LDS reads complete before overwrite
  bf16* dst; int ldc, bnl; bool doSilu;
  if (mode == 10) {
    if (bn < 3072) { dst = C0; ldc = 3072; bnl = bn; doSilu = false; }
    else           { dst = C1; ldc = 1536; bnl = bn - 3072; doSilu = false; }
  } else {  // mode 11
    if (bn < 3072) { dst = C0; ldc = 3072; bnl = bn; doSilu = true; }
    else           { dst = C1; ldc = 3072; bnl = bn - 3072; doSilu = false; }
  }
  bf16* cw = lds + w * 8192;   // per-wave 128x64 region
#pragma unroll
  for (int m = 0; m < 8; m++)
#pragma unroll
    for (int n = 0; n < 4; n++)
#pragma unroll
      for (int i = 0; i < 4; i++) {
        int row_l = m * 16 + lq * 4 + i;
        int col_l = n * 16 + l15;
        float v = acc[m][n][i];
        if (doSilu) v = siluf(v);
        cw[row_l * 64 + col_l] = __float2bfloat16(v);
      }
  __syncthreads();
  int r8 = lane >> 3, c8 = (lane & 7) * 8;
#pragma unroll
  for (int it = 0; it < 16; it++) {   // full 128x64 per wave
    int row_l = it * 8 + r8;
    bf16x8 val = *(const bf16x8*)&cw[row_l * 64 + c8];
    *(bf16x8*)&dst[(size_t)(bm + wr * 128 + row_l) * ldc + bnl + wc * 64 + c8] = val;
  }
}

// ---------------- 128x128 MFMA GEMM, 4-buffer pipeline + reg-dbuf frags ----------------
// mode 0: fp32 out (+res). mode 3: bf16 acc. K/32 >= 3 required (K>=96), NT even.
#define STAGE128(bi, k0) do { \
    { int c0_ = 2 * w4; \
      int arow_ = bm + c0_ * 16 + srow; \
      glds16(A + (size_t)arow_ * K + (k0) + gq * 8, &As[bi][c0_ * 512]); \
      int brow_ = bn + c0_ * 16 + srow; if (brow_ >= N) brow_ = 0; \
      glds16(Bt + (size_t)brow_ * K + (k0) + gq * 8, &Bs[bi][c0_ * 512]); \
      int c1_ = c0_ + 1; \
      int arow2_ = bm + c1_ * 16 + srow; \
      glds16(A + (size_t)arow2_ * K + (k0) + gq * 8, &As[bi][c1_ * 512]); \
      int brow2_ = bn + c1_ * 16 + srow; if (brow2_ >= N) brow2_ = 0; \
      glds16(Bt + (size_t)brow2_ * K + (k0) + gq * 8, &Bs[bi][c1_ * 512]); \
    } \
  } while (0)
#define LOADFRAG128(dstA, dstB, bi) do { \
    _Pragma("unroll") \
    for (int m_ = 0; m_ < 4; m_++) \
      dstA[m_] = *(const bf16x8*)&As[bi][(arow_base + m_ * 16) * 32 + qa * 8]; \
    _Pragma("unroll") \
    for (int n_ = 0; n_ < 4; n_++) \
      dstB[n_] = *(const bf16x8*)&Bs[bi][(brow_base + n_ * 16) * 32 + qa * 8]; \
  } while (0)
#define MFMA128(srcA, srcB) do { \
    __builtin_amdgcn_s_setprio(1); \
    _Pragma("unroll") \
    for (int m_ = 0; m_ < 4; m_++) \
      _Pragma("unroll") \
      for (int n_ = 0; n_ < 4; n_++) \
        acc[m_][n_] = mfma16(srcA[m_], srcB[n_], acc[m_][n_]); \
    __builtin_amdgcn_s_setprio(0); \
  } while (0)

__global__ __launch_bounds__(256) void gemm_mfma(
    const bf16* __restrict__ A, const bf16* __restrict__ Bt,
    void* __restrict__ Cv, const float* __restrict__ res,
    int N, int K, int ldc, int mode) {
  __shared__ bf16 As[4][4096];
  __shared__ bf16 Bs[4][4096];
  int tid = threadIdx.x, lane = tid & 63, w4 = tid >> 6;
  int bm = blockIdx.y * 128, bn = blockIdx.x * 128;
  int wr = w4 >> 1, wc = w4 & 1;
  int srow = lane >> 2;
  int gq = (lane & 3) ^ ((lane >> 3) & 3);
  int qa = (lane >> 4) ^ ((lane >> 1) & 3);
  int arow_base = wr * 64 + (lane & 15);
  int brow_base = wc * 64 + (lane & 15);
  f32x4 acc[4][4];
#pragma unroll
  for (int m = 0; m < 4; m++)
#pragma unroll
    for (int n = 0; n < 4; n++) acc[m][n] = (f32x4){0.f, 0.f, 0.f, 0.f};
  int NT = K >> 5;
  STAGE128(0, 0);
  STAGE128(1, 32);
  STAGE128(2, 64);
  bf16x8 afA[4], bfA[4], afB[4], bfB[4];
  asm volatile("s_waitcnt vmcnt(8)" ::: "memory");
  __builtin_amdgcn_s_barrier();
  LOADFRAG128(afA, bfA, 0);
  for (int t = 0; t < NT; t += 2) {
    if (t + 2 < NT) { asm volatile("s_waitcnt vmcnt(4)" ::: "memory"); }
    else            { asm volatile("s_waitcnt vmcnt(0)" ::: "memory"); }
    __builtin_amdgcn_s_barrier();
    if (t + 1 < NT) { int b1 = (t + 1) & 3; LOADFRAG128(afB, bfB, b1); }
    MFMA128(afA, bfA);
    if (t + 3 < NT) STAGE128((t + 3) & 3, (t + 3) * 32);
    if (t + 1 < NT) {
      if (t + 3 < NT) { asm volatile("s_waitcnt vmcnt(4)" ::: "memory"); }
      else            { asm volatile("s_waitcnt vmcnt(0)" ::: "memory"); }
      __builtin_amdgcn_s_barrier();
      if (t + 2 < NT) { int b2 = (t + 2) & 3; LOADFRAG128(afA, bfA, b2); }
      MFMA128(afB, bfB);
      if (t + 4 < NT) STAGE128((t + 4) & 3, (t + 4) * 32);
    }
  }
#pragma unroll
  for (int m = 0; m < 4; m++) {
#pragma unroll
    for (int n = 0; n < 4; n++) {
      int col = bn + wc * 64 + n * 16 + (lane & 15);
      if (col >= N) continue;
#pragma unroll
      for (int i = 0; i < 4; i++) {
        int row = bm + wr * 64 + m * 16 + (lane >> 4) * 4 + i;
        float v = acc[m][n][i];
        size_t idx = (size_t)row * ldc + col;
        if (mode == 0) {
          if (res) v += res[idx];
          ((float*)Cv)[idx] = v;
        } else {
          ((bf16*)Cv)[idx] = __float2bfloat16(v);
        }
      }
    }
  }
}

// ---------------- Parallel causal conv (K=4) + silu ----------------
__global__ __launch_bounds__(256) void convsilu2_k(const bf16* __restrict__ in,
                                                   bf16* __restrict__ outp,
                                                   const float* __restrict__ wq,
                                                   const float* __restrict__ wk,
                                                   const float* __restrict__ wv) {
  int tx = threadIdx.x & 31;
  int ty = threadIdx.x >> 5;
  int c = (blockIdx.x * 32 + tx) * 8;
  int gt = blockIdx.y * 8 + ty;
  int b = gt >> 11, t = gt & (Tn - 1);
  const float* wsrc = (c < HDK) ? (wq + c * 4)
                     : (c < 2 * HDK) ? (wk + (c - HDK) * 4)
                                     : (wv + (c - 2 * HDK) * 4);
  float4 W[8];
#pragma unroll
  for (int j = 0; j < 8; j++) W[j] = ((const float4*)wsrc)[j];
  const bf16* base = in + (size_t)b * Tn * QKVC + c;
  bf16x8 r[4];
  bf16x8 zero = {0, 0, 0, 0, 0, 0, 0, 0};
#pragma unroll
  for (int j = 0; j < 4; j++) {
    int tt = t - 3 + j;
    r[j] = (tt >= 0) ? *(const bf16x8*)(base + (size_t)tt * QKVC) : zero;
  }
  bf16x8 o;
#pragma unroll
  for (int ch = 0; ch < 8; ch++) {
    float x0 = b2f(r[0][ch]), x1 = b2f(r[1][ch]), x2 = b2f(r[2][ch]), x3 = b2f(r[3][ch]);
    float y = x0 * W[ch].x + x1 * W[ch].y + x2 * W[ch].z + x3 * W[ch].w;
    o[ch] = f2b(siluf(y));
  }
  *(bf16x8*)(outp + (size_t)gt * QKVC + c) = o;
}

// ---------------- l2norm: thread-per-48-elem head row, vectorized ----------------
__global__ __launch_bounds__(256) void l2norm_k(bf16* __restrict__ qkv) {
  int row = blockIdx.x * 256 + threadIdx.x;   // 0 .. BT*32-1
  int t = row >> 5, hr = row & 31;
  bf16* p = qkv + (size_t)t * QKVC + hr * DKn;
  bf16x8 v[6];
  float ss = 0.f;
#pragma unroll
  for (int j = 0; j < 6; j++) {
    v[j] = *(const bf16x8*)(p + j * 8);
#pragma unroll
    for (int e = 0; e < 8; e++) { float f = b2f(v[j][e]); ss += f * f; }
  }
  float rs = rsqrtf(ss + 1e-6f);
#pragma unroll
  for (int j = 0; j < 6; j++) {
    bf16x8 o;
#pragma unroll
    for (int e = 0; e < 8; e++) o[e] = f2b(b2f(v[j][e]) * rs);
    *(bf16x8*)(p + j * 8) = o;
  }
}

// ---------------- beta/g transform ----------------
__global__ void betag_k(float* __restrict__ ba, const float* __restrict__ A_log,
                        const float* __restrict__ dt_bias) {
  int i = blockIdx.x * blockDim.x + threadIdx.x;
  int h = i & 15, r = i >> 4;
  float bv = ba[(size_t)r * 32 + h];
  float av = ba[(size_t)r * 32 + 16 + h];
  ba[(size_t)r * 32 + h] = sigmoidf_(bv);
  float xx = av + dt_bias[h];
  float sp = (xx > 20.f) ? xx : log1pf(__expf(xx));
  ba[(size_t)r * 32 + 16 + h] = -__expf(A_log[h]) * sp;
}

// ---------------- Fused P1+P2a: WY precompute + affine coefficients ----------------
__global__ __launch_bounds__(256) void dn_p1a(const bf16* __restrict__ qkv,
                                              const float* __restrict__ ba,
                                              float* __restrict__ Gc_g,
                                              bf16* __restrict__ T_g,
                                              bf16* __restrict__ Uv_g,
                                              bf16* __restrict__ A_g,
                                              bf16* __restrict__ B_g) {
  __shared__ __align__(16) char smem[62976];
  bf16 (*Kl)[72]   = (bf16(*)[72])(smem);                 //  9216 B
  bf16 (*Tl)[72]   = (bf16(*)[72])(smem + 9216);          //  9216 B
  bf16 (*UvdT)[72] = (bf16(*)[72])(smem + 18432);         // 13824 B
  float* Gcl = (float*)(smem + 32256);
  float* Bl  = (float*)(smem + 32512);
  bf16 (*Vl)[100]  = (bf16(*)[100])(smem + 32768);
  float (*Nl)[68]  = (float(*)[68])(smem + 45568);
  bf16 (*KTl)[72]  = (bf16(*)[72])(smem + 32768);
  bf16 (*KTbl)[72] = (bf16(*)[72])(smem + 39680);
  bf16 (*M2T)[72]  = (bf16(*)[72])(smem + 46592);
  int cid = blockIdx.x;
  int nc = cid & (NC - 1);
  int bh = cid >> 5;
  int h = bh & 15, b = bh >> 4;
  int t0 = nc * CC;
  int tid = threadIdx.x, lane = tid & 63, w = tid >> 6;
  int l15 = lane & 15, qd = lane >> 4;
  bf16 zb = __float2bfloat16(0.f);
  {
    int t = tid >> 2, p = tid & 3;
    const bf16* row = qkv + ((size_t)(b * Tn + t0 + t)) * QKVC;
    int c0 = p * 12;
#pragma unroll
    for (int j = 0; j < 12; ++j) Kl[t][c0 + j] = row[HDK + h * DKn + c0 + j];
    int j0 = p * 24;
#pragma unroll
    for (int j = 0; j < 24; ++j) Vl[t][j0 + j] = row[2 * HDK + h * DVn + j0 + j];
  }
  for (int i = tid; i < 64 * 24; i += 256) {
    int t = i / 24, c = 48 + (i % 24);
    Kl[t][c] = zb;
  }
  if (tid < 64) {
    size_t row = (size_t)(b * Tn + t0 + tid);
    float g = ba[row * 32 + 16 + h];
    float be = ba[row * 32 + h];
    float acc = g;
#pragma unroll
    for (int d = 1; d < 64; d <<= 1) {
      float o = __shfl_up(acc, d);
      if (tid >= d) acc += o;
    }
    Gcl[tid] = acc; Bl[tid] = be;
    Gc_g[(size_t)bh * Tn + t0 + tid] = acc;
  }
  __syncthreads();
  f32x4 dacc[4];
#pragma unroll
  for (int n = 0; n < 4; n++) dacc[n] = (f32x4){0.f, 0.f, 0.f, 0.f};
  {
    int arow = w * 16 + l15;
    bf16x8 a0 = *(const bf16x8*)&Kl[arow][qd * 8];
    bf16x8 a1 = *(const bf16x8*)&Kl[arow][32 + qd * 8];
#pragma unroll
    for (int n = 0; n < 4; n++) {
      int brow = n * 16 + l15;
      bf16x8 b0 = *(const bf16x8*)&Kl[brow][qd * 8];
      bf16x8 b1 = *(const bf16x8*)&Kl[brow][32 + qd * 8];
      dacc[n] = mfma16(a0, b0, dacc[n]);
      dacc[n] = mfma16(a1, b1, dacc[n]);
    }
  }
#pragma unroll
  for (int i = 0; i < 4; i++) {
    int t = w * 16 + qd * 4 + i;
    float bt = Bl[t], gt = Gcl[t];
#pragma unroll
    for (int n = 0; n < 4; n++) {
      int s = n * 16 + l15;
      Nl[t][s] = (s < t) ? bt * __expf(gt - Gcl[s]) * dacc[n][i] : 0.f;
    }
  }
  __syncthreads();
  float g63 = Gcl[63];
  int c = tid;
  if (c < 160) {
    float R[64];
    if (c < 64) {
#pragma unroll
      for (int t = 0; t < 64; ++t) R[t] = (t == c) ? 1.f : 0.f;
    } else {
      int j = c - 64;
#pragma unroll
      for (int t = 0; t < 64; ++t) R[t] = Bl[t] * __bfloat162float(Vl[t][j]);
    }
#pragma unroll
    for (int t = 1; t < 64; ++t) {
      float a0 = 0.f, a1 = 0.f, a2 = 0.f, a3 = 0.f;
#pragma unroll
      for (int s = 0; s + 3 < t; s += 4) {
        float4 n4 = *(const float4*)&Nl[t][s];
        a0 += n4.x * R[s]; a1 += n4.y * R[s + 1];
        a2 += n4.z * R[s + 2]; a3 += n4.w * R[s + 3];
      }
#pragma unroll
      for (int s = t & ~3; s < t; ++s) a0 += Nl[t][s] * R[s];
      R[t] -= ((a0 + a1) + (a2 + a3));
    }
    if (c < 64) {
#pragma unroll
      for (int t = 0; t < 64; ++t) {
        bf16 v = __float2bfloat16(R[t]);
        T_g[(size_t)cid * 4096 + t * 64 + c] = v;
        Tl[t][c] = v;
      }
    } else {
      int j = c - 64;
#pragma unroll
      for (int t = 0; t < 64; ++t) {
        Uv_g[(size_t)cid * 6144 + t * 96 + j] = __float2bfloat16(R[t]);
        UvdT[j][t] = __float2bfloat16(R[t] * __expf(g63 - Gcl[t]));
      }
    }
  }
  __syncthreads();
  for (int i = tid; i < 48 * 64; i += 256) {
    int dk = i >> 6, t = i & 63;
    bf16 kv = Kl[t][dk];
    KTl[dk][t] = kv;
    float bl = Bl[t] * __expf(Gcl[t]);
    KTbl[dk][t] = __float2bfloat16(__bfloat162float(kv) * bl);
  }
  __syncthreads();
  f32x4 m1[3];
#pragma unroll
  for (int n = 0; n < 3; n++) m1[n] = (f32x4){0.f, 0.f, 0.f, 0.f};
  {
    int arow = w * 16 + l15;
    bf16x8 a0 = *(const bf16x8*)&Tl[arow][qd * 8];
    bf16x8 a1 = *(const bf16x8*)&Tl[arow][32 + qd * 8];
#pragma unroll
    for (int n = 0; n < 3; n++) {
      int brow = n * 16 + l15;
      bf16x8 b0 = *(const bf16x8*)&KTbl[brow][qd * 8];
      bf16x8 b1 = *(const bf16x8*)&KTbl[brow][32 + qd * 8];
      m1[n] = mfma16(a0, b0, m1[n]);
      m1[n] = mfma16(a1, b1, m1[n]);
    }
  }
#pragma unroll
  for (int i = 0; i < 4; i++) {
    int tt = w * 16 + qd * 4 + i;
    float dd = __expf(g63 - Gcl[tt]);
#pragma unroll
    for (int n = 0; n < 3; n++) {
      int dk = n * 16 + l15;
      M2T[dk][tt] = __float2bfloat16(m1[n][i] * dd);
    }
  }
  __syncthreads();
  float lamC = __expf(g63);
#pragma unroll
  for (int tswap = 0; tswap < 7; tswap++) {
    int t = w + 4 * tswap;
    if (t >= 27) break;
    int mi, ni; bool isA;
    if (t < 9) { isA = true; mi = t / 3; ni = t % 3; }
    else { isA = false; mi = (t - 9) / 6; ni = (t - 9) % 6; }
    f32x4 acc = (f32x4){0.f, 0.f, 0.f, 0.f};
    int arow = mi * 16 + l15;
    bf16x8 a0 = *(const bf16x8*)&KTl[arow][qd * 8];
    bf16x8 a1 = *(const bf16x8*)&KTl[arow][32 + qd * 8];
    int brow = ni * 16 + l15;
    if (isA) {
      bf16x8 b0 = *(const bf16x8*)&M2T[brow][qd * 8];
      bf16x8 b1 = *(const bf16x8*)&M2T[brow][32 + qd * 8];
      acc = mfma16(a0, b0, acc);
      acc = mfma16(a1, b1, acc);
#pragma unroll
      for (int i = 0; i < 4; i++) {
        int row = mi * 16 + qd * 4 + i, colv = ni * 16 + l15;
        float v = ((row == colv) ? lamC : 0.f) - acc[i];
        A_g[(size_t)cid * 2304 + row * 48 + colv] = __float2bfloat16(v);
      }
    } else {
      bf16x8 b0 = *(const bf16x8*)&UvdT[brow][qd * 8];
      bf16x8 b1 = *(const bf16x8*)&UvdT[brow][32 + qd * 8];
      acc = mfma16(a0, b0, acc);
      acc = mfma16(a1, b1, acc);
#pragma unroll
      for (int i = 0; i < 4; i++) {
        int row = mi * 16 + qd * 4 + i, colv = ni * 16 + l15;
        B_g[(size_t)cid * 4608 + row * 96 + colv] = __float2bfloat16(acc[i]);
      }
    }
  }
}

// ---------------- P2b: pipelined serial affine scan S' = A S + B ----------------
__global__ __launch_bounds__(256) void dn_p2b(const bf16* __restrict__ A_g,
                                              const bf16* __restrict__ B_g,
                                              bf16* __restrict__ St_g) {
  __shared__ bf16 STl[2][96][72];
  __shared__ bf16 Al[2][48][72];
  __shared__ bf16 Bl[2][4608];
  int bh = blockIdx.x;
  int tid = threadIdx.x, lane = tid & 63, w = tid >> 6;
  int l15 = lane & 15, qd = lane >> 4;
  bf16 zb = __float2bfloat16(0.f);
  for (int i = tid; i < 2 * 96 * 72; i += 256) (&STl[0][0][0])[i] = zb;
  for (int i = tid; i < 2 * 48 * 24; i += 256) {
    int buf = i / (48 * 24), r = (i / 24) % 48, cc = 48 + (i % 24);
    Al[buf][r][cc] = zb;
  }
  bf16x8 ra0, ra1, rb0, rb1;
  unsigned int rb2;
  int e_a0 = tid * 8, e_a1 = 2048 + tid * 8;
  {
    size_t cid = (size_t)bh * NC;
    ra0 = *(const bf16x8*)(A_g + cid * 2304 + e_a0);
    if (tid < 32) ra1 = *(const bf16x8*)(A_g + cid * 2304 + e_a1);
    rb0 = *(const bf16x8*)(B_g + cid * 4608 + tid * 16);
    rb1 = *(const bf16x8*)(B_g + cid * 4608 + tid * 16 + 8);
    rb2 = *(const unsigned int*)(B_g + cid * 4608 + 4096 + tid * 2);
  }
  *(bf16x8*)&Al[0][e_a0 / 48][e_a0 % 48] = ra0;
  if (tid < 32) *(bf16x8*)&Al[0][e_a1 / 48][e_a1 % 48] = ra1;
  *(bf16x8*)&Bl[0][tid * 16] = rb0;
  *(bf16x8*)&Bl[0][tid * 16 + 8] = rb1;
  *(unsigned int*)&Bl[0][4096 + tid * 2] = rb2;
  {
    size_t cid = (size_t)bh * NC + 1;
    ra0 = *(const bf16x8*)(A_g + cid * 2304 + e_a0);
    if (tid < 32) ra1 = *(const bf16x8*)(A_g + cid * 2304 + e_a1);
    rb0 = *(const bf16x8*)(B_g + cid * 4608 + tid * 16);
    rb1 = *(const bf16x8*)(B_g + cid * 4608 + tid * 16 + 8);
    rb2 = *(const unsigned int*)(B_g + cid * 4608 + 4096 + tid * 2);
  }
  __syncthreads();

  for (int c = 0; c < NC - 1; ++c) {
    int cur = c & 1, nxt = cur ^ 1;
    size_t cid = (size_t)bh * NC + c;
    {
      int e0 = tid * 8, e1 = 2048 + tid * 8, e2 = 4096 + tid * 2;
      *(bf16x8*)(St_g + cid * 4608 + e0) = *(const bf16x8*)&STl[cur][e0 / 48][e0 % 48];
      *(bf16x8*)(St_g + cid * 4608 + e1) = *(const bf16x8*)&STl[cur][e1 / 48][e1 % 48];
      *(unsigned int*)(St_g + cid * 4608 + e2) = *(const unsigned int*)&STl[cur][e2 / 48][e2 % 48];
    }
    float vals[5][4];
#pragma unroll
    for (int ts = 0; ts < 5; ts++) {
      int t = w + 4 * ts;
      if (t >= 18) break;
      int mi = t / 3, ni = t % 3;
      f32x4 acc = (f32x4){0.f, 0.f, 0.f, 0.f};
      int arow = mi * 16 + l15;
      bf16x8 a0 = *(const bf16x8*)&STl[cur][arow][qd * 8];
      bf16x8 a1 = *(const bf16x8*)&STl[cur][arow][32 + qd * 8];
      int brow = ni * 16 + l15;
      bf16x8 b0 = *(const bf16x8*)&Al[cur][brow][qd * 8];
      bf16x8 b1 = *(const bf16x8*)&Al[cur][brow][32 + qd * 8];
      acc = mfma16(a0, b0, acc);
      acc = mfma16(a1, b1, acc);
#pragma unroll
      for (int i = 0; i < 4; i++) {
        int dv = mi * 16 + qd * 4 + i, ii = ni * 16 + l15;
        vals[ts][i] = acc[i] + __bfloat162float(Bl[cur][ii * 96 + dv]);
      }
    }
#pragma unroll
    for (int ts = 0; ts < 5; ts++) {
      int t = w + 4 * ts;
      if (t >= 18) break;
      int mi = t / 3, ni = t % 3;
#pragma unroll
      for (int i = 0; i < 4; i++) {
        int dv = mi * 16 + qd * 4 + i, ii = ni * 16 + l15;
        STl[nxt][dv][ii] = __float2bfloat16(vals[ts][i]);
      }
    }
    if (c + 1 <= NC - 2) {
      *(bf16x8*)&Al[nxt][e_a0 / 48][e_a0 % 48] = ra0;
      if (tid < 32) *(bf16x8*)&Al[nxt][e_a1 / 48][e_a1 % 48] = ra1;
      *(bf16x8*)&Bl[nxt][tid * 16] = rb0;
      *(bf16x8*)&Bl[nxt][tid * 16 + 8] = rb1;
      *(unsigned int*)&Bl[nxt][4096 + tid * 2] = rb2;
      if (c + 2 <= NC - 2) {
        size_t cid2 = (size_t)bh * NC + c + 2;
        ra0 = *(const bf16x8*)(A_g + cid2 * 2304 + e_a0);
        if (tid < 32) ra1 = *(const bf16x8*)(A_g + cid2 * 2304 + e_a1);
        rb0 = *(const bf16x8*)(B_g + cid2 * 4608 + tid * 16);
        rb1 = *(const bf16x8*)(B_g + cid2 * 4608 + tid * 16 + 8);
        rb2 = *(const unsigned int*)(B_g + cid2 * 4608 + 4096 + tid * 2);
      }
    }
    __syncthreads();
  }
  {
    size_t cid = (size_t)bh * NC + (NC - 1);
    int cur = (NC - 1) & 1;
    int e0 = tid * 8, e1 = 2048 + tid * 8, e2 = 4096 + tid * 2;
    *(bf16x8*)(St_g + cid * 4608 + e0) = *(const bf16x8*)&STl[cur][e0 / 48][e0 % 48];
    *(bf16x8*)(St_g + cid * 4608 + e1) = *(const bf16x8*)&STl[cur][e1 / 48][e1 % 48];
    *(unsigned int*)(St_g + cid * 4608 + e2) = *(const unsigned int*)&STl[cur][e2 / 48][e2 % 48];
  }
}

// ---------------- P2c: per-chunk output + fused gated RMSNorm ----------------
__global__ __launch_bounds__(256) void dn_p2c(const bf16* __restrict__ qkv,
                                              const float* __restrict__ ba,
                                              const float* __restrict__ Gc_g,
                                              const bf16* __restrict__ T_g,
                                              const bf16* __restrict__ Uv_g,
                                              const bf16* __restrict__ St_g,
                                              const bf16* __restrict__ gate,
                                              const float* __restrict__ onw,
                                              bf16* __restrict__ attn) {
  __shared__ bf16 Kl[64][72], Ql[64][72], Tl[64][72], Ml[64][72];
  __shared__ bf16 G1T[96][72], UT[96][72], STb[96][72];
  __shared__ float Gcl[64], Bl[64];
  __shared__ float onwl[96];
  int cid = blockIdx.x;
  int nc = cid & (NC - 1);
  int bh = cid >> 5;
  int h = bh & 15, b = bh >> 4;
  int t0 = nc * CC;
  int tid = threadIdx.x, lane = tid & 63, w = tid >> 6;
  int l15 = lane & 15, qd = lane >> 4;
  const float scale = 0.14433756729740643f;  // 48^-0.5
  bf16 zb = __float2bfloat16(0.f);
  {
    int t = tid >> 2, p = tid & 3;
    size_t grow = (size_t)(b * Tn + t0 + t);
    const bf16* row = qkv + grow * QKVC;
    int c0 = p * 12;
#pragma unroll
    for (int j = 0; j < 12; ++j) {
      int cc = c0 + j;
      Kl[t][cc] = row[HDK + h * DKn + cc];
      Ql[t][cc] = __float2bfloat16(__bfloat162float(row[h * DKn + cc]) * scale);
    }
    if (p == 0) { Gcl[t] = Gc_g[(size_t)bh * Tn + t0 + t]; Bl[t] = ba[grow * 32 + h]; }
  }
  if (tid < 96) onwl[tid] = onw[tid];
  for (int i = tid; i < 64 * 16; i += 256) {
    int t = i >> 4, cc = 48 + (i & 15);
    Kl[t][cc] = zb; Ql[t][cc] = zb;
  }
  for (int i = tid; i < 4096; i += 256)
    (&Tl[0][0])[(i >> 6) * 72 + (i & 63)] = T_g[(size_t)cid * 4096 + i];
  for (int i = tid; i < 4608; i += 256)
    STb[i / 48][i % 48] = St_g[(size_t)cid * 4608 + i];
  for (int i = tid; i < 96 * 16; i += 256)
    STb[i >> 4][48 + (i & 15)] = zb;
  __syncthreads();  // sync1
  f32x4 acc[6];
#pragma unroll
  for (int n = 0; n < 6; n++) acc[n] = (f32x4){0.f, 0.f, 0.f, 0.f};
  {
    int arow = w * 16 + l15;
    bf16x8 a0 = *(const bf16x8*)&Kl[arow][qd * 8];
    bf16x8 a1 = *(const bf16x8*)&Kl[arow][32 + qd * 8];
#pragma unroll
    for (int n = 0; n < 6; n++) {
      int brow = n * 16 + l15;
      bf16x8 b0 = *(const bf16x8*)&STb[brow][qd * 8];
      bf16x8 b1 = *(const bf16x8*)&STb[brow][32 + qd * 8];
      acc[n] = mfma16(a0, b0, acc[n]);
      acc[n] = mfma16(a1, b1, acc[n]);
    }
  }
#pragma unroll
  for (int i = 0; i < 4; i++) {
    int tt = w * 16 + qd * 4 + i;
    float sc = Bl[tt] * __expf(Gcl[tt]);
#pragma unroll
    for (int n = 0; n < 6; n++)
      G1T[n * 16 + l15][tt] = __float2bfloat16(acc[n][i] * sc);
  }
  __syncthreads();  // sync2
#pragma unroll
  for (int n = 0; n < 6; n++) acc[n] = (f32x4){0.f, 0.f, 0.f, 0.f};
  {
    int arow = w * 16 + l15;
    bf16x8 a0 = *(const bf16x8*)&Tl[arow][qd * 8];
    bf16x8 a1 = *(const bf16x8*)&Tl[arow][32 + qd * 8];
#pragma unroll
    for (int n = 0; n < 6; n++) {
      int brow = n * 16 + l15;
      bf16x8 b0 = *(const bf16x8*)&G1T[brow][qd * 8];
      bf16x8 b1 = *(const bf16x8*)&G1T[brow][32 + qd * 8];
      acc[n] = mfma16(a0, b0, acc[n]);
      acc[n] = mfma16(a1, b1, acc[n]);
    }
  }
#pragma unroll
  for (int i = 0; i < 4; i++) {
    int tt = w * 16 + qd * 4 + i;
#pragma unroll
    for (int n = 0; n < 6; n++) {
      int dv = n * 16 + l15;
      float uv = __bfloat162float(Uv_g[(size_t)cid * 6144 + tt * 96 + dv]);
      UT[dv][tt] = __float2bfloat16(uv - acc[n][i]);
    }
  }
  f32x4 qk[4];
#pragma unroll
  for (int n = 0; n < 4; n++) qk[n] = (f32x4){0.f, 0.f, 0.f, 0.f};
  {
    int arow = w * 16 + l15;
    bf16x8 a0 = *(const bf16x8*)&Ql[arow][qd * 8];
    bf16x8 a1 = *(const bf16x8*)&Ql[arow][32 + qd * 8];
#pragma unroll
    for (int n = 0; n < 4; n++) {
      int brow = n * 16 + l15;
      bf16x8 b0 = *(const bf16x8*)&Kl[brow][qd * 8];
      bf16x8 b1 = *(const bf16x8*)&Kl[brow][32 + qd * 8];
      qk[n] = mfma16(a0, b0, qk[n]);
      qk[n] = mfma16(a1, b1, qk[n]);
    }
  }
#pragma unroll
  for (int i = 0; i < 4; i++) {
    int tt = w * 16 + qd * 4 + i;
    float gt = Gcl[tt];
#pragma unroll
    for (int n = 0; n < 4; n++) {
      int ss = n * 16 + l15;
      float m = (ss <= tt) ? qk[n][i] * __expf(gt - Gcl[ss]) : 0.f;
      Ml[tt][ss] = __float2bfloat16(m);
    }
  }
  __syncthreads();  // sync3
#pragma unroll
  for (int n = 0; n < 6; n++) acc[n] = (f32x4){0.f, 0.f, 0.f, 0.f};
  {
    int arow = w * 16 + l15;
    float lam = __expf(Gcl[arow]);
    bf16x8 a0 = scale8(*(const bf16x8*)&Ql[arow][qd * 8], lam);
    bf16x8 a1 = scale8(*(const bf16x8*)&Ql[arow][32 + qd * 8], lam);
    bf16x8 m0 = *(const bf16x8*)&Ml[arow][qd * 8];
    bf16x8 m1 = *(const bf16x8*)&Ml[arow][32 + qd * 8];
#pragma unroll
    for (int n = 0; n < 6; n++) {
      int brow = n * 16 + l15;
      bf16x8 b0 = *(const bf16x8*)&STb[brow][qd * 8];
      bf16x8 b1 = *(const bf16x8*)&STb[brow][32 + qd * 8];
      acc[n] = mfma16(a0, b0, acc[n]);
      acc[n] = mfma16(a1, b1, acc[n]);
      bf16x8 u0 = *(const bf16x8*)&UT[brow][qd * 8];
      bf16x8 u1 = *(const bf16x8*)&UT[brow][32 + qd * 8];
      acc[n] = mfma16(m0, u0, acc[n]);
      acc[n] = mfma16(m1, u1, acc[n]);
    }
  }
  // fused gated RMSNorm: row stats via 16-lane shfl reduce, then write attn
#pragma unroll
  for (int i = 0; i < 4; i++) {
    int tt = w * 16 + qd * 4 + i;
    float ss = 0.f;
#pragma unroll
    for (int n = 0; n < 6; n++) ss += acc[n][i] * acc[n][i];
    ss += __shfl_xor(ss, 1, 64);
    ss += __shfl_xor(ss, 2, 64);
    ss += __shfl_xor(ss, 4, 64);
    ss += __shfl_xor(ss, 8, 64);
    float rs = rsqrtf(ss * (1.f / DVn) + 1e-5f);
    size_t orow = ((size_t)(b * Tn + t0 + tt)) * HDV + h * DVn;
#pragma unroll
    for (int n = 0; n < 6; n++) {
      int dv = n * 16 + l15;
      float g = __bfloat162float(gate[orow + dv]);
      attn[orow + dv] = __float2bfloat16(acc[n][i] * rs * onwl[dv] * siluf(g));
    }
  }
}

// ---------------- act *= up  (bf16x8, act already silu'd) ----------------
__global__ __launch_bounds__(256) void silumul_bf_k(bf16* __restrict__ a,
                                                    const bf16* __restrict__ b) {
  size_t i = ((size_t)blockIdx.x * 256 + threadIdx.x) * 8;
  bf16x8 av = *(const bf16x8*)(a + i);
  bf16x8 bv = *(const bf16x8*)(b + i);
  bf16x8 r;
#pragma unroll
  for (int e = 0; e < 8; e++) r[e] = f2b(b2f(av[e]) * b2f(bv[e]));
  *(bf16x8*)(a + i) = r;
}

extern "C" void kernel_launch(void* const* d_in, const int* in_sizes, int n_in,
                              void* d_out, int out_size, void* d_ws, size_t ws_size,
                              hipStream_t stream) {
  const float* x       = (const float*)d_in[0];
  const float* norm1_w = (const float*)d_in[1];
  const float* q_w     = (const float*)d_in[2];
  const float* k_w     = (const float*)d_in[3];
  const float* v_w     = (const float*)d_in[4];
  const float* cq_w    = (const float*)d_in[5];
  const float* ck_w    = (const float*)d_in[6];
  const float* cv_w    = (const float*)d_in[7];
  const float* b_w     = (const float*)d_in[8];
  const float* a_w     = (const float*)d_in[9];
  const float* A_log   = (const float*)d_in[10];
  const float* dt_bias = (const float*)d_in[11];
  const float* g_w     = (const float*)d_in[12];
  const float* o_norm_w= (const float*)d_in[13];
  const float* o_w     = (const float*)d_in[14];
  const float* norm2_w = (const float*)d_in[15];
  const float* gate_w  = (const float*)d_in[16];
  const float* up_w    = (const float*)d_in[17];
  const float* down_w  = (const float*)d_in[18];
  char* wsb = (char*)d_ws;
  float* out = (float*)d_out;

  bf16*  hbf   = (bf16*)(wsb + WO_HBF);
  bf16*  qkvr  = (bf16*)(wsb + WO_QKVR);
  bf16*  qkvc  = (bf16*)(wsb + WO_QKVC);
  bf16*  upb   = (bf16*)(wsb + WO_QKVC);   // reuse after p2c
  bf16*  attn  = (bf16*)(wsb + WO_OSC);    // attn in old osc slot (no St overlap)
  bf16*  actb  = (bf16*)(wsb + WO_ACT);
  bf16*  gateb = (bf16*)(wsb + WO_GATE);
  float* x1    = (float*)(wsb + WO_X1);
  float* ba    = (float*)(wsb + WO_BA);
  float* Gc    = (float*)(wsb + WO_GC);
  bf16*  Tg    = (bf16*)(wsb + WO_T);
  bf16*  Uvg   = (bf16*)(wsb + WO_UV);
  bf16*  A_g   = (bf16*)(wsb + WO_A);
  bf16*  B_g   = (bf16*)(wsb + WO_B);
  bf16*  St_g  = (bf16*)(wsb + WO_ST);
  bf16*  wb    = (bf16*)(wsb + WO_WB);

  // 0. merged transpose-cast of all 10 weights (one launch)
  {
    TcastArgs ta;
    const float* srcs[10] = {q_w, k_w, v_w, g_w, o_w, gate_w, up_w, down_w, b_w, a_w};
    bf16* dsts[10] = {wb + WB_QKVT, wb + WB_QKVT + 768 * 1024, wb + WB_QKVT + 1536 * 1024,
                      wb + WB_GT, wb + WB_OT, wb + WB_GATET, wb + WB_UPT, wb + WB_DOWNT,
                      wb + WB_ABT, wb + WB_ABT + 16 * 1024};
    int Rs[10] = {1024, 1024, 1024, 1024, 1536, 1024, 1024, 3072, 1024, 1024};
    int Cs[10] = {768, 768, 1536, 1536, 1024, 3072, 3072, 1024, 16, 16};
    int off = 0;
    for (int i = 0; i < 10; i++) {
      ta.src[i] = srcs[i]; ta.dst[i] = dsts[i];
      ta.R[i] = Rs[i]; ta.C[i] = Cs[i];
      ta.gxw[i] = (Cs[i] + 31) / 32;
      ta.t0[i] = off;
      off += ta.gxw[i] * (Rs[i] / 32);
    }
    tcast_all<<<off, dim3(32, 8), 0, stream>>>(ta);
  }

  // 1. h_bf = rmsnorm(x)
  rmsnorm_bf_k<<<BT, 256, 0, stream>>>(x, norm1_w, hbf);
  // 2. fused qkv+gate projection; ba on small kernel
  gemm256<<<576, 512, 0, stream>>>(hbf, wb + WB_QKVT, qkvr, gateb, 18, 4608, 1024, 10);
  gemm_mfma<<<dim3(1, 64), 256, 0, stream>>>(hbf, wb + WB_ABT, ba, nullptr, 32, 1024, 32, 0);
  // 3. conv+silu, l2norm, beta/g
  convsilu2_k<<<dim3(QKVC / 256, BT / 8), 256, 0, stream>>>(qkvr, qkvc, cq_w, ck_w, cv_w);
  l2norm_k<<<(BT * 32) / 256, 256, 0, stream>>>(qkvc);
  betag_k<<<(BT * Hn) / 256, 256, 0, stream>>>(ba, A_log, dt_bias);
  // 4. chunked gated delta rule (fused WY+affine -> scan -> fused output+gatednorm)
  dn_p1a<<<Bn * Hn * NC, 256, 0, stream>>>(qkvc, ba, Gc, Tg, Uvg, A_g, B_g);
  dn_p2b<<<Bn * Hn, 256, 0, stream>>>(A_g, B_g, St_g);
  dn_p2c<<<Bn * Hn * NC, 256, 0, stream>>>(qkvc, ba, Gc, Tg, Uvg, St_g, gateb, o_norm_w, attn);
  // 5. x1 = x + attn @ o_w
  gemm_mfma<<<dim3(8, 64), 256, 0, stream>>>(attn, wb + WB_OT, x1, x, 1024, 1536, 1024, 0);
  // 6. h2 = rmsnorm(x1)
  rmsnorm_bf_k<<<BT, 256, 0, stream>>>(x1, norm2_w, hbf);
  // 7. fused MLP gate+up, then act *= up
  gemm256<<<768, 512, 0, stream>>>(hbf, wb + WB_GATET, actb, upb, 24, 6144, 1024, 11);
  silumul_bf_k<<<(BT * In) / (8 * 256), 256, 0, stream>>>(actb, upb);
  // 8. out = x1 + act @ down_w
  gemm_mfma<<<dim3(8, 64), 256, 0, stream>>>(actb, wb + WB_DOWNT, out, x1, 1024, 3072, 1024, 0);
}

// Round 17
// 665.278 us; speedup vs baseline: 1.0862x; 1.0862x over previous
//
#include <hip/hip_runtime.h>
#include <hip/hip_bf16.h>
#include <math.h>

// Problem constants
constexpr int Bn = 4, Tn = 2048, Dn = 1024, Hn = 16, DKn = 48, DVn = 96, In = 3072;
constexpr int BT = Bn * Tn;               // 8192
constexpr int HDK = Hn * DKn;             // 768
constexpr int HDV = Hn * DVn;             // 1536
constexpr int QKVC = 2 * HDK + HDV;       // 3072
constexpr int CC = 64;                    // chunk length
constexpr int NC = Tn / CC;               // 32 chunks per (b,h)

using bf16 = __hip_bfloat16;
typedef __attribute__((ext_vector_type(8))) short bf16x8;
typedef __attribute__((ext_vector_type(4))) float f32x4;

// ---- Workspace layout (byte offsets) ----
constexpr size_t WO_HBF   = 0;              // h/h2 bf16 [8192][1024]     16 MB
constexpr size_t WO_QKVR  = 16777216;       // raw qkv 48MB; then A/B; then attn; then act
constexpr size_t WO_OSC   = 16777216;       // attn bf16 [8192][1536] (ends 41.9MB < St 45.1MB)
constexpr size_t WO_ACT   = 16777216;       // mlp act bf16 [8192][3072]
constexpr size_t WO_A     = 16777216;       // A bf16 [2048][48][48]  9.4 MB
constexpr size_t WO_B     = 26214400;       // B bf16 [2048][48][96]  18.9 MB (ends 45.1MB)
constexpr size_t WO_ST    = 45088768;       // St bf16 [2048][96][48] 18.9 MB (ends 64.0MB)
constexpr size_t WO_QKVC  = 67108864;       // conv'd qkv bf16 [8192][3072] 48 MB; later upb
constexpr size_t WO_GATE  = 117440512;      // gate bf16 [8192][1536]     24 MB
constexpr size_t WO_X1    = 142606336;      // x1 fp32 [8192][1024]       32 MB
constexpr size_t WO_BA    = 176160768;      // ba fp32 [8192][32]         1 MB
constexpr size_t WO_GC    = 177209344;      // Gc fp32 [64][2048]         0.5 MB
constexpr size_t WO_T     = 177733632;      // T bf16 [2048][64][64]      16.8 MB
constexpr size_t WO_UV    = 194510848;      // Uv bf16 [2048][64][96]     25.2 MB
constexpr size_t WO_WB    = 219676672;      // bf16 weights ~31.5 MB
// bf16-element offsets inside WB:
constexpr size_t WB_QKVT = 0;              // [3072][1024]  (+GT contiguous => [4608][1024])
constexpr size_t WB_GT   = 3145728;        // [1536][1024]
constexpr size_t WB_OT   = 4718592;        // [1024][1536]
constexpr size_t WB_GATET= 6291456;        // [3072][1024]  (+UPT contiguous => [6144][1024])
constexpr size_t WB_UPT  = 9437184;        // [3072][1024]
constexpr size_t WB_DOWNT= 12582912;       // [1024][3072]
constexpr size_t WB_ABT  = 15728640;       // [32][1024]

__device__ __forceinline__ float sigmoidf_(float x) { return 1.f / (1.f + __expf(-x)); }
__device__ __forceinline__ float siluf(float x) { return x * sigmoidf_(x); }

__device__ __forceinline__ void glds16(const void* g, void* l) {
  __builtin_amdgcn_global_load_lds((const __attribute__((address_space(1))) void*)g,
                                   (__attribute__((address_space(3))) void*)l, 16, 0, 0);
}

__device__ __forceinline__ f32x4 mfma16(bf16x8 a, bf16x8 b, f32x4 c) {
  return __builtin_amdgcn_mfma_f32_16x16x32_bf16(a, b, c, 0, 0, 0);
}

__device__ __forceinline__ bf16x8 scale8(bf16x8 a, float s) {
  bf16x8 r;
#pragma unroll
  for (int e = 0; e < 8; e++) {
    float f = __bfloat162float(__ushort_as_bfloat16((unsigned short)a[e])) * s;
    r[e] = (short)__bfloat16_as_ushort(__float2bfloat16(f));
  }
  return r;
}

__device__ __forceinline__ float b2f(short u) {
  return __bfloat162float(__ushort_as_bfloat16((unsigned short)u));
}
__device__ __forceinline__ short f2b(float f) {
  return (short)__bfloat16_as_ushort(__float2bfloat16(f));
}

// ---------------- merged transpose-cast: 10 weights in one launch ----------------
struct TcastArgs {
  const float* src[10];
  bf16* dst[10];
  int R[10], C[10], gxw[10], t0[10];
};

__global__ void tcast_all(TcastArgs a) {
  __shared__ float t[32][33];
  int bid = blockIdx.x;
  int i = 0;
#pragma unroll
  for (int k = 1; k < 10; k++) if (bid >= a.t0[k]) i = k;
  int lt = bid - a.t0[i];
  int gxw = a.gxw[i];
  int bx = lt % gxw, by = lt / gxw;
  const float* in = a.src[i];
  bf16* out = a.dst[i];
  int R = a.R[i], C = a.C[i];
  int tx = threadIdx.x, ty = threadIdx.y;
  int c0 = bx * 32, r0 = by * 32;
#pragma unroll
  for (int j = 0; j < 4; j++) {
    int r = ty + j * 8;
    float v = (c0 + tx < C) ? in[(size_t)(r0 + r) * C + c0 + tx] : 0.f;
    t[r][tx] = v;
  }
  __syncthreads();
#pragma unroll
  for (int j = 0; j < 4; j++) {
    int cc = ty + j * 8;
    if (c0 + cc < C) out[(size_t)(c0 + cc) * R + r0 + tx] = __float2bfloat16(t[tx][cc]);
  }
}

// ---------------- RMSNorm -> bf16 out ----------------
__global__ void rmsnorm_bf_k(const float* __restrict__ x, const float* __restrict__ w,
                             bf16* __restrict__ y) {
  int row = blockIdx.x;
  const float4* xr = (const float4*)(x + (size_t)row * Dn);
  int tid = threadIdx.x;
  float4 v = xr[tid];
  float ss = v.x * v.x + v.y * v.y + v.z * v.z + v.w * v.w;
  for (int m = 32; m >= 1; m >>= 1) ss += __shfl_xor(ss, m, 64);
  __shared__ float wsum[4];
  if ((tid & 63) == 0) wsum[tid >> 6] = ss;
  __syncthreads();
  ss = wsum[0] + wsum[1] + wsum[2] + wsum[3];
  float rs = rsqrtf(ss * (1.f / Dn) + 1e-5f);
  float4 wv = ((const float4*)w)[tid];
  bf16* yr = y + (size_t)row * Dn + tid * 4;
  yr[0] = __float2bfloat16(v.x * rs * wv.x);
  yr[1] = __float2bfloat16(v.y * rs * wv.y);
  yr[2] = __float2bfloat16(v.z * rs * wv.z);
  yr[3] = __float2bfloat16(v.w * rs * wv.w);
}

// ---------------- 256x256 16-wave MFMA GEMM, 4-buffer counted-vmcnt pipeline ----------------
// 1024 threads (4 waves/SIMD). Per-wave output 64x64 (acc[4][4]). 2 glds16/thread/tile.
// mode 10: col<3072 -> C0 ld 3072 raw, else C1 ld 1536 raw.
// mode 11: col<3072 -> silu -> C0 ld 3072, else raw -> C1 ld 3072.
#define AS256(bi) (lds + (bi) * 8192)
#define BS256(bi) (lds + 32768 + (bi) * 8192)
#define STAGE256(bi, k0) do { \
    glds16(gA0 + (k0), AS256(bi) + w * 512); \
    glds16(gB0 + (k0), BS256(bi) + w * 512); \
  } while (0)

__global__ __launch_bounds__(1024) void gemm256(
    const bf16* __restrict__ A, const bf16* __restrict__ Bt,
    bf16* __restrict__ C0, bf16* __restrict__ C1,
    int gx, int N, int K, int mode) {
  __shared__ bf16 lds[65536];
  int nb = gx * 32;
  int q8 = nb >> 3;
  int bid = blockIdx.x;
  int sw = (bid & 7) * q8 + (bid >> 3);     // bijective XCD swizzle (nb%8==0)
  int by = sw & 31, bx = sw >> 5;           // M fastest within XCD -> B-panel L2 reuse
  int bm = by * 256, bn = bx * 256;
  int tid = threadIdx.x;
  int lane = tid & 63, w = tid >> 6;        // w in 0..15
  int l15 = lane & 15, lq = lane >> 4;
  int wr = w >> 2, wc = w & 3;              // 4x4 wave grid, per-wave 64x64
  int arow0 = tid >> 2;                     // 0..255
  int srcq = (tid & 3) ^ ((arow0 >> 1) & 3);
  const bf16* gA0 = A + (size_t)(bm + arow0) * K + srcq * 8;
  const bf16* gB0 = Bt + (size_t)(bn + arow0) * K + srcq * 8;
  int slot = lq ^ ((l15 >> 1) & 3);         // frag-read swizzle (matches store)
  f32x4 acc[4][4];
#pragma unroll
  for (int m = 0; m < 4; m++)
#pragma unroll
    for (int n = 0; n < 4; n++) acc[m][n] = (f32x4){0.f, 0.f, 0.f, 0.f};
  int NT = K >> 5;
  STAGE256(0, 0);
  STAGE256(1, 32);
  STAGE256(2, 64);
  for (int t = 0; t < NT; ++t) {
    int b = t & 3;
    if (t <= NT - 3)      { asm volatile("s_waitcnt vmcnt(4)" ::: "memory"); }
    else if (t == NT - 2) { asm volatile("s_waitcnt vmcnt(2)" ::: "memory"); }
    else                  { asm volatile("s_waitcnt vmcnt(0)" ::: "memory"); }
    __builtin_amdgcn_s_barrier();
    bf16x8 af[4], bfr[4];
#pragma unroll
    for (int m = 0; m < 4; m++)
      af[m] = *(const bf16x8*)(AS256(b) + (wr * 64 + m * 16 + l15) * 32 + slot * 8);
#pragma unroll
    for (int n = 0; n < 4; n++)
      bfr[n] = *(const bf16x8*)(BS256(b) + (wc * 64 + n * 16 + l15) * 32 + slot * 8);
    __builtin_amdgcn_s_setprio(1);
#pragma unroll
    for (int m = 0; m < 4; m++)
#pragma unroll
      for (int n = 0; n < 4; n++)
        acc[m][n] = mfma16(af[m], bfr[n], acc[m][n]);
    __builtin_amdgcn_s_setprio(0);
    if (t + 3 < NT) STAGE256((t + 3) & 3, (t + 3) * 32);
  }
  // ---- epilogue: LDS-coalesced C write (XOR-swizzled to avoid bank conflicts) ----
  __syncthreads();   // all K-loop LDS reads complete before overwrite
  bf16* dst; int ldc, bnl; bool doSilu;
  if (mode == 10) {
    if (bn < 3072) { dst = C0; ldc = 3072; bnl = bn; doSilu = false; }
    else           { dst = C1; ldc = 1536; bnl = bn - 3072; doSilu = false; }
  } else {  // mode 11
    if (bn < 3072) { dst = C0; ldc = 3072; bnl = bn; doSilu = true; }
    else           { dst = C1; ldc = 3072; bnl = bn - 3072; doSilu = false; }
  }
  bf16* cw = lds + w * 4096;   // per-wave 64x64 region
#pragma unroll
  for (int m = 0; m < 4; m++)
#pragma unroll
    for (int n = 0; n < 4; n++)
#pragma unroll
      for (int i = 0; i < 4; i++) {
        int row_l = m * 16 + lq * 4 + i;
        int col_l = n * 16 + l15;
        float v = acc[m][n][i];
        if (doSilu) v = siluf(v);
        cw[row_l * 64 + (col_l ^ ((row_l & 7) << 3))] = __float2bfloat16(v);
      }
  __syncthreads();
  int r8 = lane >> 3, cblk = lane & 7;
#pragma unroll
  for (int it = 0; it < 8; it++) {   // 8 iters x 64 lanes x 8 bf16 = 4096 (full 64x64)
    int row_l = it * 8 + r8;
    int sblk = cblk ^ (row_l & 7);
    bf16x8 val = *(const bf16x8*)&cw[row_l * 64 + sblk * 8];
    *(bf16x8*)&dst[(size_t)(bm + wr * 64 + row_l) * ldc + bnl + wc * 64 + cblk * 8] = val;
  }
}

// ---------------- 128x128 16-wave MFMA GEMM, 4-buffer counted-vmcnt pipeline ----------------
// 1024 threads. Per-wave 32x32 (acc[2][2]). A staged by waves 0-7, B by waves 8-15
// (1 glds16/thread/tile). mode 0: fp32 out (+res). mode 3: bf16 acc. K>=96.
__global__ __launch_bounds__(1024) void gemm_mfma(
    const bf16* __restrict__ A, const bf16* __restrict__ Bt,
    void* __restrict__ Cv, const float* __restrict__ res,
    int N, int K, int ldc, int mode) {
  __shared__ bf16 As[4][4096];
  __shared__ bf16 Bs[4][4096];
  int tid = threadIdx.x, lane = tid & 63, w = tid >> 6;   // w in 0..15
  int bm = blockIdx.y * 128, bn = blockIdx.x * 128;
  int l15 = lane & 15, lq = lane >> 4;
  int wr = w >> 2, wc = w & 3;              // per-wave 32x32
  int r0 = (tid & 511) >> 2;                // 0..127
  int sq = (tid & 3) ^ ((r0 >> 1) & 3);
  const bf16* g0;
  bf16* lb;
  if (w < 8) {
    g0 = A + (size_t)(bm + r0) * K + sq * 8;
    lb = &As[0][w * 512];
  } else {
    int br = bn + r0; if (br >= N) br = 0;
    g0 = Bt + (size_t)br * K + sq * 8;
    lb = &Bs[0][(w - 8) * 512];
  }
#define STAGE128X(bi, k0) glds16(g0 + (k0), lb + (bi) * 4096)
  int slot = lq ^ ((l15 >> 1) & 3);
  f32x4 acc[2][2];
#pragma unroll
  for (int m = 0; m < 2; m++)
#pragma unroll
    for (int n = 0; n < 2; n++) acc[m][n] = (f32x4){0.f, 0.f, 0.f, 0.f};
  int NT = K >> 5;
  STAGE128X(0, 0);
  STAGE128X(1, 32);
  STAGE128X(2, 64);
  for (int t = 0; t < NT; ++t) {
    int b = t & 3;
    if (t <= NT - 3)      { asm volatile("s_waitcnt vmcnt(2)" ::: "memory"); }
    else if (t == NT - 2) { asm volatile("s_waitcnt vmcnt(1)" ::: "memory"); }
    else                  { asm volatile("s_waitcnt vmcnt(0)" ::: "memory"); }
    __builtin_amdgcn_s_barrier();
    bf16x8 af[2], bfr[2];
#pragma unroll
    for (int m = 0; m < 2; m++)
      af[m] = *(const bf16x8*)&As[b][(wr * 32 + m * 16 + l15) * 32 + slot * 8];
#pragma unroll
    for (int n = 0; n < 2; n++)
      bfr[n] = *(const bf16x8*)&Bs[b][(wc * 32 + n * 16 + l15) * 32 + slot * 8];
    __builtin_amdgcn_s_setprio(1);
#pragma unroll
    for (int m = 0; m < 2; m++)
#pragma unroll
      for (int n = 0; n < 2; n++)
        acc[m][n] = mfma16(af[m], bfr[n], acc[m][n]);
    __builtin_amdgcn_s_setprio(0);
    if (t + 3 < NT) STAGE128X((t + 3) & 3, (t + 3) * 32);
  }
#pragma unroll
  for (int m = 0; m < 2; m++) {
#pragma unroll
    for (int n = 0; n < 2; n++) {
      int col = bn + wc * 32 + n * 16 + l15;
      if (col >= N) continue;
#pragma unroll
      for (int i = 0; i < 4; i++) {
        int row = bm + wr * 32 + m * 16 + lq * 4 + i;
        float v = acc[m][n][i];
        size_t idx = (size_t)row * ldc + col;
        if (mode == 0) {
          if (res) v += res[idx];
          ((float*)Cv)[idx] = v;
        } else {
          ((bf16*)Cv)[idx] = __float2bfloat16(v);
        }
      }
    }
  }
}

// ---------------- Parallel causal conv (K=4) + silu ----------------
__global__ __launch_bounds__(256) void convsilu2_k(const bf16* __restrict__ in,
                                                   bf16* __restrict__ outp,
                                                   const float* __restrict__ wq,
                                                   const float* __restrict__ wk,
                                                   const float* __restrict__ wv) {
  int tx = threadIdx.x & 31;
  int ty = threadIdx.x >> 5;
  int c = (blockIdx.x * 32 + tx) * 8;
  int gt = blockIdx.y * 8 + ty;
  int b = gt >> 11, t = gt & (Tn - 1);
  const float* wsrc = (c < HDK) ? (wq + c * 4)
                     : (c < 2 * HDK) ? (wk + (c - HDK) * 4)
                                     : (wv + (c - 2 * HDK) * 4);
  float4 W[8];
#pragma unroll
  for (int j = 0; j < 8; j++) W[j] = ((const float4*)wsrc)[j];
  const bf16* base = in + (size_t)b * Tn * QKVC + c;
  bf16x8 r[4];
  bf16x8 zero = {0, 0, 0, 0, 0, 0, 0, 0};
#pragma unroll
  for (int j = 0; j < 4; j++) {
    int tt = t - 3 + j;
    r[j] = (tt >= 0) ? *(const bf16x8*)(base + (size_t)tt * QKVC) : zero;
  }
  bf16x8 o;
#pragma unroll
  for (int ch = 0; ch < 8; ch++) {
    float x0 = b2f(r[0][ch]), x1 = b2f(r[1][ch]), x2 = b2f(r[2][ch]), x3 = b2f(r[3][ch]);
    float y = x0 * W[ch].x + x1 * W[ch].y + x2 * W[ch].z + x3 * W[ch].w;
    o[ch] = f2b(siluf(y));
  }
  *(bf16x8*)(outp + (size_t)gt * QKVC + c) = o;
}

// ---------------- l2norm: thread-per-48-elem head row, vectorized ----------------
__global__ __launch_bounds__(256) void l2norm_k(bf16* __restrict__ qkv) {
  int row = blockIdx.x * 256 + threadIdx.x;   // 0 .. BT*32-1
  int t = row >> 5, hr = row & 31;
  bf16* p = qkv + (size_t)t * QKVC + hr * DKn;
  bf16x8 v[6];
  float ss = 0.f;
#pragma unroll
  for (int j = 0; j < 6; j++) {
    v[j] = *(const bf16x8*)(p + j * 8);
#pragma unroll
    for (int e = 0; e < 8; e++) { float f = b2f(v[j][e]); ss += f * f; }
  }
  float rs = rsqrtf(ss + 1e-6f);
#pragma unroll
  for (int j = 0; j < 6; j++) {
    bf16x8 o;
#pragma unroll
    for (int e = 0; e < 8; e++) o[e] = f2b(b2f(v[j][e]) * rs);
    *(bf16x8*)(p + j * 8) = o;
  }
}

// ---------------- beta/g transform ----------------
__global__ void betag_k(float* __restrict__ ba, const float* __restrict__ A_log,
                        const float* __restrict__ dt_bias) {
  int i = blockIdx.x * blockDim.x + threadIdx.x;
  int h = i & 15, r = i >> 4;
  float bv = ba[(size_t)r * 32 + h];
  float av = ba[(size_t)r * 32 + 16 + h];
  ba[(size_t)r * 32 + h] = sigmoidf_(bv);
  float xx = av + dt_bias[h];
  float sp = (xx > 20.f) ? xx : log1pf(__expf(xx));
  ba[(size_t)r * 32 + 16 + h] = -__expf(A_log[h]) * sp;
}

// ---------------- Fused P1+P2a: WY precompute + affine coefficients ----------------
__global__ __launch_bounds__(256) void dn_p1a(const bf16* __restrict__ qkv,
                                              const float* __restrict__ ba,
                                              float* __restrict__ Gc_g,
                                              bf16* __restrict__ T_g,
                                              bf16* __restrict__ Uv_g,
                                              bf16* __restrict__ A_g,
                                              bf16* __restrict__ B_g) {
  __shared__ __align__(16) char smem[62976];
  bf16 (*Kl)[72]   = (bf16(*)[72])(smem);                 //  9216 B
  bf16 (*Tl)[72]   = (bf16(*)[72])(smem + 9216);          //  9216 B
  bf16 (*UvdT)[72] = (bf16(*)[72])(smem + 18432);         // 13824 B
  float* Gcl = (float*)(smem + 32256);
  float* Bl  = (float*)(smem + 32512);
  bf16 (*Vl)[100]  = (bf16(*)[100])(smem + 32768);
  float (*Nl)[68]  = (float(*)[68])(smem + 45568);
  bf16 (*KTl)[72]  = (bf16(*)[72])(smem + 32768);
  bf16 (*KTbl)[72] = (bf16(*)[72])(smem + 39680);
  bf16 (*M2T)[72]  = (bf16(*)[72])(smem + 46592);
  int cid = blockIdx.x;
  int nc = cid & (NC - 1);
  int bh = cid >> 5;
  int h = bh & 15, b = bh >> 4;
  int t0 = nc * CC;
  int tid = threadIdx.x, lane = tid & 63, w = tid >> 6;
  int l15 = lane & 15, qd = lane >> 4;
  bf16 zb = __float2bfloat16(0.f);
  {
    int t = tid >> 2, p = tid & 3;
    const bf16* row = qkv + ((size_t)(b * Tn + t0 + t)) * QKVC;
    int c0 = p * 12;
#pragma unroll
    for (int j = 0; j < 12; ++j) Kl[t][c0 + j] = row[HDK + h * DKn + c0 + j];
    int j0 = p * 24;
#pragma unroll
    for (int j = 0; j < 24; ++j) Vl[t][j0 + j] = row[2 * HDK + h * DVn + j0 + j];
  }
  for (int i = tid; i < 64 * 24; i += 256) {
    int t = i / 24, c = 48 + (i % 24);
    Kl[t][c] = zb;
  }
  if (tid < 64) {
    size_t row = (size_t)(b * Tn + t0 + tid);
    float g = ba[row * 32 + 16 + h];
    float be = ba[row * 32 + h];
    float acc = g;
#pragma unroll
    for (int d = 1; d < 64; d <<= 1) {
      float o = __shfl_up(acc, d);
      if (tid >= d) acc += o;
    }
    Gcl[tid] = acc; Bl[tid] = be;
    Gc_g[(size_t)bh * Tn + t0 + tid] = acc;
  }
  __syncthreads();
  f32x4 dacc[4];
#pragma unroll
  for (int n = 0; n < 4; n++) dacc[n] = (f32x4){0.f, 0.f, 0.f, 0.f};
  {
    int arow = w * 16 + l15;
    bf16x8 a0 = *(const bf16x8*)&Kl[arow][qd * 8];
    bf16x8 a1 = *(const bf16x8*)&Kl[arow][32 + qd * 8];
#pragma unroll
    for (int n = 0; n < 4; n++) {
      int brow = n * 16 + l15;
      bf16x8 b0 = *(const bf16x8*)&Kl[brow][qd * 8];
      bf16x8 b1 = *(const bf16x8*)&Kl[brow][32 + qd * 8];
      dacc[n] = mfma16(a0, b0, dacc[n]);
      dacc[n] = mfma16(a1, b1, dacc[n]);
    }
  }
#pragma unroll
  for (int i = 0; i < 4; i++) {
    int t = w * 16 + qd * 4 + i;
    float bt = Bl[t], gt = Gcl[t];
#pragma unroll
    for (int n = 0; n < 4; n++) {
      int s = n * 16 + l15;
      Nl[t][s] = (s < t) ? bt * __expf(gt - Gcl[s]) * dacc[n][i] : 0.f;
    }
  }
  __syncthreads();
  float g63 = Gcl[63];
  int c = tid;
  if (c < 160) {
    float R[64];
    if (c < 64) {
#pragma unroll
      for (int t = 0; t < 64; ++t) R[t] = (t == c) ? 1.f : 0.f;
    } else {
      int j = c - 64;
#pragma unroll
      for (int t = 0; t < 64; ++t) R[t] = Bl[t] * __bfloat162float(Vl[t][j]);
    }
#pragma unroll
    for (int t = 1; t < 64; ++t) {
      float a0 = 0.f, a1 = 0.f, a2 = 0.f, a3 = 0.f;
#pragma unroll
      for (int s = 0; s + 3 < t; s += 4) {
        float4 n4 = *(const float4*)&Nl[t][s];
        a0 += n4.x * R[s]; a1 += n4.y * R[s + 1];
        a2 += n4.z * R[s + 2]; a3 += n4.w * R[s + 3];
      }
#pragma unroll
      for (int s = t & ~3; s < t; ++s) a0 += Nl[t][s] * R[s];
      R[t] -= ((a0 + a1) + (a2 + a3));
    }
    if (c < 64) {
#pragma unroll
      for (int t = 0; t < 64; ++t) {
        bf16 v = __float2bfloat16(R[t]);
        T_g[(size_t)cid * 4096 + t * 64 + c] = v;
        Tl[t][c] = v;
      }
    } else {
      int j = c - 64;
#pragma unroll
      for (int t = 0; t < 64; ++t) {
        Uv_g[(size_t)cid * 6144 + t * 96 + j] = __float2bfloat16(R[t]);
        UvdT[j][t] = __float2bfloat16(R[t] * __expf(g63 - Gcl[t]));
      }
    }
  }
  __syncthreads();
  for (int i = tid; i < 48 * 64; i += 256) {
    int dk = i >> 6, t = i & 63;
    bf16 kv = Kl[t][dk];
    KTl[dk][t] = kv;
    float bl = Bl[t] * __expf(Gcl[t]);
    KTbl[dk][t] = __float2bfloat16(__bfloat162float(kv) * bl);
  }
  __syncthreads();
  f32x4 m1[3];
#pragma unroll
  for (int n = 0; n < 3; n++) m1[n] = (f32x4){0.f, 0.f, 0.f, 0.f};
  {
    int arow = w * 16 + l15;
    bf16x8 a0 = *(const bf16x8*)&Tl[arow][qd * 8];
    bf16x8 a1 = *(const bf16x8*)&Tl[arow][32 + qd * 8];
#pragma unroll
    for (int n = 0; n < 3; n++) {
      int brow = n * 16 + l15;
      bf16x8 b0 = *(const bf16x8*)&KTbl[brow][qd * 8];
      bf16x8 b1 = *(const bf16x8*)&KTbl[brow][32 + qd * 8];
      m1[n] = mfma16(a0, b0, m1[n]);
      m1[n] = mfma16(a1, b1, m1[n]);
    }
  }
#pragma unroll
  for (int i = 0; i < 4; i++) {
    int tt = w * 16 + qd * 4 + i;
    float dd = __expf(g63 - Gcl[tt]);
#pragma unroll
    for (int n = 0; n < 3; n++) {
      int dk = n * 16 + l15;
      M2T[dk][tt] = __float2bfloat16(m1[n][i] * dd);
    }
  }
  __syncthreads();
  float lamC = __expf(g63);
#pragma unroll
  for (int tswap = 0; tswap < 7; tswap++) {
    int t = w + 4 * tswap;
    if (t >= 27) break;
    int mi, ni; bool isA;
    if (t < 9) { isA = true; mi = t / 3; ni = t % 3; }
    else { isA = false; mi = (t - 9) / 6; ni = (t - 9) % 6; }
    f32x4 acc = (f32x4){0.f, 0.f, 0.f, 0.f};
    int arow = mi * 16 + l15;
    bf16x8 a0 = *(const bf16x8*)&KTl[arow][qd * 8];
    bf16x8 a1 = *(const bf16x8*)&KTl[arow][32 + qd * 8];
    int brow = ni * 16 + l15;
    if (isA) {
      bf16x8 b0 = *(const bf16x8*)&M2T[brow][qd * 8];
      bf16x8 b1 = *(const bf16x8*)&M2T[brow][32 + qd * 8];
      acc = mfma16(a0, b0, acc);
      acc = mfma16(a1, b1, acc);
#pragma unroll
      for (int i = 0; i < 4; i++) {
        int row = mi * 16 + qd * 4 + i, colv = ni * 16 + l15;
        float v = ((row == colv) ? lamC : 0.f) - acc[i];
        A_g[(size_t)cid * 2304 + row * 48 + colv] = __float2bfloat16(v);
      }
    } else {
      bf16x8 b0 = *(const bf16x8*)&UvdT[brow][qd * 8];
      bf16x8 b1 = *(const bf16x8*)&UvdT[brow][32 + qd * 8];
      acc = mfma16(a0, b0, acc);
      acc = mfma16(a1, b1, acc);
#pragma unroll
      for (int i = 0; i < 4; i++) {
        int row = mi * 16 + qd * 4 + i, colv = ni * 16 + l15;
        B_g[(size_t)cid * 4608 + row * 96 + colv] = __float2bfloat16(acc[i]);
      }
    }
  }
}

// ---------------- P2b: pipelined serial affine scan S' = A S + B ----------------
__global__ __launch_bounds__(256) void dn_p2b(const bf16* __restrict__ A_g,
                                              const bf16* __restrict__ B_g,
                                              bf16* __restrict__ St_g) {
  __shared__ bf16 STl[2][96][72];
  __shared__ bf16 Al[2][48][72];
  __shared__ bf16 Bl[2][4608];
  int bh = blockIdx.x;
  int tid = threadIdx.x, lane = tid & 63, w = tid >> 6;
  int l15 = lane & 15, qd = lane >> 4;
  bf16 zb = __float2bfloat16(0.f);
  for (int i = tid; i < 2 * 96 * 72; i += 256) (&STl[0][0][0])[i] = zb;
  for (int i = tid; i < 2 * 48 * 24; i += 256) {
    int buf = i / (48 * 24), r = (i / 24) % 48, cc = 48 + (i % 24);
    Al[buf][r][cc] = zb;
  }
  bf16x8 ra0, ra1, rb0, rb1;
  unsigned int rb2;
  int e_a0 = tid * 8, e_a1 = 2048 + tid * 8;
  {
    size_t cid = (size_t)bh * NC;
    ra0 = *(const bf16x8*)(A_g + cid * 2304 + e_a0);
    if (tid < 32) ra1 = *(const bf16x8*)(A_g + cid * 2304 + e_a1);
    rb0 = *(const bf16x8*)(B_g + cid * 4608 + tid * 16);
    rb1 = *(const bf16x8*)(B_g + cid * 4608 + tid * 16 + 8);
    rb2 = *(const unsigned int*)(B_g + cid * 4608 + 4096 + tid * 2);
  }
  *(bf16x8*)&Al[0][e_a0 / 48][e_a0 % 48] = ra0;
  if (tid < 32) *(bf16x8*)&Al[0][e_a1 / 48][e_a1 % 48] = ra1;
  *(bf16x8*)&Bl[0][tid * 16] = rb0;
  *(bf16x8*)&Bl[0][tid * 16 + 8] = rb1;
  *(unsigned int*)&Bl[0][4096 + tid * 2] = rb2;
  {
    size_t cid = (size_t)bh * NC + 1;
    ra0 = *(const bf16x8*)(A_g + cid * 2304 + e_a0);
    if (tid < 32) ra1 = *(const bf16x8*)(A_g + cid * 2304 + e_a1);
    rb0 = *(const bf16x8*)(B_g + cid * 4608 + tid * 16);
    rb1 = *(const bf16x8*)(B_g + cid * 4608 + tid * 16 + 8);
    rb2 = *(const unsigned int*)(B_g + cid * 4608 + 4096 + tid * 2);
  }
  __syncthreads();

  for (int c = 0; c < NC - 1; ++c) {
    int cur = c & 1, nxt = cur ^ 1;
    size_t cid = (size_t)bh * NC + c;
    {
      int e0 = tid * 8, e1 = 2048 + tid * 8, e2 = 4096 + tid * 2;
      *(bf16x8*)(St_g + cid * 4608 + e0) = *(const bf16x8*)&STl[cur][e0 / 48][e0 % 48];
      *(bf16x8*)(St_g + cid * 4608 + e1) = *(const bf16x8*)&STl[cur][e1 / 48][e1 % 48];
      *(unsigned int*)(St_g + cid * 4608 + e2) = *(const unsigned int*)&STl[cur][e2 / 48][e2 % 48];
    }
    float vals[5][4];
#pragma unroll
    for (int ts = 0; ts < 5; ts++) {
      int t = w + 4 * ts;
      if (t >= 18) break;
      int mi = t / 3, ni = t % 3;
      f32x4 acc = (f32x4){0.f, 0.f, 0.f, 0.f};
      int arow = mi * 16 + l15;
      bf16x8 a0 = *(const bf16x8*)&STl[cur][arow][qd * 8];
      bf16x8 a1 = *(const bf16x8*)&STl[cur][arow][32 + qd * 8];
      int brow = ni * 16 + l15;
      bf16x8 b0 = *(const bf16x8*)&Al[cur][brow][qd * 8];
      bf16x8 b1 = *(const bf16x8*)&Al[cur][brow][32 + qd * 8];
      acc = mfma16(a0, b0, acc);
      acc = mfma16(a1, b1, acc);
#pragma unroll
      for (int i = 0; i < 4; i++) {
        int dv = mi * 16 + qd * 4 + i, ii = ni * 16 + l15;
        vals[ts][i] = acc[i] + __bfloat162float(Bl[cur][ii * 96 + dv]);
      }
    }
#pragma unroll
    for (int ts = 0; ts < 5; ts++) {
      int t = w + 4 * ts;
      if (t >= 18) break;
      int mi = t / 3, ni = t % 3;
#pragma unroll
      for (int i = 0; i < 4; i++) {
        int dv = mi * 16 + qd * 4 + i, ii = ni * 16 + l15;
        STl[nxt][dv][ii] = __float2bfloat16(vals[ts][i]);
      }
    }
    if (c + 1 <= NC - 2) {
      *(bf16x8*)&Al[nxt][e_a0 / 48][e_a0 % 48] = ra0;
      if (tid < 32) *(bf16x8*)&Al[nxt][e_a1 / 48][e_a1 % 48] = ra1;
      *(bf16x8*)&Bl[nxt][tid * 16] = rb0;
      *(bf16x8*)&Bl[nxt][tid * 16 + 8] = rb1;
      *(unsigned int*)&Bl[nxt][4096 + tid * 2] = rb2;
      if (c + 2 <= NC - 2) {
        size_t cid2 = (size_t)bh * NC + c + 2;
        ra0 = *(const bf16x8*)(A_g + cid2 * 2304 + e_a0);
        if (tid < 32) ra1 = *(const bf16x8*)(A_g + cid2 * 2304 + e_a1);
        rb0 = *(const bf16x8*)(B_g + cid2 * 4608 + tid * 16);
        rb1 = *(const bf16x8*)(B_g + cid2 * 4608 + tid * 16 + 8);
        rb2 = *(const unsigned int*)(B_g + cid2 * 4608 + 4096 + tid * 2);
      }
    }
    __syncthreads();
  }
  {
    size_t cid = (size_t)bh * NC + (NC - 1);
    int cur = (NC - 1) & 1;
    int e0 = tid * 8, e1 = 2048 + tid * 8, e2 = 4096 + tid * 2;
    *(bf16x8*)(St_g + cid * 4608 + e0) = *(const bf16x8*)&STl[cur][e0 / 48][e0 % 48];
    *(bf16x8*)(St_g + cid * 4608 + e1) = *(const bf16x8*)&STl[cur][e1 / 48][e1 % 48];
    *(unsigned int*)(St_g + cid * 4608 + e2) = *(const unsigned int*)&STl[cur][e2 / 48][e2 % 48];
  }
}

// ---------------- P2c: per-chunk output + fused gated RMSNorm ----------------
__global__ __launch_bounds__(256) void dn_p2c(const bf16* __restrict__ qkv,
                                              const float* __restrict__ ba,
                                              const float* __restrict__ Gc_g,
                                              const bf16* __restrict__ T_g,
                                              const bf16* __restrict__ Uv_g,
                                              const bf16* __restrict__ St_g,
                                              const bf16* __restrict__ gate,
                                              const float* __restrict__ onw,
                                              bf16* __restrict__ attn) {
  __shared__ bf16 Kl[64][72], Ql[64][72], Tl[64][72], Ml[64][72];
  __shared__ bf16 G1T[96][72], UT[96][72], STb[96][72];
  __shared__ float Gcl[64], Bl[64];
  __shared__ float onwl[96];
  int cid = blockIdx.x;
  int nc = cid & (NC - 1);
  int bh = cid >> 5;
  int h = bh & 15, b = bh >> 4;
  int t0 = nc * CC;
  int tid = threadIdx.x, lane = tid & 63, w = tid >> 6;
  int l15 = lane & 15, qd = lane >> 4;
  const float scale = 0.14433756729740643f;  // 48^-0.5
  bf16 zb = __float2bfloat16(0.f);
  {
    int t = tid >> 2, p = tid & 3;
    size_t grow = (size_t)(b * Tn + t0 + t);
    const bf16* row = qkv + grow * QKVC;
    int c0 = p * 12;
#pragma unroll
    for (int j = 0; j < 12; ++j) {
      int cc = c0 + j;
      Kl[t][cc] = row[HDK + h * DKn + cc];
      Ql[t][cc] = __float2bfloat16(__bfloat162float(row[h * DKn + cc]) * scale);
    }
    if (p == 0) { Gcl[t] = Gc_g[(size_t)bh * Tn + t0 + t]; Bl[t] = ba[grow * 32 + h]; }
  }
  if (tid < 96) onwl[tid] = onw[tid];
  for (int i = tid; i < 64 * 16; i += 256) {
    int t = i >> 4, cc = 48 + (i & 15);
    Kl[t][cc] = zb; Ql[t][cc] = zb;
  }
  for (int i = tid; i < 4096; i += 256)
    (&Tl[0][0])[(i >> 6) * 72 + (i & 63)] = T_g[(size_t)cid * 4096 + i];
  for (int i = tid; i < 4608; i += 256)
    STb[i / 48][i % 48] = St_g[(size_t)cid * 4608 + i];
  for (int i = tid; i < 96 * 16; i += 256)
    STb[i >> 4][48 + (i & 15)] = zb;
  __syncthreads();  // sync1
  f32x4 acc[6];
#pragma unroll
  for (int n = 0; n < 6; n++) acc[n] = (f32x4){0.f, 0.f, 0.f, 0.f};
  {
    int arow = w * 16 + l15;
    bf16x8 a0 = *(const bf16x8*)&Kl[arow][qd * 8];
    bf16x8 a1 = *(const bf16x8*)&Kl[arow][32 + qd * 8];
#pragma unroll
    for (int n = 0; n < 6; n++) {
      int brow = n * 16 + l15;
      bf16x8 b0 = *(const bf16x8*)&STb[brow][qd * 8];
      bf16x8 b1 = *(const bf16x8*)&STb[brow][32 + qd * 8];
      acc[n] = mfma16(a0, b0, acc[n]);
      acc[n] = mfma16(a1, b1, acc[n]);
    }
  }
#pragma unroll
  for (int i = 0; i < 4; i++) {
    int tt = w * 16 + qd * 4 + i;
    float sc = Bl[tt] * __expf(Gcl[tt]);
#pragma unroll
    for (int n = 0; n < 6; n++)
      G1T[n * 16 + l15][tt] = __float2bfloat16(acc[n][i] * sc);
  }
  __syncthreads();  // sync2
#pragma unroll
  for (int n = 0; n < 6; n++) acc[n] = (f32x4){0.f, 0.f, 0.f, 0.f};
  {
    int arow = w * 16 + l15;
    bf16x8 a0 = *(const bf16x8*)&Tl[arow][qd * 8];
    bf16x8 a1 = *(const bf16x8*)&Tl[arow][32 + qd * 8];
#pragma unroll
    for (int n = 0; n < 6; n++) {
      int brow = n * 16 + l15;
      bf16x8 b0 = *(const bf16x8*)&G1T[brow][qd * 8];
      bf16x8 b1 = *(const bf16x8*)&G1T[brow][32 + qd * 8];
      acc[n] = mfma16(a0, b0, acc[n]);
      acc[n] = mfma16(a1, b1, acc[n]);
    }
  }
#pragma unroll
  for (int i = 0; i < 4; i++) {
    int tt = w * 16 + qd * 4 + i;
#pragma unroll
    for (int n = 0; n < 6; n++) {
      int dv = n * 16 + l15;
      float uv = __bfloat162float(Uv_g[(size_t)cid * 6144 + tt * 96 + dv]);
      UT[dv][tt] = __float2bfloat16(uv - acc[n][i]);
    }
  }
  f32x4 qk[4];
#pragma unroll
  for (int n = 0; n < 4; n++) qk[n] = (f32x4){0.f, 0.f, 0.f, 0.f};
  {
    int arow = w * 16 + l15;
    bf16x8 a0 = *(const bf16x8*)&Ql[arow][qd * 8];
    bf16x8 a1 = *(const bf16x8*)&Ql[arow][32 + qd * 8];
#pragma unroll
    for (int n = 0; n < 4; n++) {
      int brow = n * 16 + l15;
      bf16x8 b0 = *(const bf16x8*)&Kl[brow][qd * 8];
      bf16x8 b1 = *(const bf16x8*)&Kl[brow][32 + qd * 8];
      qk[n] = mfma16(a0, b0, qk[n]);
      qk[n] = mfma16(a1, b1, qk[n]);
    }
  }
#pragma unroll
  for (int i = 0; i < 4; i++) {
    int tt = w * 16 + qd * 4 + i;
    float gt = Gcl[tt];
#pragma unroll
    for (int n = 0; n < 4; n++) {
      int ss = n * 16 + l15;
      float m = (ss <= tt) ? qk[n][i] * __expf(gt - Gcl[ss]) : 0.f;
      Ml[tt][ss] = __float2bfloat16(m);
    }
  }
  __syncthreads();  // sync3
#pragma unroll
  for (int n = 0; n < 6; n++) acc[n] = (f32x4){0.f, 0.f, 0.f, 0.f};
  {
    int arow = w * 16 + l15;
    float lam = __expf(Gcl[arow]);
    bf16x8 a0 = scale8(*(const bf16x8*)&Ql[arow][qd * 8], lam);
    bf16x8 a1 = scale8(*(const bf16x8*)&Ql[arow][32 + qd * 8], lam);
    bf16x8 m0 = *(const bf16x8*)&Ml[arow][qd * 8];
    bf16x8 m1 = *(const bf16x8*)&Ml[arow][32 + qd * 8];
#pragma unroll
    for (int n = 0; n < 6; n++) {
      int brow = n * 16 + l15;
      bf16x8 b0 = *(const bf16x8*)&STb[brow][qd * 8];
      bf16x8 b1 = *(const bf16x8*)&STb[brow][32 + qd * 8];
      acc[n] = mfma16(a0, b0, acc[n]);
      acc[n] = mfma16(a1, b1, acc[n]);
      bf16x8 u0 = *(const bf16x8*)&UT[brow][qd * 8];
      bf16x8 u1 = *(const bf16x8*)&UT[brow][32 + qd * 8];
      acc[n] = mfma16(m0, u0, acc[n]);
      acc[n] = mfma16(m1, u1, acc[n]);
    }
  }
  // fused gated RMSNorm: row stats via 16-lane shfl reduce, then write attn
#pragma unroll
  for (int i = 0; i < 4; i++) {
    int tt = w * 16 + qd * 4 + i;
    float ss = 0.f;
#pragma unroll
    for (int n = 0; n < 6; n++) ss += acc[n][i] * acc[n][i];
    ss += __shfl_xor(ss, 1, 64);
    ss += __shfl_xor(ss, 2, 64);
    ss += __shfl_xor(ss, 4, 64);
    ss += __shfl_xor(ss, 8, 64);
    float rs = rsqrtf(ss * (1.f / DVn) + 1e-5f);
    size_t orow = ((size_t)(b * Tn + t0 + tt)) * HDV + h * DVn;
#pragma unroll
    for (int n = 0; n < 6; n++) {
      int dv = n * 16 + l15;
      float g = __bfloat162float(gate[orow + dv]);
      attn[orow + dv] = __float2bfloat16(acc[n][i] * rs * onwl[dv] * siluf(g));
    }
  }
}

// ---------------- act *= up  (bf16x8, act already silu'd) ----------------
__global__ __launch_bounds__(256) void silumul_bf_k(bf16* __restrict__ a,
                                                    const bf16* __restrict__ b) {
  size_t i = ((size_t)blockIdx.x * 256 + threadIdx.x) * 8;
  bf16x8 av = *(const bf16x8*)(a + i);
  bf16x8 bv = *(const bf16x8*)(b + i);
  bf16x8 r;
#pragma unroll
  for (int e = 0; e < 8; e++) r[e] = f2b(b2f(av[e]) * b2f(bv[e]));
  *(bf16x8*)(a + i) = r;
}

extern "C" void kernel_launch(void* const* d_in, const int* in_sizes, int n_in,
                              void* d_out, int out_size, void* d_ws, size_t ws_size,
                              hipStream_t stream) {
  const float* x       = (const float*)d_in[0];
  const float* norm1_w = (const float*)d_in[1];
  const float* q_w     = (const float*)d_in[2];
  const float* k_w     = (const float*)d_in[3];
  const float* v_w     = (const float*)d_in[4];
  const float* cq_w    = (const float*)d_in[5];
  const float* ck_w    = (const float*)d_in[6];
  const float* cv_w    = (const float*)d_in[7];
  const float* b_w     = (const float*)d_in[8];
  const float* a_w     = (const float*)d_in[9];
  const float* A_log   = (const float*)d_in[10];
  const float* dt_bias = (const float*)d_in[11];
  const float* g_w     = (const float*)d_in[12];
  const float* o_norm_w= (const float*)d_in[13];
  const float* o_w     = (const float*)d_in[14];
  const float* norm2_w = (const float*)d_in[15];
  const float* gate_w  = (const float*)d_in[16];
  const float* up_w    = (const float*)d_in[17];
  const float* down_w  = (const float*)d_in[18];
  char* wsb = (char*)d_ws;
  float* out = (float*)d_out;

  bf16*  hbf   = (bf16*)(wsb + WO_HBF);
  bf16*  qkvr  = (bf16*)(wsb + WO_QKVR);
  bf16*  qkvc  = (bf16*)(wsb + WO_QKVC);
  bf16*  upb   = (bf16*)(wsb + WO_QKVC);   // reuse after p2c
  bf16*  attn  = (bf16*)(wsb + WO_OSC);    // attn in old osc slot (no St overlap)
  bf16*  actb  = (bf16*)(wsb + WO_ACT);
  bf16*  gateb = (bf16*)(wsb + WO_GATE);
  float* x1    = (float*)(wsb + WO_X1);
  float* ba    = (float*)(wsb + WO_BA);
  float* Gc    = (float*)(wsb + WO_GC);
  bf16*  Tg    = (bf16*)(wsb + WO_T);
  bf16*  Uvg   = (bf16*)(wsb + WO_UV);
  bf16*  A_g   = (bf16*)(wsb + WO_A);
  bf16*  B_g   = (bf16*)(wsb + WO_B);
  bf16*  St_g  = (bf16*)(wsb + WO_ST);
  bf16*  wb    = (bf16*)(wsb + WO_WB);

  // 0. merged transpose-cast of all 10 weights (one launch)
  {
    TcastArgs ta;
    const float* srcs[10] = {q_w, k_w, v_w, g_w, o_w, gate_w, up_w, down_w, b_w, a_w};
    bf16* dsts[10] = {wb + WB_QKVT, wb + WB_QKVT + 768 * 1024, wb + WB_QKVT + 1536 * 1024,
                      wb + WB_GT, wb + WB_OT, wb + WB_GATET, wb + WB_UPT, wb + WB_DOWNT,
                      wb + WB_ABT, wb + WB_ABT + 16 * 1024};
    int Rs[10] = {1024, 1024, 1024, 1024, 1536, 1024, 1024, 3072, 1024, 1024};
    int Cs[10] = {768, 768, 1536, 1536, 1024, 3072, 3072, 1024, 16, 16};
    int off = 0;
    for (int i = 0; i < 10; i++) {
      ta.src[i] = srcs[i]; ta.dst[i] = dsts[i];
      ta.R[i] = Rs[i]; ta.C[i] = Cs[i];
      ta.gxw[i] = (Cs[i] + 31) / 32;
      ta.t0[i] = off;
      off += ta.gxw[i] * (Rs[i] / 32);
    }
    tcast_all<<<off, dim3(32, 8), 0, stream>>>(ta);
  }

  // 1. h_bf = rmsnorm(x)
  rmsnorm_bf_k<<<BT, 256, 0, stream>>>(x, norm1_w, hbf);
  // 2. fused qkv+gate projection; ba on small kernel
  gemm256<<<576, 1024, 0, stream>>>(hbf, wb + WB_QKVT, qkvr, gateb, 18, 4608, 1024, 10);
  gemm_mfma<<<dim3(1, 64), 1024, 0, stream>>>(hbf, wb + WB_ABT, ba, nullptr, 32, 1024, 32, 0);
  // 3. conv+silu, l2norm, beta/g
  convsilu2_k<<<dim3(QKVC / 256, BT / 8), 256, 0, stream>>>(qkvr, qkvc, cq_w, ck_w, cv_w);
  l2norm_k<<<(BT * 32) / 256, 256, 0, stream>>>(qkvc);
  betag_k<<<(BT * Hn) / 256, 256, 0, stream>>>(ba, A_log, dt_bias);
  // 4. chunked gated delta rule (fused WY+affine -> scan -> fused output+gatednorm)
  dn_p1a<<<Bn * Hn * NC, 256, 0, stream>>>(qkvc, ba, Gc, Tg, Uvg, A_g, B_g);
  dn_p2b<<<Bn * Hn, 256, 0, stream>>>(A_g, B_g, St_g);
  dn_p2c<<<Bn * Hn * NC, 256, 0, stream>>>(qkvc, ba, Gc, Tg, Uvg, St_g, gateb, o_norm_w, attn);
  // 5. x1 = x + attn @ o_w
  gemm_mfma<<<dim3(8, 64), 1024, 0, stream>>>(attn, wb + WB_OT, x1, x, 1024, 1536, 1024, 0);
  // 6. h2 = rmsnorm(x1)
  rmsnorm_bf_k<<<BT, 256, 0, stream>>>(x1, norm2_w, hbf);
  // 7. fused MLP gate+up, then act *= up
  gemm256<<<768, 1024, 0, stream>>>(hbf, wb + WB_GATET, actb, upb, 24, 6144, 1024, 11);
  silumul_bf_k<<<(BT * In) / (8 * 256), 256, 0, stream>>>(actb, upb);
  // 8. out = x1 + act @ down_w
  gemm_mfma<<<dim3(8, 64), 1024, 0, stream>>>(actb, wb + WB_DOWNT, out, x1, 1024, 3072, 1024, 0);
}

// Round 18
// 616.105 us; speedup vs baseline: 1.1729x; 1.0798x over previous
//
#include <hip/hip_runtime.h>
#include <hip/hip_bf16.h>
#include <math.h>

// Problem constants
constexpr int Bn = 4, Tn = 2048, Dn = 1024, Hn = 16, DKn = 48, DVn = 96, In = 3072;
constexpr int BT = Bn * Tn;               // 8192
constexpr int HDK = Hn * DKn;             // 768
constexpr int HDV = Hn * DVn;             // 1536
constexpr int QKVC = 2 * HDK + HDV;       // 3072
constexpr int CC = 64;                    // chunk length
constexpr int NC = Tn / CC;               // 32 chunks per (b,h)

using bf16 = __hip_bfloat16;
typedef __attribute__((ext_vector_type(8))) short bf16x8;
typedef __attribute__((ext_vector_type(4))) float f32x4;

// ---- Workspace layout (byte offsets) ----
constexpr size_t WO_HBF   = 0;              // h/h2 bf16 [8192][1024]     16 MB
constexpr size_t WO_QKVR  = 16777216;       // raw qkv 48MB; then A/B; then attn; then act
constexpr size_t WO_OSC   = 16777216;       // attn bf16 [8192][1536] (ends 41.9MB < St 45.1MB)
constexpr size_t WO_ACT   = 16777216;       // mlp act bf16 [8192][3072]
constexpr size_t WO_A     = 16777216;       // A bf16 [2048][48][48]  9.4 MB
constexpr size_t WO_B     = 26214400;       // B bf16 [2048][48][96]  18.9 MB (ends 45.1MB)
constexpr size_t WO_ST    = 45088768;       // St bf16 [2048][96][48] 18.9 MB (ends 64.0MB)
constexpr size_t WO_QKVC  = 67108864;       // conv'd qkv bf16 [8192][3072] 48 MB
constexpr size_t WO_GATE  = 117440512;      // gate bf16 [8192][1536]     24 MB
constexpr size_t WO_X1    = 142606336;      // x1 fp32 [8192][1024]       32 MB
constexpr size_t WO_BA    = 176160768;      // ba fp32 [8192][32]         1 MB
constexpr size_t WO_GC    = 177209344;      // Gc fp32 [64][2048]         0.5 MB
constexpr size_t WO_T     = 177733632;      // T bf16 [2048][64][64]      16.8 MB
constexpr size_t WO_UV    = 194510848;      // Uv bf16 [2048][64][96]     25.2 MB
constexpr size_t WO_WB    = 219676672;      // bf16 weights ~31.5 MB
// bf16-element offsets inside WB:
constexpr size_t WB_QKVT = 0;              // [3072][1024]  (+GT contiguous => [4608][1024])
constexpr size_t WB_GT   = 3145728;        // [1536][1024]
constexpr size_t WB_OT   = 4718592;        // [1024][1536]
constexpr size_t WB_GATET= 6291456;        // [3072][1024]  (+UPT contiguous => [6144][1024])
constexpr size_t WB_UPT  = 9437184;        // [3072][1024]
constexpr size_t WB_DOWNT= 12582912;       // [1024][3072]
constexpr size_t WB_ABT  = 15728640;       // [32][1024]

__device__ __forceinline__ float sigmoidf_(float x) { return 1.f / (1.f + __expf(-x)); }
__device__ __forceinline__ float siluf(float x) { return x * sigmoidf_(x); }

__device__ __forceinline__ void glds16(const void* g, void* l) {
  __builtin_amdgcn_global_load_lds((const __attribute__((address_space(1))) void*)g,
                                   (__attribute__((address_space(3))) void*)l, 16, 0, 0);
}

__device__ __forceinline__ f32x4 mfma16(bf16x8 a, bf16x8 b, f32x4 c) {
  return __builtin_amdgcn_mfma_f32_16x16x32_bf16(a, b, c, 0, 0, 0);
}

__device__ __forceinline__ bf16x8 scale8(bf16x8 a, float s) {
  bf16x8 r;
#pragma unroll
  for (int e = 0; e < 8; e++) {
    float f = __bfloat162float(__ushort_as_bfloat16((unsigned short)a[e])) * s;
    r[e] = (short)__bfloat16_as_ushort(__float2bfloat16(f));
  }
  return r;
}

__device__ __forceinline__ float b2f(short u) {
  return __bfloat162float(__ushort_as_bfloat16((unsigned short)u));
}
__device__ __forceinline__ short f2b(float f) {
  return (short)__bfloat16_as_ushort(__float2bfloat16(f));
}

// ---------------- merged transpose-cast: 10 weights in one launch ----------------
struct TcastArgs {
  const float* src[10];
  bf16* dst[10];
  int R[10], C[10], gxw[10], t0[10];
};

__global__ void tcast_all(TcastArgs a) {
  __shared__ float t[32][33];
  int bid = blockIdx.x;
  int i = 0;
#pragma unroll
  for (int k = 1; k < 10; k++) if (bid >= a.t0[k]) i = k;
  int lt = bid - a.t0[i];
  int gxw = a.gxw[i];
  int bx = lt % gxw, by = lt / gxw;
  const float* in = a.src[i];
  bf16* out = a.dst[i];
  int R = a.R[i], C = a.C[i];
  int tx = threadIdx.x, ty = threadIdx.y;
  int c0 = bx * 32, r0 = by * 32;
#pragma unroll
  for (int j = 0; j < 4; j++) {
    int r = ty + j * 8;
    float v = (c0 + tx < C) ? in[(size_t)(r0 + r) * C + c0 + tx] : 0.f;
    t[r][tx] = v;
  }
  __syncthreads();
#pragma unroll
  for (int j = 0; j < 4; j++) {
    int cc = ty + j * 8;
    if (c0 + cc < C) out[(size_t)(c0 + cc) * R + r0 + tx] = __float2bfloat16(t[tx][cc]);
  }
}

// ---------------- RMSNorm -> bf16 out ----------------
__global__ void rmsnorm_bf_k(const float* __restrict__ x, const float* __restrict__ w,
                             bf16* __restrict__ y) {
  int row = blockIdx.x;
  const float4* xr = (const float4*)(x + (size_t)row * Dn);
  int tid = threadIdx.x;
  float4 v = xr[tid];
  float ss = v.x * v.x + v.y * v.y + v.z * v.z + v.w * v.w;
  for (int m = 32; m >= 1; m >>= 1) ss += __shfl_xor(ss, m, 64);
  __shared__ float wsum[4];
  if ((tid & 63) == 0) wsum[tid >> 6] = ss;
  __syncthreads();
  ss = wsum[0] + wsum[1] + wsum[2] + wsum[3];
  float rs = rsqrtf(ss * (1.f / Dn) + 1e-5f);
  float4 wv = ((const float4*)w)[tid];
  bf16* yr = y + (size_t)row * Dn + tid * 4;
  yr[0] = __float2bfloat16(v.x * rs * wv.x);
  yr[1] = __float2bfloat16(v.y * rs * wv.y);
  yr[2] = __float2bfloat16(v.z * rs * wv.z);
  yr[3] = __float2bfloat16(v.w * rs * wv.w);
}

// ---------------- 256x256 16-wave MFMA GEMM, 4-buffer counted-vmcnt pipeline ----------------
// 1024 threads (4 waves/SIMD). Per-wave output 64x64 (acc[4][4]). 2 glds16/thread/tile.
// mode 10: col<3072 -> C0 ld 3072 raw, else C1 ld 1536 raw.
#define AS256(bi) (lds + (bi) * 8192)
#define BS256(bi) (lds + 32768 + (bi) * 8192)
#define STAGE256(bi, k0) do { \
    glds16(gA0 + (k0), AS256(bi) + w * 512); \
    glds16(gB0 + (k0), BS256(bi) + w * 512); \
  } while (0)

__global__ __launch_bounds__(1024) void gemm256(
    const bf16* __restrict__ A, const bf16* __restrict__ Bt,
    bf16* __restrict__ C0, bf16* __restrict__ C1,
    int gx, int N, int K, int mode) {
  __shared__ bf16 lds[65536];
  int nb = gx * 32;
  int q8 = nb >> 3;
  int bid = blockIdx.x;
  int sw = (bid & 7) * q8 + (bid >> 3);     // bijective XCD swizzle (nb%8==0)
  int by = sw & 31, bx = sw >> 5;           // M fastest within XCD -> B-panel L2 reuse
  int bm = by * 256, bn = bx * 256;
  int tid = threadIdx.x;
  int lane = tid & 63, w = tid >> 6;        // w in 0..15
  int l15 = lane & 15, lq = lane >> 4;
  int wr = w >> 2, wc = w & 3;              // 4x4 wave grid, per-wave 64x64
  int arow0 = tid >> 2;                     // 0..255
  int srcq = (tid & 3) ^ ((arow0 >> 1) & 3);
  const bf16* gA0 = A + (size_t)(bm + arow0) * K + srcq * 8;
  const bf16* gB0 = Bt + (size_t)(bn + arow0) * K + srcq * 8;
  int slot = lq ^ ((l15 >> 1) & 3);         // frag-read swizzle (matches store)
  f32x4 acc[4][4];
#pragma unroll
  for (int m = 0; m < 4; m++)
#pragma unroll
    for (int n = 0; n < 4; n++) acc[m][n] = (f32x4){0.f, 0.f, 0.f, 0.f};
  int NT = K >> 5;
  STAGE256(0, 0);
  STAGE256(1, 32);
  STAGE256(2, 64);
  for (int t = 0; t < NT; ++t) {
    int b = t & 3;
    if (t <= NT - 3)      { asm volatile("s_waitcnt vmcnt(4)" ::: "memory"); }
    else if (t == NT - 2) { asm volatile("s_waitcnt vmcnt(2)" ::: "memory"); }
    else                  { asm volatile("s_waitcnt vmcnt(0)" ::: "memory"); }
    __builtin_amdgcn_s_barrier();
    bf16x8 af[4], bfr[4];
#pragma unroll
    for (int m = 0; m < 4; m++)
      af[m] = *(const bf16x8*)(AS256(b) + (wr * 64 + m * 16 + l15) * 32 + slot * 8);
#pragma unroll
    for (int n = 0; n < 4; n++)
      bfr[n] = *(const bf16x8*)(BS256(b) + (wc * 64 + n * 16 + l15) * 32 + slot * 8);
    __builtin_amdgcn_s_setprio(1);
#pragma unroll
    for (int m = 0; m < 4; m++)
#pragma unroll
      for (int n = 0; n < 4; n++)
        acc[m][n] = mfma16(af[m], bfr[n], acc[m][n]);
    __builtin_amdgcn_s_setprio(0);
    if (t + 3 < NT) STAGE256((t + 3) & 3, (t + 3) * 32);
  }
  // ---- epilogue: LDS-coalesced C write (XOR-swizzled) ----
  __syncthreads();
  bf16* dst; int ldc, bnl;
  if (bn < 3072) { dst = C0; ldc = 3072; bnl = bn; }
  else           { dst = C1; ldc = 1536; bnl = bn - 3072; }
  bf16* cw = lds + w * 4096;   // per-wave 64x64 region
#pragma unroll
  for (int m = 0; m < 4; m++)
#pragma unroll
    for (int n = 0; n < 4; n++)
#pragma unroll
      for (int i = 0; i < 4; i++) {
        int row_l = m * 16 + lq * 4 + i;
        int col_l = n * 16 + l15;
        cw[row_l * 64 + (col_l ^ ((row_l & 7) << 3))] = __float2bfloat16(acc[m][n][i]);
      }
  __syncthreads();
  int r8 = lane >> 3, cblk = lane & 7;
#pragma unroll
  for (int it = 0; it < 8; it++) {
    int row_l = it * 8 + r8;
    int sblk = cblk ^ (row_l & 7);
    bf16x8 val = *(const bf16x8*)&cw[row_l * 64 + sblk * 8];
    *(bf16x8*)&dst[(size_t)(bm + wr * 64 + row_l) * ldc + bnl + wc * 64 + cblk * 8] = val;
  }
}

// ---------------- fused MLP gate+up GEMM: act = silu(A@Wg) * (A@Wu) ----------------
// Grid 768 = 24 bx (128-col act panels) x 32 by (256-row panels), XCD-swizzled.
// Bt rows 0..3071 = gate_w^T, rows 3072..6143 = up_w^T (contiguous in WB).
// 1024 threads, per-wave 64x32 dual acc. 2 glds16/thread/tile (A 256 rows, B 256 rows).
#define AMS(bi) (lds + (bi) * 8192)
#define BMS(bi) (lds + 32768 + (bi) * 8192)
#define STAGEML(bi, k0) do { \
    glds16(gA0 + (k0), AMS(bi) + w * 512); \
    glds16(gB0 + (k0), BMS(bi) + w * 512); \
  } while (0)

__global__ __launch_bounds__(1024) void gemm_mlp(
    const bf16* __restrict__ A, const bf16* __restrict__ Bt,
    bf16* __restrict__ C, int K) {
  __shared__ bf16 lds[65536];
  int bid = blockIdx.x;
  int sw = (bid & 7) * 96 + (bid >> 3);     // bijective (768 blocks)
  int by = sw & 31, bx = sw >> 5;           // bx 0..23, by 0..31
  int bm = by * 256, bn = bx * 128;
  int tid = threadIdx.x;
  int lane = tid & 63, w = tid >> 6;
  int l15 = lane & 15, lq = lane >> 4;
  int wr = w >> 2, wc = w & 3;              // per-wave 64 rows x 32 cols
  int r0 = tid >> 2;                        // 0..255
  int srcq = (tid & 3) ^ ((r0 >> 1) & 3);
  const bf16* gA0 = A + (size_t)(bm + r0) * K + srcq * 8;
  int growB = bn + (r0 & 127) + (r0 >> 7) * 3072;   // gate rows then up rows
  const bf16* gB0 = Bt + (size_t)growB * K + srcq * 8;
  int slot = lq ^ ((l15 >> 1) & 3);
  f32x4 accg[4][2], accu[4][2];
#pragma unroll
  for (int m = 0; m < 4; m++)
#pragma unroll
    for (int n = 0; n < 2; n++) {
      accg[m][n] = (f32x4){0.f, 0.f, 0.f, 0.f};
      accu[m][n] = (f32x4){0.f, 0.f, 0.f, 0.f};
    }
  int NT = K >> 5;
  STAGEML(0, 0);
  STAGEML(1, 32);
  STAGEML(2, 64);
  for (int t = 0; t < NT; ++t) {
    int b = t & 3;
    if (t <= NT - 3)      { asm volatile("s_waitcnt vmcnt(4)" ::: "memory"); }
    else if (t == NT - 2) { asm volatile("s_waitcnt vmcnt(2)" ::: "memory"); }
    else                  { asm volatile("s_waitcnt vmcnt(0)" ::: "memory"); }
    __builtin_amdgcn_s_barrier();
    bf16x8 af[4], bg[2], bu[2];
#pragma unroll
    for (int m = 0; m < 4; m++)
      af[m] = *(const bf16x8*)(AMS(b) + (wr * 64 + m * 16 + l15) * 32 + slot * 8);
#pragma unroll
    for (int n = 0; n < 2; n++) {
      bg[n] = *(const bf16x8*)(BMS(b) + (wc * 32 + n * 16 + l15) * 32 + slot * 8);
      bu[n] = *(const bf16x8*)(BMS(b) + (128 + wc * 32 + n * 16 + l15) * 32 + slot * 8);
    }
    __builtin_amdgcn_s_setprio(1);
#pragma unroll
    for (int m = 0; m < 4; m++)
#pragma unroll
      for (int n = 0; n < 2; n++) {
        accg[m][n] = mfma16(af[m], bg[n], accg[m][n]);
        accu[m][n] = mfma16(af[m], bu[n], accu[m][n]);
      }
    __builtin_amdgcn_s_setprio(0);
    if (t + 3 < NT) STAGEML((t + 3) & 3, (t + 3) * 32);
  }
  // ---- epilogue: act = silu(g)*u, LDS-coalesced ----
  __syncthreads();
  bf16* cw = lds + w * 2048;   // per-wave 64x32 region
#pragma unroll
  for (int m = 0; m < 4; m++)
#pragma unroll
    for (int n = 0; n < 2; n++)
#pragma unroll
      for (int i = 0; i < 4; i++) {
        int row_l = m * 16 + lq * 4 + i;
        int col_l = n * 16 + l15;
        float v = siluf(accg[m][n][i]) * accu[m][n][i];
        cw[row_l * 32 + (col_l ^ ((row_l & 3) << 3))] = __float2bfloat16(v);
      }
  __syncthreads();
  int r16 = lane >> 2, cblk = lane & 3;
#pragma unroll
  for (int it = 0; it < 4; it++) {   // 4 iters x 64 lanes x 8 bf16 = 2048 (full 64x32)
    int row_l = it * 16 + r16;
    int sblk = cblk ^ (row_l & 3);
    bf16x8 val = *(const bf16x8*)&cw[row_l * 32 + sblk * 8];
    *(bf16x8*)&C[(size_t)(bm + wr * 64 + row_l) * 3072 + bn + wc * 32 + cblk * 8] = val;
  }
}

// ---------------- 128x128 16-wave MFMA GEMM, 4-buffer counted-vmcnt pipeline ----------------
// 1024 threads. Per-wave 32x32 (acc[2][2]). A staged by waves 0-7, B by waves 8-15.
// mode 0: fp32 out (+res). mode 3: bf16 acc. K>=96.
__global__ __launch_bounds__(1024) void gemm_mfma(
    const bf16* __restrict__ A, const bf16* __restrict__ Bt,
    void* __restrict__ Cv, const float* __restrict__ res,
    int N, int K, int ldc, int mode) {
  __shared__ bf16 As[4][4096];
  __shared__ bf16 Bs[4][4096];
  int tid = threadIdx.x, lane = tid & 63, w = tid >> 6;   // w in 0..15
  int bm = blockIdx.y * 128, bn = blockIdx.x * 128;
  int l15 = lane & 15, lq = lane >> 4;
  int wr = w >> 2, wc = w & 3;              // per-wave 32x32
  int r0 = (tid & 511) >> 2;                // 0..127
  int sq = (tid & 3) ^ ((r0 >> 1) & 3);
  const bf16* g0;
  bf16* lb;
  if (w < 8) {
    g0 = A + (size_t)(bm + r0) * K + sq * 8;
    lb = &As[0][w * 512];
  } else {
    int br = bn + r0; if (br >= N) br = 0;
    g0 = Bt + (size_t)br * K + sq * 8;
    lb = &Bs[0][(w - 8) * 512];
  }
#define STAGE128X(bi, k0) glds16(g0 + (k0), lb + (bi) * 4096)
  int slot = lq ^ ((l15 >> 1) & 3);
  f32x4 acc[2][2];
#pragma unroll
  for (int m = 0; m < 2; m++)
#pragma unroll
    for (int n = 0; n < 2; n++) acc[m][n] = (f32x4){0.f, 0.f, 0.f, 0.f};
  int NT = K >> 5;
  STAGE128X(0, 0);
  STAGE128X(1, 32);
  STAGE128X(2, 64);
  for (int t = 0; t < NT; ++t) {
    int b = t & 3;
    if (t <= NT - 3)      { asm volatile("s_waitcnt vmcnt(2)" ::: "memory"); }
    else if (t == NT - 2) { asm volatile("s_waitcnt vmcnt(1)" ::: "memory"); }
    else                  { asm volatile("s_waitcnt vmcnt(0)" ::: "memory"); }
    __builtin_amdgcn_s_barrier();
    bf16x8 af[2], bfr[2];
#pragma unroll
    for (int m = 0; m < 2; m++)
      af[m] = *(const bf16x8*)&As[b][(wr * 32 + m * 16 + l15) * 32 + slot * 8];
#pragma unroll
    for (int n = 0; n < 2; n++)
      bfr[n] = *(const bf16x8*)&Bs[b][(wc * 32 + n * 16 + l15) * 32 + slot * 8];
    __builtin_amdgcn_s_setprio(1);
#pragma unroll
    for (int m = 0; m < 2; m++)
#pragma unroll
      for (int n = 0; n < 2; n++)
        acc[m][n] = mfma16(af[m], bfr[n], acc[m][n]);
    __builtin_amdgcn_s_setprio(0);
    if (t + 3 < NT) STAGE128X((t + 3) & 3, (t + 3) * 32);
  }
#pragma unroll
  for (int m = 0; m < 2; m++) {
#pragma unroll
    for (int n = 0; n < 2; n++) {
      int col = bn + wc * 32 + n * 16 + l15;
      if (col >= N) continue;
#pragma unroll
      for (int i = 0; i < 4; i++) {
        int row = bm + wr * 32 + m * 16 + lq * 4 + i;
        float v = acc[m][n][i];
        size_t idx = (size_t)row * ldc + col;
        if (mode == 0) {
          if (res) v += res[idx];
          ((float*)Cv)[idx] = v;
        } else {
          ((bf16*)Cv)[idx] = __float2bfloat16(v);
        }
      }
    }
  }
}

// ---------------- Parallel causal conv (K=4) + silu ----------------
__global__ __launch_bounds__(256) void convsilu2_k(const bf16* __restrict__ in,
                                                   bf16* __restrict__ outp,
                                                   const float* __restrict__ wq,
                                                   const float* __restrict__ wk,
                                                   const float* __restrict__ wv) {
  int tx = threadIdx.x & 31;
  int ty = threadIdx.x >> 5;
  int c = (blockIdx.x * 32 + tx) * 8;
  int gt = blockIdx.y * 8 + ty;
  int b = gt >> 11, t = gt & (Tn - 1);
  const float* wsrc = (c < HDK) ? (wq + c * 4)
                     : (c < 2 * HDK) ? (wk + (c - HDK) * 4)
                                     : (wv + (c - 2 * HDK) * 4);
  float4 W[8];
#pragma unroll
  for (int j = 0; j < 8; j++) W[j] = ((const float4*)wsrc)[j];
  const bf16* base = in + (size_t)b * Tn * QKVC + c;
  bf16x8 r[4];
  bf16x8 zero = {0, 0, 0, 0, 0, 0, 0, 0};
#pragma unroll
  for (int j = 0; j < 4; j++) {
    int tt = t - 3 + j;
    r[j] = (tt >= 0) ? *(const bf16x8*)(base + (size_t)tt * QKVC) : zero;
  }
  bf16x8 o;
#pragma unroll
  for (int ch = 0; ch < 8; ch++) {
    float x0 = b2f(r[0][ch]), x1 = b2f(r[1][ch]), x2 = b2f(r[2][ch]), x3 = b2f(r[3][ch]);
    float y = x0 * W[ch].x + x1 * W[ch].y + x2 * W[ch].z + x3 * W[ch].w;
    o[ch] = f2b(siluf(y));
  }
  *(bf16x8*)(outp + (size_t)gt * QKVC + c) = o;
}

// ---------------- l2norm: thread-per-48-elem head row, vectorized ----------------
__global__ __launch_bounds__(256) void l2norm_k(bf16* __restrict__ qkv) {
  int row = blockIdx.x * 256 + threadIdx.x;   // 0 .. BT*32-1
  int t = row >> 5, hr = row & 31;
  bf16* p = qkv + (size_t)t * QKVC + hr * DKn;
  bf16x8 v[6];
  float ss = 0.f;
#pragma unroll
  for (int j = 0; j < 6; j++) {
    v[j] = *(const bf16x8*)(p + j * 8);
#pragma unroll
    for (int e = 0; e < 8; e++) { float f = b2f(v[j][e]); ss += f * f; }
  }
  float rs = rsqrtf(ss + 1e-6f);
#pragma unroll
  for (int j = 0; j < 6; j++) {
    bf16x8 o;
#pragma unroll
    for (int e = 0; e < 8; e++) o[e] = f2b(b2f(v[j][e]) * rs);
    *(bf16x8*)(p + j * 8) = o;
  }
}

// ---------------- beta/g transform ----------------
__global__ void betag_k(float* __restrict__ ba, const float* __restrict__ A_log,
                        const float* __restrict__ dt_bias) {
  int i = blockIdx.x * blockDim.x + threadIdx.x;
  int h = i & 15, r = i >> 4;
  float bv = ba[(size_t)r * 32 + h];
  float av = ba[(size_t)r * 32 + 16 + h];
  ba[(size_t)r * 32 + h] = sigmoidf_(bv);
  float xx = av + dt_bias[h];
  float sp = (xx > 20.f) ? xx : log1pf(__expf(xx));
  ba[(size_t)r * 32 + 16 + h] = -__expf(A_log[h]) * sp;
}

// ---------------- Fused P1+P2a: WY precompute + affine coefficients ----------------
__global__ __launch_bounds__(256) void dn_p1a(const bf16* __restrict__ qkv,
                                              const float* __restrict__ ba,
                                              float* __restrict__ Gc_g,
                                              bf16* __restrict__ T_g,
                                              bf16* __restrict__ Uv_g,
                                              bf16* __restrict__ A_g,
                                              bf16* __restrict__ B_g) {
  __shared__ __align__(16) char smem[62976];
  bf16 (*Kl)[72]   = (bf16(*)[72])(smem);                 //  9216 B
  bf16 (*Tl)[72]   = (bf16(*)[72])(smem + 9216);          //  9216 B
  bf16 (*UvdT)[72] = (bf16(*)[72])(smem + 18432);         // 13824 B
  float* Gcl = (float*)(smem + 32256);
  float* Bl  = (float*)(smem + 32512);
  bf16 (*Vl)[100]  = (bf16(*)[100])(smem + 32768);
  float (*Nl)[68]  = (float(*)[68])(smem + 45568);
  bf16 (*KTl)[72]  = (bf16(*)[72])(smem + 32768);
  bf16 (*KTbl)[72] = (bf16(*)[72])(smem + 39680);
  bf16 (*M2T)[72]  = (bf16(*)[72])(smem + 46592);
  int cid = blockIdx.x;
  int nc = cid & (NC - 1);
  int bh = cid >> 5;
  int h = bh & 15, b = bh >> 4;
  int t0 = nc * CC;
  int tid = threadIdx.x, lane = tid & 63, w = tid >> 6;
  int l15 = lane & 15, qd = lane >> 4;
  bf16 zb = __float2bfloat16(0.f);
  {
    int t = tid >> 2, p = tid & 3;
    const bf16* row = qkv + ((size_t)(b * Tn + t0 + t)) * QKVC;
    int c0 = p * 12;
#pragma unroll
    for (int j = 0; j < 12; ++j) Kl[t][c0 + j] = row[HDK + h * DKn + c0 + j];
    int j0 = p * 24;
#pragma unroll
    for (int j = 0; j < 24; ++j) Vl[t][j0 + j] = row[2 * HDK + h * DVn + j0 + j];
  }
  for (int i = tid; i < 64 * 24; i += 256) {
    int t = i / 24, c = 48 + (i % 24);
    Kl[t][c] = zb;
  }
  if (tid < 64) {
    size_t row = (size_t)(b * Tn + t0 + tid);
    float g = ba[row * 32 + 16 + h];
    float be = ba[row * 32 + h];
    float acc = g;
#pragma unroll
    for (int d = 1; d < 64; d <<= 1) {
      float o = __shfl_up(acc, d);
      if (tid >= d) acc += o;
    }
    Gcl[tid] = acc; Bl[tid] = be;
    Gc_g[(size_t)bh * Tn + t0 + tid] = acc;
  }
  __syncthreads();
  f32x4 dacc[4];
#pragma unroll
  for (int n = 0; n < 4; n++) dacc[n] = (f32x4){0.f, 0.f, 0.f, 0.f};
  {
    int arow = w * 16 + l15;
    bf16x8 a0 = *(const bf16x8*)&Kl[arow][qd * 8];
    bf16x8 a1 = *(const bf16x8*)&Kl[arow][32 + qd * 8];
#pragma unroll
    for (int n = 0; n < 4; n++) {
      int brow = n * 16 + l15;
      bf16x8 b0 = *(const bf16x8*)&Kl[brow][qd * 8];
      bf16x8 b1 = *(const bf16x8*)&Kl[brow][32 + qd * 8];
      dacc[n] = mfma16(a0, b0, dacc[n]);
      dacc[n] = mfma16(a1, b1, dacc[n]);
    }
  }
#pragma unroll
  for (int i = 0; i < 4; i++) {
    int t = w * 16 + qd * 4 + i;
    float bt = Bl[t], gt = Gcl[t];
#pragma unroll
    for (int n = 0; n < 4; n++) {
      int s = n * 16 + l15;
      Nl[t][s] = (s < t) ? bt * __expf(gt - Gcl[s]) * dacc[n][i] : 0.f;
    }
  }
  __syncthreads();
  float g63 = Gcl[63];
  int c = tid;
  if (c < 160) {
    float R[64];
    if (c < 64) {
#pragma unroll
      for (int t = 0; t < 64; ++t) R[t] = (t == c) ? 1.f : 0.f;
    } else {
      int j = c - 64;
#pragma unroll
      for (int t = 0; t < 64; ++t) R[t] = Bl[t] * __bfloat162float(Vl[t][j]);
    }
#pragma unroll
    for (int t = 1; t < 64; ++t) {
      float a0 = 0.f, a1 = 0.f, a2 = 0.f, a3 = 0.f;
#pragma unroll
      for (int s = 0; s + 3 < t; s += 4) {
        float4 n4 = *(const float4*)&Nl[t][s];
        a0 += n4.x * R[s]; a1 += n4.y * R[s + 1];
        a2 += n4.z * R[s + 2]; a3 += n4.w * R[s + 3];
      }
#pragma unroll
      for (int s = t & ~3; s < t; ++s) a0 += Nl[t][s] * R[s];
      R[t] -= ((a0 + a1) + (a2 + a3));
    }
    if (c < 64) {
#pragma unroll
      for (int t = 0; t < 64; ++t) {
        bf16 v = __float2bfloat16(R[t]);
        T_g[(size_t)cid * 4096 + t * 64 + c] = v;
        Tl[t][c] = v;
      }
    } else {
      int j = c - 64;
#pragma unroll
      for (int t = 0; t < 64; ++t) {
        Uv_g[(size_t)cid * 6144 + t * 96 + j] = __float2bfloat16(R[t]);
        UvdT[j][t] = __float2bfloat16(R[t] * __expf(g63 - Gcl[t]));
      }
    }
  }
  __syncthreads();
  for (int i = tid; i < 48 * 64; i += 256) {
    int dk = i >> 6, t = i & 63;
    bf16 kv = Kl[t][dk];
    KTl[dk][t] = kv;
    float bl = Bl[t] * __expf(Gcl[t]);
    KTbl[dk][t] = __float2bfloat16(__bfloat162float(kv) * bl);
  }
  __syncthreads();
  f32x4 m1[3];
#pragma unroll
  for (int n = 0; n < 3; n++) m1[n] = (f32x4){0.f, 0.f, 0.f, 0.f};
  {
    int arow = w * 16 + l15;
    bf16x8 a0 = *(const bf16x8*)&Tl[arow][qd * 8];
    bf16x8 a1 = *(const bf16x8*)&Tl[arow][32 + qd * 8];
#pragma unroll
    for (int n = 0; n < 3; n++) {
      int brow = n * 16 + l15;
      bf16x8 b0 = *(const bf16x8*)&KTbl[brow][qd * 8];
      bf16x8 b1 = *(const bf16x8*)&KTbl[brow][32 + qd * 8];
      m1[n] = mfma16(a0, b0, m1[n]);
      m1[n] = mfma16(a1, b1, m1[n]);
    }
  }
#pragma unroll
  for (int i = 0; i < 4; i++) {
    int tt = w * 16 + qd * 4 + i;
    float dd = __expf(g63 - Gcl[tt]);
#pragma unroll
    for (int n = 0; n < 3; n++) {
      int dk = n * 16 + l15;
      M2T[dk][tt] = __float2bfloat16(m1[n][i] * dd);
    }
  }
  __syncthreads();
  float lamC = __expf(g63);
#pragma unroll
  for (int tswap = 0; tswap < 7; tswap++) {
    int t = w + 4 * tswap;
    if (t >= 27) break;
    int mi, ni; bool isA;
    if (t < 9) { isA = true; mi = t / 3; ni = t % 3; }
    else { isA = false; mi = (t - 9) / 6; ni = (t - 9) % 6; }
    f32x4 acc = (f32x4){0.f, 0.f, 0.f, 0.f};
    int arow = mi * 16 + l15;
    bf16x8 a0 = *(const bf16x8*)&KTl[arow][qd * 8];
    bf16x8 a1 = *(const bf16x8*)&KTl[arow][32 + qd * 8];
    int brow = ni * 16 + l15;
    if (isA) {
      bf16x8 b0 = *(const bf16x8*)&M2T[brow][qd * 8];
      bf16x8 b1 = *(const bf16x8*)&M2T[brow][32 + qd * 8];
      acc = mfma16(a0, b0, acc);
      acc = mfma16(a1, b1, acc);
#pragma unroll
      for (int i = 0; i < 4; i++) {
        int row = mi * 16 + qd * 4 + i, colv = ni * 16 + l15;
        float v = ((row == colv) ? lamC : 0.f) - acc[i];
        A_g[(size_t)cid * 2304 + row * 48 + colv] = __float2bfloat16(v);
      }
    } else {
      bf16x8 b0 = *(const bf16x8*)&UvdT[brow][qd * 8];
      bf16x8 b1 = *(const bf16x8*)&UvdT[brow][32 + qd * 8];
      acc = mfma16(a0, b0, acc);
      acc = mfma16(a1, b1, acc);
#pragma unroll
      for (int i = 0; i < 4; i++) {
        int row = mi * 16 + qd * 4 + i, colv = ni * 16 + l15;
        B_g[(size_t)cid * 4608 + row * 96 + colv] = __float2bfloat16(acc[i]);
      }
    }
  }
}

// ---------------- P2b: pipelined serial affine scan S' = A S + B ----------------
__global__ __launch_bounds__(256) void dn_p2b(const bf16* __restrict__ A_g,
                                              const bf16* __restrict__ B_g,
                                              bf16* __restrict__ St_g) {
  __shared__ bf16 STl[2][96][72];
  __shared__ bf16 Al[2][48][72];
  __shared__ bf16 Bl[2][4608];
  int bh = blockIdx.x;
  int tid = threadIdx.x, lane = tid & 63, w = tid >> 6;
  int l15 = lane & 15, qd = lane >> 4;
  bf16 zb = __float2bfloat16(0.f);
  for (int i = tid; i < 2 * 96 * 72; i += 256) (&STl[0][0][0])[i] = zb;
  for (int i = tid; i < 2 * 48 * 24; i += 256) {
    int buf = i / (48 * 24), r = (i / 24) % 48, cc = 48 + (i % 24);
    Al[buf][r][cc] = zb;
  }
  bf16x8 ra0, ra1, rb0, rb1;
  unsigned int rb2;
  int e_a0 = tid * 8, e_a1 = 2048 + tid * 8;
  {
    size_t cid = (size_t)bh * NC;
    ra0 = *(const bf16x8*)(A_g + cid * 2304 + e_a0);
    if (tid < 32) ra1 = *(const bf16x8*)(A_g + cid * 2304 + e_a1);
    rb0 = *(const bf16x8*)(B_g + cid * 4608 + tid * 16);
    rb1 = *(const bf16x8*)(B_g + cid * 4608 + tid * 16 + 8);
    rb2 = *(const unsigned int*)(B_g + cid * 4608 + 4096 + tid * 2);
  }
  *(bf16x8*)&Al[0][e_a0 / 48][e_a0 % 48] = ra0;
  if (tid < 32) *(bf16x8*)&Al[0][e_a1 / 48][e_a1 % 48] = ra1;
  *(bf16x8*)&Bl[0][tid * 16] = rb0;
  *(bf16x8*)&Bl[0][tid * 16 + 8] = rb1;
  *(unsigned int*)&Bl[0][4096 + tid * 2] = rb2;
  {
    size_t cid = (size_t)bh * NC + 1;
    ra0 = *(const bf16x8*)(A_g + cid * 2304 + e_a0);
    if (tid < 32) ra1 = *(const bf16x8*)(A_g + cid * 2304 + e_a1);
    rb0 = *(const bf16x8*)(B_g + cid * 4608 + tid * 16);
    rb1 = *(const bf16x8*)(B_g + cid * 4608 + tid * 16 + 8);
    rb2 = *(const unsigned int*)(B_g + cid * 4608 + 4096 + tid * 2);
  }
  __syncthreads();

  for (int c = 0; c < NC - 1; ++c) {
    int cur = c & 1, nxt = cur ^ 1;
    size_t cid = (size_t)bh * NC + c;
    {
      int e0 = tid * 8, e1 = 2048 + tid * 8, e2 = 4096 + tid * 2;
      *(bf16x8*)(St_g + cid * 4608 + e0) = *(const bf16x8*)&STl[cur][e0 / 48][e0 % 48];
      *(bf16x8*)(St_g + cid * 4608 + e1) = *(const bf16x8*)&STl[cur][e1 / 48][e1 % 48];
      *(unsigned int*)(St_g + cid * 4608 + e2) = *(const unsigned int*)&STl[cur][e2 / 48][e2 % 48];
    }
    float vals[5][4];
#pragma unroll
    for (int ts = 0; ts < 5; ts++) {
      int t = w + 4 * ts;
      if (t >= 18) break;
      int mi = t / 3, ni = t % 3;
      f32x4 acc = (f32x4){0.f, 0.f, 0.f, 0.f};
      int arow = mi * 16 + l15;
      bf16x8 a0 = *(const bf16x8*)&STl[cur][arow][qd * 8];
      bf16x8 a1 = *(const bf16x8*)&STl[cur][arow][32 + qd * 8];
      int brow = ni * 16 + l15;
      bf16x8 b0 = *(const bf16x8*)&Al[cur][brow][qd * 8];
      bf16x8 b1 = *(const bf16x8*)&Al[cur][brow][32 + qd * 8];
      acc = mfma16(a0, b0, acc);
      acc = mfma16(a1, b1, acc);
#pragma unroll
      for (int i = 0; i < 4; i++) {
        int dv = mi * 16 + qd * 4 + i, ii = ni * 16 + l15;
        vals[ts][i] = acc[i] + __bfloat162float(Bl[cur][ii * 96 + dv]);
      }
    }
#pragma unroll
    for (int ts = 0; ts < 5; ts++) {
      int t = w + 4 * ts;
      if (t >= 18) break;
      int mi = t / 3, ni = t % 3;
#pragma unroll
      for (int i = 0; i < 4; i++) {
        int dv = mi * 16 + qd * 4 + i, ii = ni * 16 + l15;
        STl[nxt][dv][ii] = __float2bfloat16(vals[ts][i]);
      }
    }
    if (c + 1 <= NC - 2) {
      *(bf16x8*)&Al[nxt][e_a0 / 48][e_a0 % 48] = ra0;
      if (tid < 32) *(bf16x8*)&Al[nxt][e_a1 / 48][e_a1 % 48] = ra1;
      *(bf16x8*)&Bl[nxt][tid * 16] = rb0;
      *(bf16x8*)&Bl[nxt][tid * 16 + 8] = rb1;
      *(unsigned int*)&Bl[nxt][4096 + tid * 2] = rb2;
      if (c + 2 <= NC - 2) {
        size_t cid2 = (size_t)bh * NC + c + 2;
        ra0 = *(const bf16x8*)(A_g + cid2 * 2304 + e_a0);
        if (tid < 32) ra1 = *(const bf16x8*)(A_g + cid2 * 2304 + e_a1);
        rb0 = *(const bf16x8*)(B_g + cid2 * 4608 + tid * 16);
        rb1 = *(const bf16x8*)(B_g + cid2 * 4608 + tid * 16 + 8);
        rb2 = *(const unsigned int*)(B_g + cid2 * 4608 + 4096 + tid * 2);
      }
    }
    __syncthreads();
  }
  {
    size_t cid = (size_t)bh * NC + (NC - 1);
    int cur = (NC - 1) & 1;
    int e0 = tid * 8, e1 = 2048 + tid * 8, e2 = 4096 + tid * 2;
    *(bf16x8*)(St_g + cid * 4608 + e0) = *(const bf16x8*)&STl[cur][e0 / 48][e0 % 48];
    *(bf16x8*)(St_g + cid * 4608 + e1) = *(const bf16x8*)&STl[cur][e1 / 48][e1 % 48];
    *(unsigned int*)(St_g + cid * 4608 + e2) = *(const unsigned int*)&STl[cur][e2 / 48][e2 % 48];
  }
}

// ---------------- P2c: per-chunk output + fused gated RMSNorm ----------------
__global__ __launch_bounds__(256) void dn_p2c(const bf16* __restrict__ qkv,
                                              const float* __restrict__ ba,
                                              const float* __restrict__ Gc_g,
                                              const bf16* __restrict__ T_g,
                                              const bf16* __restrict__ Uv_g,
                                              const bf16* __restrict__ St_g,
                                              const bf16* __restrict__ gate,
                                              const float* __restrict__ onw,
                                              bf16* __restrict__ attn) {
  __shared__ bf16 Kl[64][72], Ql[64][72], Tl[64][72], Ml[64][72];
  __shared__ bf16 G1T[96][72], UT[96][72], STb[96][72];
  __shared__ float Gcl[64], Bl[64];
  __shared__ float onwl[96];
  int cid = blockIdx.x;
  int nc = cid & (NC - 1);
  int bh = cid >> 5;
  int h = bh & 15, b = bh >> 4;
  int t0 = nc * CC;
  int tid = threadIdx.x, lane = tid & 63, w = tid >> 6;
  int l15 = lane & 15, qd = lane >> 4;
  const float scale = 0.14433756729740643f;  // 48^-0.5
  bf16 zb = __float2bfloat16(0.f);
  {
    int t = tid >> 2, p = tid & 3;
    size_t grow = (size_t)(b * Tn + t0 + t);
    const bf16* row = qkv + grow * QKVC;
    int c0 = p * 12;
#pragma unroll
    for (int j = 0; j < 12; ++j) {
      int cc = c0 + j;
      Kl[t][cc] = row[HDK + h * DKn + cc];
      Ql[t][cc] = __float2bfloat16(__bfloat162float(row[h * DKn + cc]) * scale);
    }
    if (p == 0) { Gcl[t] = Gc_g[(size_t)bh * Tn + t0 + t]; Bl[t] = ba[grow * 32 + h]; }
  }
  if (tid < 96) onwl[tid] = onw[tid];
  for (int i = tid; i < 64 * 16; i += 256) {
    int t = i >> 4, cc = 48 + (i & 15);
    Kl[t][cc] = zb; Ql[t][cc] = zb;
  }
  for (int i = tid; i < 4096; i += 256)
    (&Tl[0][0])[(i >> 6) * 72 + (i & 63)] = T_g[(size_t)cid * 4096 + i];
  for (int i = tid; i < 4608; i += 256)
    STb[i / 48][i % 48] = St_g[(size_t)cid * 4608 + i];
  for (int i = tid; i < 96 * 16; i += 256)
    STb[i >> 4][48 + (i & 15)] = zb;
  __syncthreads();  // sync1
  f32x4 acc[6];
#pragma unroll
  for (int n = 0; n < 6; n++) acc[n] = (f32x4){0.f, 0.f, 0.f, 0.f};
  {
    int arow = w * 16 + l15;
    bf16x8 a0 = *(const bf16x8*)&Kl[arow][qd * 8];
    bf16x8 a1 = *(const bf16x8*)&Kl[arow][32 + qd * 8];
#pragma unroll
    for (int n = 0; n < 6; n++) {
      int brow = n * 16 + l15;
      bf16x8 b0 = *(const bf16x8*)&STb[brow][qd * 8];
      bf16x8 b1 = *(const bf16x8*)&STb[brow][32 + qd * 8];
      acc[n] = mfma16(a0, b0, acc[n]);
      acc[n] = mfma16(a1, b1, acc[n]);
    }
  }
#pragma unroll
  for (int i = 0; i < 4; i++) {
    int tt = w * 16 + qd * 4 + i;
    float sc = Bl[tt] * __expf(Gcl[tt]);
#pragma unroll
    for (int n = 0; n < 6; n++)
      G1T[n * 16 + l15][tt] = __float2bfloat16(acc[n][i] * sc);
  }
  __syncthreads();  // sync2
#pragma unroll
  for (int n = 0; n < 6; n++) acc[n] = (f32x4){0.f, 0.f, 0.f, 0.f};
  {
    int arow = w * 16 + l15;
    bf16x8 a0 = *(const bf16x8*)&Tl[arow][qd * 8];
    bf16x8 a1 = *(const bf16x8*)&Tl[arow][32 + qd * 8];
#pragma unroll
    for (int n = 0; n < 6; n++) {
      int brow = n * 16 + l15;
      bf16x8 b0 = *(const bf16x8*)&G1T[brow][qd * 8];
      bf16x8 b1 = *(const bf16x8*)&G1T[brow][32 + qd * 8];
      acc[n] = mfma16(a0, b0, acc[n]);
      acc[n] = mfma16(a1, b1, acc[n]);
    }
  }
#pragma unroll
  for (int i = 0; i < 4; i++) {
    int tt = w * 16 + qd * 4 + i;
#pragma unroll
    for (int n = 0; n < 6; n++) {
      int dv = n * 16 + l15;
      float uv = __bfloat162float(Uv_g[(size_t)cid * 6144 + tt * 96 + dv]);
      UT[dv][tt] = __float2bfloat16(uv - acc[n][i]);
    }
  }
  f32x4 qk[4];
#pragma unroll
  for (int n = 0; n < 4; n++) qk[n] = (f32x4){0.f, 0.f, 0.f, 0.f};
  {
    int arow = w * 16 + l15;
    bf16x8 a0 = *(const bf16x8*)&Ql[arow][qd * 8];
    bf16x8 a1 = *(const bf16x8*)&Ql[arow][32 + qd * 8];
#pragma unroll
    for (int n = 0; n < 4; n++) {
      int brow = n * 16 + l15;
      bf16x8 b0 = *(const bf16x8*)&Kl[brow][qd * 8];
      bf16x8 b1 = *(const bf16x8*)&Kl[brow][32 + qd * 8];
      qk[n] = mfma16(a0, b0, qk[n]);
      qk[n] = mfma16(a1, b1, qk[n]);
    }
  }
#pragma unroll
  for (int i = 0; i < 4; i++) {
    int tt = w * 16 + qd * 4 + i;
    float gt = Gcl[tt];
#pragma unroll
    for (int n = 0; n < 4; n++) {
      int ss = n * 16 + l15;
      float m = (ss <= tt) ? qk[n][i] * __expf(gt - Gcl[ss]) : 0.f;
      Ml[tt][ss] = __float2bfloat16(m);
    }
  }
  __syncthreads();  // sync3
#pragma unroll
  for (int n = 0; n < 6; n++) acc[n] = (f32x4){0.f, 0.f, 0.f, 0.f};
  {
    int arow = w * 16 + l15;
    float lam = __expf(Gcl[arow]);
    bf16x8 a0 = scale8(*(const bf16x8*)&Ql[arow][qd * 8], lam);
    bf16x8 a1 = scale8(*(const bf16x8*)&Ql[arow][32 + qd * 8], lam);
    bf16x8 m0 = *(const bf16x8*)&Ml[arow][qd * 8];
    bf16x8 m1 = *(const bf16x8*)&Ml[arow][32 + qd * 8];
#pragma unroll
    for (int n = 0; n < 6; n++) {
      int brow = n * 16 + l15;
      bf16x8 b0 = *(const bf16x8*)&STb[brow][qd * 8];
      bf16x8 b1 = *(const bf16x8*)&STb[brow][32 + qd * 8];
      acc[n] = mfma16(a0, b0, acc[n]);
      acc[n] = mfma16(a1, b1, acc[n]);
      bf16x8 u0 = *(const bf16x8*)&UT[brow][qd * 8];
      bf16x8 u1 = *(const bf16x8*)&UT[brow][32 + qd * 8];
      acc[n] = mfma16(m0, u0, acc[n]);
      acc[n] = mfma16(m1, u1, acc[n]);
    }
  }
  // fused gated RMSNorm: row stats via 16-lane shfl reduce, then write attn
#pragma unroll
  for (int i = 0; i < 4; i++) {
    int tt = w * 16 + qd * 4 + i;
    float ss = 0.f;
#pragma unroll
    for (int n = 0; n < 6; n++) ss += acc[n][i] * acc[n][i];
    ss += __shfl_xor(ss, 1, 64);
    ss += __shfl_xor(ss, 2, 64);
    ss += __shfl_xor(ss, 4, 64);
    ss += __shfl_xor(ss, 8, 64);
    float rs = rsqrtf(ss * (1.f / DVn) + 1e-5f);
    size_t orow = ((size_t)(b * Tn + t0 + tt)) * HDV + h * DVn;
#pragma unroll
    for (int n = 0; n < 6; n++) {
      int dv = n * 16 + l15;
      float g = __bfloat162float(gate[orow + dv]);
      attn[orow + dv] = __float2bfloat16(acc[n][i] * rs * onwl[dv] * siluf(g));
    }
  }
}

extern "C" void kernel_launch(void* const* d_in, const int* in_sizes, int n_in,
                              void* d_out, int out_size, void* d_ws, size_t ws_size,
                              hipStream_t stream) {
  const float* x       = (const float*)d_in[0];
  const float* norm1_w = (const float*)d_in[1];
  const float* q_w     = (const float*)d_in[2];
  const float* k_w     = (const float*)d_in[3];
  const float* v_w     = (const float*)d_in[4];
  const float* cq_w    = (const float*)d_in[5];
  const float* ck_w    = (const float*)d_in[6];
  const float* cv_w    = (const float*)d_in[7];
  const float* b_w     = (const float*)d_in[8];
  const float* a_w     = (const float*)d_in[9];
  const float* A_log   = (const float*)d_in[10];
  const float* dt_bias = (const float*)d_in[11];
  const float* g_w     = (const float*)d_in[12];
  const float* o_norm_w= (const float*)d_in[13];
  const float* o_w     = (const float*)d_in[14];
  const float* norm2_w = (const float*)d_in[15];
  const float* gate_w  = (const float*)d_in[16];
  const float* up_w    = (const float*)d_in[17];
  const float* down_w  = (const float*)d_in[18];
  char* wsb = (char*)d_ws;
  float* out = (float*)d_out;

  bf16*  hbf   = (bf16*)(wsb + WO_HBF);
  bf16*  qkvr  = (bf16*)(wsb + WO_QKVR);
  bf16*  qkvc  = (bf16*)(wsb + WO_QKVC);
  bf16*  attn  = (bf16*)(wsb + WO_OSC);    // attn in old osc slot (no St overlap)
  bf16*  actb  = (bf16*)(wsb + WO_ACT);
  bf16*  gateb = (bf16*)(wsb + WO_GATE);
  float* x1    = (float*)(wsb + WO_X1);
  float* ba    = (float*)(wsb + WO_BA);
  float* Gc    = (float*)(wsb + WO_GC);
  bf16*  Tg    = (bf16*)(wsb + WO_T);
  bf16*  Uvg   = (bf16*)(wsb + WO_UV);
  bf16*  A_g   = (bf16*)(wsb + WO_A);
  bf16*  B_g   = (bf16*)(wsb + WO_B);
  bf16*  St_g  = (bf16*)(wsb + WO_ST);
  bf16*  wb    = (bf16*)(wsb + WO_WB);

  // 0. merged transpose-cast of all 10 weights (one launch)
  {
    TcastArgs ta;
    const float* srcs[10] = {q_w, k_w, v_w, g_w, o_w, gate_w, up_w, down_w, b_w, a_w};
    bf16* dsts[10] = {wb + WB_QKVT, wb + WB_QKVT + 768 * 1024, wb + WB_QKVT + 1536 * 1024,
                      wb + WB_GT, wb + WB_OT, wb + WB_GATET, wb + WB_UPT, wb + WB_DOWNT,
                      wb + WB_ABT, wb + WB_ABT + 16 * 1024};
    int Rs[10] = {1024, 1024, 1024, 1024, 1536, 1024, 1024, 3072, 1024, 1024};
    int Cs[10] = {768, 768, 1536, 1536, 1024, 3072, 3072, 1024, 16, 16};
    int off = 0;
    for (int i = 0; i < 10; i++) {
      ta.src[i] = srcs[i]; ta.dst[i] = dsts[i];
      ta.R[i] = Rs[i]; ta.C[i] = Cs[i];
      ta.gxw[i] = (Cs[i] + 31) / 32;
      ta.t0[i] = off;
      off += ta.gxw[i] * (Rs[i] / 32);
    }
    tcast_all<<<off, dim3(32, 8), 0, stream>>>(ta);
  }

  // 1. h_bf = rmsnorm(x)
  rmsnorm_bf_k<<<BT, 256, 0, stream>>>(x, norm1_w, hbf);
  // 2. fused qkv+gate projection; ba on small kernel
  gemm256<<<576, 1024, 0, stream>>>(hbf, wb + WB_QKVT, qkvr, gateb, 18, 4608, 1024, 10);
  gemm_mfma<<<dim3(1, 64), 1024, 0, stream>>>(hbf, wb + WB_ABT, ba, nullptr, 32, 1024, 32, 0);
  // 3. conv+silu, l2norm, beta/g
  convsilu2_k<<<dim3(QKVC / 256, BT / 8), 256, 0, stream>>>(qkvr, qkvc, cq_w, ck_w, cv_w);
  l2norm_k<<<(BT * 32) / 256, 256, 0, stream>>>(qkvc);
  betag_k<<<(BT * Hn) / 256, 256, 0, stream>>>(ba, A_log, dt_bias);
  // 4. chunked gated delta rule (fused WY+affine -> scan -> fused output+gatednorm)
  dn_p1a<<<Bn * Hn * NC, 256, 0, stream>>>(qkvc, ba, Gc, Tg, Uvg, A_g, B_g);
  dn_p2b<<<Bn * Hn, 256, 0, stream>>>(A_g, B_g, St_g);
  dn_p2c<<<Bn * Hn * NC, 256, 0, stream>>>(qkvc, ba, Gc, Tg, Uvg, St_g, gateb, o_norm_w, attn);
  // 5. x1 = x + attn @ o_w
  gemm_mfma<<<dim3(8, 64), 1024, 0, stream>>>(attn, wb + WB_OT, x1, x, 1024, 1536, 1024, 0);
  // 6. h2 = rmsnorm(x1)
  rmsnorm_bf_k<<<BT, 256, 0, stream>>>(x1, norm2_w, hbf);
  // 7. fused MLP: act = silu(h2@gate_w) * (h2@up_w) in ONE kernel (no up buffer, no silumul)
  gemm_mlp<<<768, 1024, 0, stream>>>(hbf, wb + WB_GATET, actb, 1024);
  // 8. out = x1 + act @ down_w
  gemm_mfma<<<dim3(8, 64), 1024, 0, stream>>>(actb, wb + WB_DOWNT, out, x1, 1024, 3072, 1024, 0);
}

// Round 19
// 587.459 us; speedup vs baseline: 1.2301x; 1.0488x over previous
//
#include <hip/hip_runtime.h>
#include <hip/hip_bf16.h>
#include <math.h>

// Problem constants
constexpr int Bn = 4, Tn = 2048, Dn = 1024, Hn = 16, DKn = 48, DVn = 96, In = 3072;
constexpr int BT = Bn * Tn;               // 8192
constexpr int HDK = Hn * DKn;             // 768
constexpr int HDV = Hn * DVn;             // 1536
constexpr int QKVC = 2 * HDK + HDV;       // 3072
constexpr int CC = 64;                    // chunk length
constexpr int NC = Tn / CC;               // 32 chunks per (b,h)

using bf16 = __hip_bfloat16;
typedef __attribute__((ext_vector_type(8))) short bf16x8;
typedef __attribute__((ext_vector_type(4))) float f32x4;

// ---- Workspace layout (byte offsets) ----
constexpr size_t WO_HBF   = 0;              // h/h2 bf16 [8192][1024]     16 MB
constexpr size_t WO_QKVR  = 16777216;       // raw qkv 48MB; then A/B; then attn; then act
constexpr size_t WO_OSC   = 16777216;       // attn bf16 [8192][1536] (ends 41.9MB < St 45.1MB)
constexpr size_t WO_ACT   = 16777216;       // mlp act bf16 [8192][3072]
constexpr size_t WO_A     = 16777216;       // A bf16 [2048][48][48]  9.4 MB
constexpr size_t WO_B     = 26214400;       // B bf16 [2048][48][96]  18.9 MB (ends 45.1MB)
constexpr size_t WO_ST    = 45088768;       // St bf16 [2048][96][48] 18.9 MB (ends 64.0MB)
constexpr size_t WO_QKVC  = 67108864;       // conv'd qkv bf16 [8192][3072] 48 MB
constexpr size_t WO_GATE  = 117440512;      // gate bf16 [8192][1536]     24 MB
constexpr size_t WO_X1    = 142606336;      // x1 fp32 [8192][1024]       32 MB
constexpr size_t WO_BA    = 176160768;      // ba fp32 [8192][32]         1 MB
constexpr size_t WO_GC    = 177209344;      // Gc fp32 [64][2048]         0.5 MB
constexpr size_t WO_T     = 177733632;      // T bf16 [2048][64][64]      16.8 MB
constexpr size_t WO_UV    = 194510848;      // Uv bf16 [2048][64][96]     25.2 MB
constexpr size_t WO_WB    = 219676672;      // bf16 weights ~31.5 MB
// bf16-element offsets inside WB:
constexpr size_t WB_QKVT = 0;              // [3072][1024]  (+GT contiguous => [4608][1024])
constexpr size_t WB_GT   = 3145728;        // [1536][1024]
constexpr size_t WB_OT   = 4718592;        // [1024][1536]
constexpr size_t WB_GATET= 6291456;        // [3072][1024]  (+UPT contiguous => [6144][1024])
constexpr size_t WB_UPT  = 9437184;        // [3072][1024]
constexpr size_t WB_DOWNT= 12582912;       // [1024][3072]
constexpr size_t WB_ABT  = 15728640;       // [32][1024]

__device__ __forceinline__ float sigmoidf_(float x) { return 1.f / (1.f + __expf(-x)); }
__device__ __forceinline__ float siluf(float x) { return x * sigmoidf_(x); }

__device__ __forceinline__ void glds16(const void* g, void* l) {
  __builtin_amdgcn_global_load_lds((const __attribute__((address_space(1))) void*)g,
                                   (__attribute__((address_space(3))) void*)l, 16, 0, 0);
}

__device__ __forceinline__ f32x4 mfma16(bf16x8 a, bf16x8 b, f32x4 c) {
  return __builtin_amdgcn_mfma_f32_16x16x32_bf16(a, b, c, 0, 0, 0);
}

__device__ __forceinline__ bf16x8 scale8(bf16x8 a, float s) {
  bf16x8 r;
#pragma unroll
  for (int e = 0; e < 8; e++) {
    float f = __bfloat162float(__ushort_as_bfloat16((unsigned short)a[e])) * s;
    r[e] = (short)__bfloat16_as_ushort(__float2bfloat16(f));
  }
  return r;
}

__device__ __forceinline__ float b2f(short u) {
  return __bfloat162float(__ushort_as_bfloat16((unsigned short)u));
}
__device__ __forceinline__ short f2b(float f) {
  return (short)__bfloat16_as_ushort(__float2bfloat16(f));
}

// ---------------- merged transpose-cast: 10 weights in one launch ----------------
struct TcastArgs {
  const float* src[10];
  bf16* dst[10];
  int R[10], C[10], gxw[10], t0[10];
};

__global__ void tcast_all(TcastArgs a) {
  __shared__ float t[32][33];
  int bid = blockIdx.x;
  int i = 0;
#pragma unroll
  for (int k = 1; k < 10; k++) if (bid >= a.t0[k]) i = k;
  int lt = bid - a.t0[i];
  int gxw = a.gxw[i];
  int bx = lt % gxw, by = lt / gxw;
  const float* in = a.src[i];
  bf16* out = a.dst[i];
  int R = a.R[i], C = a.C[i];
  int tx = threadIdx.x, ty = threadIdx.y;
  int c0 = bx * 32, r0 = by * 32;
#pragma unroll
  for (int j = 0; j < 4; j++) {
    int r = ty + j * 8;
    float v = (c0 + tx < C) ? in[(size_t)(r0 + r) * C + c0 + tx] : 0.f;
    t[r][tx] = v;
  }
  __syncthreads();
#pragma unroll
  for (int j = 0; j < 4; j++) {
    int cc = ty + j * 8;
    if (c0 + cc < C) out[(size_t)(c0 + cc) * R + r0 + tx] = __float2bfloat16(t[tx][cc]);
  }
}

// ---------------- RMSNorm -> bf16 out ----------------
__global__ void rmsnorm_bf_k(const float* __restrict__ x, const float* __restrict__ w,
                             bf16* __restrict__ y) {
  int row = blockIdx.x;
  const float4* xr = (const float4*)(x + (size_t)row * Dn);
  int tid = threadIdx.x;
  float4 v = xr[tid];
  float ss = v.x * v.x + v.y * v.y + v.z * v.z + v.w * v.w;
  for (int m = 32; m >= 1; m >>= 1) ss += __shfl_xor(ss, m, 64);
  __shared__ float wsum[4];
  if ((tid & 63) == 0) wsum[tid >> 6] = ss;
  __syncthreads();
  ss = wsum[0] + wsum[1] + wsum[2] + wsum[3];
  float rs = rsqrtf(ss * (1.f / Dn) + 1e-5f);
  float4 wv = ((const float4*)w)[tid];
  bf16* yr = y + (size_t)row * Dn + tid * 4;
  yr[0] = __float2bfloat16(v.x * rs * wv.x);
  yr[1] = __float2bfloat16(v.y * rs * wv.y);
  yr[2] = __float2bfloat16(v.z * rs * wv.z);
  yr[3] = __float2bfloat16(v.w * rs * wv.w);
}

// ---------------- 256x256 16-wave MFMA GEMM, 4-buffer counted-vmcnt pipeline ----------------
// 1024 threads (4 waves/SIMD). Per-wave output 64x64 (acc[4][4]). 2 glds16/thread/tile.
// XCD-partitioned mapping: each XCD owns a 4-wide by band (A L2-resident), bx streams B.
// mode 10: col<3072 -> C0 ld 3072 raw, else C1 ld 1536 raw.
#define AS256(bi) (lds + (bi) * 8192)
#define BS256(bi) (lds + 32768 + (bi) * 8192)
#define STAGE256(bi, k0) do { \
    glds16(gA0 + (k0), AS256(bi) + w * 512); \
    glds16(gB0 + (k0), BS256(bi) + w * 512); \
  } while (0)

__global__ __launch_bounds__(1024) void gemm256(
    const bf16* __restrict__ A, const bf16* __restrict__ Bt,
    bf16* __restrict__ C0, bf16* __restrict__ C1,
    int gx, int N, int K, int mode) {
  __shared__ bf16 lds[65536];
  // XCD-partitioned: xcd owns by in [xcd*4, xcd*4+4), bx fastest within band
  int bid = blockIdx.x;
  int xcd = bid & 7, li = bid >> 3;         // li in [0, gx*4)
  int by = xcd * 4 + li / gx;
  int bx = li % gx;
  int bm = by * 256, bn = bx * 256;
  int tid = threadIdx.x;
  int lane = tid & 63, w = tid >> 6;        // w in 0..15
  int l15 = lane & 15, lq = lane >> 4;
  int wr = w >> 2, wc = w & 3;              // 4x4 wave grid, per-wave 64x64
  int arow0 = tid >> 2;                     // 0..255
  int srcq = (tid & 3) ^ ((arow0 >> 1) & 3);
  const bf16* gA0 = A + (size_t)(bm + arow0) * K + srcq * 8;
  const bf16* gB0 = Bt + (size_t)(bn + arow0) * K + srcq * 8;
  int slot = lq ^ ((l15 >> 1) & 3);         // frag-read swizzle (matches store)
  f32x4 acc[4][4];
#pragma unroll
  for (int m = 0; m < 4; m++)
#pragma unroll
    for (int n = 0; n < 4; n++) acc[m][n] = (f32x4){0.f, 0.f, 0.f, 0.f};
  int NT = K >> 5;
  STAGE256(0, 0);
  STAGE256(1, 32);
  STAGE256(2, 64);
  for (int t = 0; t < NT; ++t) {
    int b = t & 3;
    if (t <= NT - 3)      { asm volatile("s_waitcnt vmcnt(4)" ::: "memory"); }
    else if (t == NT - 2) { asm volatile("s_waitcnt vmcnt(2)" ::: "memory"); }
    else                  { asm volatile("s_waitcnt vmcnt(0)" ::: "memory"); }
    __builtin_amdgcn_s_barrier();
    bf16x8 af[4], bfr[4];
#pragma unroll
    for (int m = 0; m < 4; m++)
      af[m] = *(const bf16x8*)(AS256(b) + (wr * 64 + m * 16 + l15) * 32 + slot * 8);
#pragma unroll
    for (int n = 0; n < 4; n++)
      bfr[n] = *(const bf16x8*)(BS256(b) + (wc * 64 + n * 16 + l15) * 32 + slot * 8);
    __builtin_amdgcn_s_setprio(1);
#pragma unroll
    for (int m = 0; m < 4; m++)
#pragma unroll
      for (int n = 0; n < 4; n++)
        acc[m][n] = mfma16(af[m], bfr[n], acc[m][n]);
    __builtin_amdgcn_s_setprio(0);
    if (t + 3 < NT) STAGE256((t + 3) & 3, (t + 3) * 32);
  }
  // ---- epilogue: LDS-coalesced C write (XOR-swizzled) ----
  __syncthreads();
  bf16* dst; int ldc, bnl;
  if (bn < 3072) { dst = C0; ldc = 3072; bnl = bn; }
  else           { dst = C1; ldc = 1536; bnl = bn - 3072; }
  bf16* cw = lds + w * 4096;   // per-wave 64x64 region
#pragma unroll
  for (int m = 0; m < 4; m++)
#pragma unroll
    for (int n = 0; n < 4; n++)
#pragma unroll
      for (int i = 0; i < 4; i++) {
        int row_l = m * 16 + lq * 4 + i;
        int col_l = n * 16 + l15;
        cw[row_l * 64 + (col_l ^ ((row_l & 7) << 3))] = __float2bfloat16(acc[m][n][i]);
      }
  __syncthreads();
  int r8 = lane >> 3, cblk = lane & 7;
#pragma unroll
  for (int it = 0; it < 8; it++) {
    int row_l = it * 8 + r8;
    int sblk = cblk ^ (row_l & 7);
    bf16x8 val = *(const bf16x8*)&cw[row_l * 64 + sblk * 8];
    *(bf16x8*)&dst[(size_t)(bm + wr * 64 + row_l) * ldc + bnl + wc * 64 + cblk * 8] = val;
  }
}

// ---------------- fused MLP gate+up GEMM: act = silu(A@Wg) * (A@Wu) ----------------
// Grid 768 = 24 bx (128-col act panels) x 32 by (256-row panels), XCD-partitioned.
__global__ __launch_bounds__(1024) void gemm_mlp(
    const bf16* __restrict__ A, const bf16* __restrict__ Bt,
    bf16* __restrict__ C, int K) {
  __shared__ bf16 lds[65536];
  int bid = blockIdx.x;
  int xcd = bid & 7, li = bid >> 3;         // li in [0, 96)
  int by = xcd * 4 + li / 24;
  int bx = li % 24;
  int bm = by * 256, bn = bx * 128;
  int tid = threadIdx.x;
  int lane = tid & 63, w = tid >> 6;
  int l15 = lane & 15, lq = lane >> 4;
  int wr = w >> 2, wc = w & 3;              // per-wave 64 rows x 32 cols
  int r0 = tid >> 2;                        // 0..255
  int srcq = (tid & 3) ^ ((r0 >> 1) & 3);
  const bf16* gA0 = A + (size_t)(bm + r0) * K + srcq * 8;
  int growB = bn + (r0 & 127) + (r0 >> 7) * 3072;   // gate rows then up rows
  const bf16* gB0 = Bt + (size_t)growB * K + srcq * 8;
  int slot = lq ^ ((l15 >> 1) & 3);
  f32x4 accg[4][2], accu[4][2];
#pragma unroll
  for (int m = 0; m < 4; m++)
#pragma unroll
    for (int n = 0; n < 2; n++) {
      accg[m][n] = (f32x4){0.f, 0.f, 0.f, 0.f};
      accu[m][n] = (f32x4){0.f, 0.f, 0.f, 0.f};
    }
  int NT = K >> 5;
  STAGE256(0, 0);
  STAGE256(1, 32);
  STAGE256(2, 64);
  for (int t = 0; t < NT; ++t) {
    int b = t & 3;
    if (t <= NT - 3)      { asm volatile("s_waitcnt vmcnt(4)" ::: "memory"); }
    else if (t == NT - 2) { asm volatile("s_waitcnt vmcnt(2)" ::: "memory"); }
    else                  { asm volatile("s_waitcnt vmcnt(0)" ::: "memory"); }
    __builtin_amdgcn_s_barrier();
    bf16x8 af[4], bg[2], bu[2];
#pragma unroll
    for (int m = 0; m < 4; m++)
      af[m] = *(const bf16x8*)(AS256(b) + (wr * 64 + m * 16 + l15) * 32 + slot * 8);
#pragma unroll
    for (int n = 0; n < 2; n++) {
      bg[n] = *(const bf16x8*)(BS256(b) + (wc * 32 + n * 16 + l15) * 32 + slot * 8);
      bu[n] = *(const bf16x8*)(BS256(b) + (128 + wc * 32 + n * 16 + l15) * 32 + slot * 8);
    }
    __builtin_amdgcn_s_setprio(1);
#pragma unroll
    for (int m = 0; m < 4; m++)
#pragma unroll
      for (int n = 0; n < 2; n++) {
        accg[m][n] = mfma16(af[m], bg[n], accg[m][n]);
        accu[m][n] = mfma16(af[m], bu[n], accu[m][n]);
      }
    __builtin_amdgcn_s_setprio(0);
    if (t + 3 < NT) STAGE256((t + 3) & 3, (t + 3) * 32);
  }
  // ---- epilogue: act = silu(g)*u, LDS-coalesced ----
  __syncthreads();
  bf16* cw = lds + w * 2048;   // per-wave 64x32 region
#pragma unroll
  for (int m = 0; m < 4; m++)
#pragma unroll
    for (int n = 0; n < 2; n++)
#pragma unroll
      for (int i = 0; i < 4; i++) {
        int row_l = m * 16 + lq * 4 + i;
        int col_l = n * 16 + l15;
        float v = siluf(accg[m][n][i]) * accu[m][n][i];
        cw[row_l * 32 + (col_l ^ ((row_l & 3) << 3))] = __float2bfloat16(v);
      }
  __syncthreads();
  int r16 = lane >> 2, cblk = lane & 3;
#pragma unroll
  for (int it = 0; it < 4; it++) {   // 4 iters x 64 lanes x 8 bf16 = 2048 (full 64x32)
    int row_l = it * 16 + r16;
    int sblk = cblk ^ (row_l & 3);
    bf16x8 val = *(const bf16x8*)&cw[row_l * 32 + sblk * 8];
    *(bf16x8*)&C[(size_t)(bm + wr * 64 + row_l) * 3072 + bn + wc * 32 + cblk * 8] = val;
  }
}

// ---------------- 128x128 16-wave MFMA GEMM, 4-buffer counted-vmcnt pipeline ----------------
// 1D grid gx*gy, XCD-partitioned (gy%8==0): xcd owns gy/8 by rows, bx fastest.
// 1024 threads. Per-wave 32x32 (acc[2][2]). A staged by waves 0-7, B by waves 8-15.
// mode 0: fp32 out (+res). K>=96.
__global__ __launch_bounds__(1024) void gemm_mfma(
    const bf16* __restrict__ A, const bf16* __restrict__ Bt,
    void* __restrict__ Cv, const float* __restrict__ res,
    int N, int K, int ldc, int mode, int gx, int gy) {
  __shared__ bf16 As[4][4096];
  __shared__ bf16 Bs[4][4096];
  int bid = blockIdx.x;
  int xcd = bid & 7, li = bid >> 3;         // li in [0, gx*gy/8)
  int by = xcd * (gy >> 3) + li / gx;
  int bx = li % gx;
  int tid = threadIdx.x, lane = tid & 63, w = tid >> 6;   // w in 0..15
  int bm = by * 128, bn = bx * 128;
  int l15 = lane & 15, lq = lane >> 4;
  int wr = w >> 2, wc = w & 3;              // per-wave 32x32
  int r0 = (tid & 511) >> 2;                // 0..127
  int sq = (tid & 3) ^ ((r0 >> 1) & 3);
  const bf16* g0;
  bf16* lb;
  if (w < 8) {
    g0 = A + (size_t)(bm + r0) * K + sq * 8;
    lb = &As[0][w * 512];
  } else {
    int br = bn + r0; if (br >= N) br = 0;
    g0 = Bt + (size_t)br * K + sq * 8;
    lb = &Bs[0][(w - 8) * 512];
  }
#define STAGE128X(bi, k0) glds16(g0 + (k0), lb + (bi) * 4096)
  int slot = lq ^ ((l15 >> 1) & 3);
  f32x4 acc[2][2];
#pragma unroll
  for (int m = 0; m < 2; m++)
#pragma unroll
    for (int n = 0; n < 2; n++) acc[m][n] = (f32x4){0.f, 0.f, 0.f, 0.f};
  int NT = K >> 5;
  STAGE128X(0, 0);
  STAGE128X(1, 32);
  STAGE128X(2, 64);
  for (int t = 0; t < NT; ++t) {
    int b = t & 3;
    if (t <= NT - 3)      { asm volatile("s_waitcnt vmcnt(2)" ::: "memory"); }
    else if (t == NT - 2) { asm volatile("s_waitcnt vmcnt(1)" ::: "memory"); }
    else                  { asm volatile("s_waitcnt vmcnt(0)" ::: "memory"); }
    __builtin_amdgcn_s_barrier();
    bf16x8 af[2], bfr[2];
#pragma unroll
    for (int m = 0; m < 2; m++)
      af[m] = *(const bf16x8*)&As[b][(wr * 32 + m * 16 + l15) * 32 + slot * 8];
#pragma unroll
    for (int n = 0; n < 2; n++)
      bfr[n] = *(const bf16x8*)&Bs[b][(wc * 32 + n * 16 + l15) * 32 + slot * 8];
    __builtin_amdgcn_s_setprio(1);
#pragma unroll
    for (int m = 0; m < 2; m++)
#pragma unroll
      for (int n = 0; n < 2; n++)
        acc[m][n] = mfma16(af[m], bfr[n], acc[m][n]);
    __builtin_amdgcn_s_setprio(0);
    if (t + 3 < NT) STAGE128X((t + 3) & 3, (t + 3) * 32);
  }
#pragma unroll
  for (int m = 0; m < 2; m++) {
#pragma unroll
    for (int n = 0; n < 2; n++) {
      int col = bn + wc * 32 + n * 16 + l15;
      if (col >= N) continue;
#pragma unroll
      for (int i = 0; i < 4; i++) {
        int row = bm + wr * 32 + m * 16 + lq * 4 + i;
        float v = acc[m][n][i];
        size_t idx = (size_t)row * ldc + col;
        if (mode == 0) {
          if (res) v += res[idx];
          ((float*)Cv)[idx] = v;
        } else {
          ((bf16*)Cv)[idx] = __float2bfloat16(v);
        }
      }
    }
  }
}

// ---------------- Parallel causal conv (K=4) + silu ----------------
__global__ __launch_bounds__(256) void convsilu2_k(const bf16* __restrict__ in,
                                                   bf16* __restrict__ outp,
                                                   const float* __restrict__ wq,
                                                   const float* __restrict__ wk,
                                                   const float* __restrict__ wv) {
  int tx = threadIdx.x & 31;
  int ty = threadIdx.x >> 5;
  int c = (blockIdx.x * 32 + tx) * 8;
  int gt = blockIdx.y * 8 + ty;
  int b = gt >> 11, t = gt & (Tn - 1);
  const float* wsrc = (c < HDK) ? (wq + c * 4)
                     : (c < 2 * HDK) ? (wk + (c - HDK) * 4)
                                     : (wv + (c - 2 * HDK) * 4);
  float4 W[8];
#pragma unroll
  for (int j = 0; j < 8; j++) W[j] = ((const float4*)wsrc)[j];
  const bf16* base = in + (size_t)b * Tn * QKVC + c;
  bf16x8 r[4];
  bf16x8 zero = {0, 0, 0, 0, 0, 0, 0, 0};
#pragma unroll
  for (int j = 0; j < 4; j++) {
    int tt = t - 3 + j;
    r[j] = (tt >= 0) ? *(const bf16x8*)(base + (size_t)tt * QKVC) : zero;
  }
  bf16x8 o;
#pragma unroll
  for (int ch = 0; ch < 8; ch++) {
    float x0 = b2f(r[0][ch]), x1 = b2f(r[1][ch]), x2 = b2f(r[2][ch]), x3 = b2f(r[3][ch]);
    float y = x0 * W[ch].x + x1 * W[ch].y + x2 * W[ch].z + x3 * W[ch].w;
    o[ch] = f2b(siluf(y));
  }
  *(bf16x8*)(outp + (size_t)gt * QKVC + c) = o;
}

// ---------------- l2norm: thread-per-48-elem head row, vectorized ----------------
__global__ __launch_bounds__(256) void l2norm_k(bf16* __restrict__ qkv) {
  int row = blockIdx.x * 256 + threadIdx.x;   // 0 .. BT*32-1
  int t = row >> 5, hr = row & 31;
  bf16* p = qkv + (size_t)t * QKVC + hr * DKn;
  bf16x8 v[6];
  float ss = 0.f;
#pragma unroll
  for (int j = 0; j < 6; j++) {
    v[j] = *(const bf16x8*)(p + j * 8);
#pragma unroll
    for (int e = 0; e < 8; e++) { float f = b2f(v[j][e]); ss += f * f; }
  }
  float rs = rsqrtf(ss + 1e-6f);
#pragma unroll
  for (int j = 0; j < 6; j++) {
    bf16x8 o;
#pragma unroll
    for (int e = 0; e < 8; e++) o[e] = f2b(b2f(v[j][e]) * rs);
    *(bf16x8*)(p + j * 8) = o;
  }
}

// ---------------- beta/g transform ----------------
__global__ void betag_k(float* __restrict__ ba, const float* __restrict__ A_log,
                        const float* __restrict__ dt_bias) {
  int i = blockIdx.x * blockDim.x + threadIdx.x;
  int h = i & 15, r = i >> 4;
  float bv = ba[(size_t)r * 32 + h];
  float av = ba[(size_t)r * 32 + 16 + h];
  ba[(size_t)r * 32 + h] = sigmoidf_(bv);
  float xx = av + dt_bias[h];
  float sp = (xx > 20.f) ? xx : log1pf(__expf(xx));
  ba[(size_t)r * 32 + 16 + h] = -__expf(A_log[h]) * sp;
}

// ---------------- Fused P1+P2a: WY precompute + affine coefficients ----------------
__global__ __launch_bounds__(256) void dn_p1a(const bf16* __restrict__ qkv,
                                              const float* __restrict__ ba,
                                              float* __restrict__ Gc_g,
                                              bf16* __restrict__ T_g,
                                              bf16* __restrict__ Uv_g,
                                              bf16* __restrict__ A_g,
                                              bf16* __restrict__ B_g) {
  __shared__ __align__(16) char smem[62976];
  bf16 (*Kl)[72]   = (bf16(*)[72])(smem);                 //  9216 B
  bf16 (*Tl)[72]   = (bf16(*)[72])(smem + 9216);          //  9216 B
  bf16 (*UvdT)[72] = (bf16(*)[72])(smem + 18432);         // 13824 B
  float* Gcl = (float*)(smem + 32256);
  float* Bl  = (float*)(smem + 32512);
  bf16 (*Vl)[100]  = (bf16(*)[100])(smem + 32768);
  float (*Nl)[68]  = (float(*)[68])(smem + 45568);
  bf16 (*KTl)[72]  = (bf16(*)[72])(smem + 32768);
  bf16 (*KTbl)[72] = (bf16(*)[72])(smem + 39680);
  bf16 (*M2T)[72]  = (bf16(*)[72])(smem + 46592);
  int cid = blockIdx.x;
  int nc = cid & (NC - 1);
  int bh = cid >> 5;
  int h = bh & 15, b = bh >> 4;
  int t0 = nc * CC;
  int tid = threadIdx.x, lane = tid & 63, w = tid >> 6;
  int l15 = lane & 15, qd = lane >> 4;
  bf16 zb = __float2bfloat16(0.f);
  {
    int t = tid >> 2, p = tid & 3;
    const bf16* row = qkv + ((size_t)(b * Tn + t0 + t)) * QKVC;
    int c0 = p * 12;
#pragma unroll
    for (int j = 0; j < 12; ++j) Kl[t][c0 + j] = row[HDK + h * DKn + c0 + j];
    int j0 = p * 24;
#pragma unroll
    for (int j = 0; j < 24; ++j) Vl[t][j0 + j] = row[2 * HDK + h * DVn + j0 + j];
  }
  for (int i = tid; i < 64 * 24; i += 256) {
    int t = i / 24, c = 48 + (i % 24);
    Kl[t][c] = zb;
  }
  if (tid < 64) {
    size_t row = (size_t)(b * Tn + t0 + tid);
    float g = ba[row * 32 + 16 + h];
    float be = ba[row * 32 + h];
    float acc = g;
#pragma unroll
    for (int d = 1; d < 64; d <<= 1) {
      float o = __shfl_up(acc, d);
      if (tid >= d) acc += o;
    }
    Gcl[tid] = acc; Bl[tid] = be;
    Gc_g[(size_t)bh * Tn + t0 + tid] = acc;
  }
  __syncthreads();
  f32x4 dacc[4];
#pragma unroll
  for (int n = 0; n < 4; n++) dacc[n] = (f32x4){0.f, 0.f, 0.f, 0.f};
  {
    int arow = w * 16 + l15;
    bf16x8 a0 = *(const bf16x8*)&Kl[arow][qd * 8];
    bf16x8 a1 = *(const bf16x8*)&Kl[arow][32 + qd * 8];
#pragma unroll
    for (int n = 0; n < 4; n++) {
      int brow = n * 16 + l15;
      bf16x8 b0 = *(const bf16x8*)&Kl[brow][qd * 8];
      bf16x8 b1 = *(const bf16x8*)&Kl[brow][32 + qd * 8];
      dacc[n] = mfma16(a0, b0, dacc[n]);
      dacc[n] = mfma16(a1, b1, dacc[n]);
    }
  }
#pragma unroll
  for (int i = 0; i < 4; i++) {
    int t = w * 16 + qd * 4 + i;
    float bt = Bl[t], gt = Gcl[t];
#pragma unroll
    for (int n = 0; n < 4; n++) {
      int s = n * 16 + l15;
      Nl[t][s] = (s < t) ? bt * __expf(gt - Gcl[s]) * dacc[n][i] : 0.f;
    }
  }
  __syncthreads();
  float g63 = Gcl[63];
  int c = tid;
  if (c < 160) {
    float R[64];
    if (c < 64) {
#pragma unroll
      for (int t = 0; t < 64; ++t) R[t] = (t == c) ? 1.f : 0.f;
    } else {
      int j = c - 64;
#pragma unroll
      for (int t = 0; t < 64; ++t) R[t] = Bl[t] * __bfloat162float(Vl[t][j]);
    }
#pragma unroll
    for (int t = 1; t < 64; ++t) {
      float a0 = 0.f, a1 = 0.f, a2 = 0.f, a3 = 0.f;
#pragma unroll
      for (int s = 0; s + 3 < t; s += 4) {
        float4 n4 = *(const float4*)&Nl[t][s];
        a0 += n4.x * R[s]; a1 += n4.y * R[s + 1];
        a2 += n4.z * R[s + 2]; a3 += n4.w * R[s + 3];
      }
#pragma unroll
      for (int s = t & ~3; s < t; ++s) a0 += Nl[t][s] * R[s];
      R[t] -= ((a0 + a1) + (a2 + a3));
    }
    if (c < 64) {
#pragma unroll
      for (int t = 0; t < 64; ++t) {
        bf16 v = __float2bfloat16(R[t]);
        T_g[(size_t)cid * 4096 + t * 64 + c] = v;
        Tl[t][c] = v;
      }
    } else {
      int j = c - 64;
#pragma unroll
      for (int t = 0; t < 64; ++t) {
        Uv_g[(size_t)cid * 6144 + t * 96 + j] = __float2bfloat16(R[t]);
        UvdT[j][t] = __float2bfloat16(R[t] * __expf(g63 - Gcl[t]));
      }
    }
  }
  __syncthreads();
  for (int i = tid; i < 48 * 64; i += 256) {
    int dk = i >> 6, t = i & 63;
    bf16 kv = Kl[t][dk];
    KTl[dk][t] = kv;
    float bl = Bl[t] * __expf(Gcl[t]);
    KTbl[dk][t] = __float2bfloat16(__bfloat162float(kv) * bl);
  }
  __syncthreads();
  f32x4 m1[3];
#pragma unroll
  for (int n = 0; n < 3; n++) m1[n] = (f32x4){0.f, 0.f, 0.f, 0.f};
  {
    int arow = w * 16 + l15;
    bf16x8 a0 = *(const bf16x8*)&Tl[arow][qd * 8];
    bf16x8 a1 = *(const bf16x8*)&Tl[arow][32 + qd * 8];
#pragma unroll
    for (int n = 0; n < 3; n++) {
      int brow = n * 16 + l15;
      bf16x8 b0 = *(const bf16x8*)&KTbl[brow][qd * 8];
      bf16x8 b1 = *(const bf16x8*)&KTbl[brow][32 + qd * 8];
      m1[n] = mfma16(a0, b0, m1[n]);
      m1[n] = mfma16(a1, b1, m1[n]);
    }
  }
#pragma unroll
  for (int i = 0; i < 4; i++) {
    int tt = w * 16 + qd * 4 + i;
    float dd = __expf(g63 - Gcl[tt]);
#pragma unroll
    for (int n = 0; n < 3; n++) {
      int dk = n * 16 + l15;
      M2T[dk][tt] = __float2bfloat16(m1[n][i] * dd);
    }
  }
  __syncthreads();
  float lamC = __expf(g63);
#pragma unroll
  for (int tswap = 0; tswap < 7; tswap++) {
    int t = w + 4 * tswap;
    if (t >= 27) break;
    int mi, ni; bool isA;
    if (t < 9) { isA = true; mi = t / 3; ni = t % 3; }
    else { isA = false; mi = (t - 9) / 6; ni = (t - 9) % 6; }
    f32x4 acc = (f32x4){0.f, 0.f, 0.f, 0.f};
    int arow = mi * 16 + l15;
    bf16x8 a0 = *(const bf16x8*)&KTl[arow][qd * 8];
    bf16x8 a1 = *(const bf16x8*)&KTl[arow][32 + qd * 8];
    int brow = ni * 16 + l15;
    if (isA) {
      bf16x8 b0 = *(const bf16x8*)&M2T[brow][qd * 8];
      bf16x8 b1 = *(const bf16x8*)&M2T[brow][32 + qd * 8];
      acc = mfma16(a0, b0, acc);
      acc = mfma16(a1, b1, acc);
#pragma unroll
      for (int i = 0; i < 4; i++) {
        int row = mi * 16 + qd * 4 + i, colv = ni * 16 + l15;
        float v = ((row == colv) ? lamC : 0.f) - acc[i];
        A_g[(size_t)cid * 2304 + row * 48 + colv] = __float2bfloat16(v);
      }
    } else {
      bf16x8 b0 = *(const bf16x8*)&UvdT[brow][qd * 8];
      bf16x8 b1 = *(const bf16x8*)&UvdT[brow][32 + qd * 8];
      acc = mfma16(a0, b0, acc);
      acc = mfma16(a1, b1, acc);
#pragma unroll
      for (int i = 0; i < 4; i++) {
        int row = mi * 16 + qd * 4 + i, colv = ni * 16 + l15;
        B_g[(size_t)cid * 4608 + row * 96 + colv] = __float2bfloat16(acc[i]);
      }
    }
  }
}

// ---------------- P2b: pipelined serial affine scan S' = A S + B ----------------
__global__ __launch_bounds__(256) void dn_p2b(const bf16* __restrict__ A_g,
                                              const bf16* __restrict__ B_g,
                                              bf16* __restrict__ St_g) {
  __shared__ bf16 STl[2][96][72];
  __shared__ bf16 Al[2][48][72];
  __shared__ bf16 Bl[2][4608];
  int bh = blockIdx.x;
  int tid = threadIdx.x, lane = tid & 63, w = tid >> 6;
  int l15 = lane & 15, qd = lane >> 4;
  bf16 zb = __float2bfloat16(0.f);
  for (int i = tid; i < 2 * 96 * 72; i += 256) (&STl[0][0][0])[i] = zb;
  for (int i = tid; i < 2 * 48 * 24; i += 256) {
    int buf = i / (48 * 24), r = (i / 24) % 48, cc = 48 + (i % 24);
    Al[buf][r][cc] = zb;
  }
  bf16x8 ra0, ra1, rb0, rb1;
  unsigned int rb2;
  int e_a0 = tid * 8, e_a1 = 2048 + tid * 8;
  {
    size_t cid = (size_t)bh * NC;
    ra0 = *(const bf16x8*)(A_g + cid * 2304 + e_a0);
    if (tid < 32) ra1 = *(const bf16x8*)(A_g + cid * 2304 + e_a1);
    rb0 = *(const bf16x8*)(B_g + cid * 4608 + tid * 16);
    rb1 = *(const bf16x8*)(B_g + cid * 4608 + tid * 16 + 8);
    rb2 = *(const unsigned int*)(B_g + cid * 4608 + 4096 + tid * 2);
  }
  *(bf16x8*)&Al[0][e_a0 / 48][e_a0 % 48] = ra0;
  if (tid < 32) *(bf16x8*)&Al[0][e_a1 / 48][e_a1 % 48] = ra1;
  *(bf16x8*)&Bl[0][tid * 16] = rb0;
  *(bf16x8*)&Bl[0][tid * 16 + 8] = rb1;
  *(unsigned int*)&Bl[0][4096 + tid * 2] = rb2;
  {
    size_t cid = (size_t)bh * NC + 1;
    ra0 = *(const bf16x8*)(A_g + cid * 2304 + e_a0);
    if (tid < 32) ra1 = *(const bf16x8*)(A_g + cid * 2304 + e_a1);
    rb0 = *(const bf16x8*)(B_g + cid * 4608 + tid * 16);
    rb1 = *(const bf16x8*)(B_g + cid * 4608 + tid * 16 + 8);
    rb2 = *(const unsigned int*)(B_g + cid * 4608 + 4096 + tid * 2);
  }
  __syncthreads();

  for (int c = 0; c < NC - 1; ++c) {
    int cur = c & 1, nxt = cur ^ 1;
    size_t cid = (size_t)bh * NC + c;
    {
      int e0 = tid * 8, e1 = 2048 + tid * 8, e2 = 4096 + tid * 2;
      *(bf16x8*)(St_g + cid * 4608 + e0) = *(const bf16x8*)&STl[cur][e0 / 48][e0 % 48];
      *(bf16x8*)(St_g + cid * 4608 + e1) = *(const bf16x8*)&STl[cur][e1 / 48][e1 % 48];
      *(unsigned int*)(St_g + cid * 4608 + e2) = *(const unsigned int*)&STl[cur][e2 / 48][e2 % 48];
    }
    float vals[5][4];
#pragma unroll
    for (int ts = 0; ts < 5; ts++) {
      int t = w + 4 * ts;
      if (t >= 18) break;
      int mi = t / 3, ni = t % 3;
      f32x4 acc = (f32x4){0.f, 0.f, 0.f, 0.f};
      int arow = mi * 16 + l15;
      bf16x8 a0 = *(const bf16x8*)&STl[cur][arow][qd * 8];
      bf16x8 a1 = *(const bf16x8*)&STl[cur][arow][32 + qd * 8];
      int brow = ni * 16 + l15;
      bf16x8 b0 = *(const bf16x8*)&Al[cur][brow][qd * 8];
      bf16x8 b1 = *(const bf16x8*)&Al[cur][brow][32 + qd * 8];
      acc = mfma16(a0, b0, acc);
      acc = mfma16(a1, b1, acc);
#pragma unroll
      for (int i = 0; i < 4; i++) {
        int dv = mi * 16 + qd * 4 + i, ii = ni * 16 + l15;
        vals[ts][i] = acc[i] + __bfloat162float(Bl[cur][ii * 96 + dv]);
      }
    }
#pragma unroll
    for (int ts = 0; ts < 5; ts++) {
      int t = w + 4 * ts;
      if (t >= 18) break;
      int mi = t / 3, ni = t % 3;
#pragma unroll
      for (int i = 0; i < 4; i++) {
        int dv = mi * 16 + qd * 4 + i, ii = ni * 16 + l15;
        STl[nxt][dv][ii] = __float2bfloat16(vals[ts][i]);
      }
    }
    if (c + 1 <= NC - 2) {
      *(bf16x8*)&Al[nxt][e_a0 / 48][e_a0 % 48] = ra0;
      if (tid < 32) *(bf16x8*)&Al[nxt][e_a1 / 48][e_a1 % 48] = ra1;
      *(bf16x8*)&Bl[nxt][tid * 16] = rb0;
      *(bf16x8*)&Bl[nxt][tid * 16 + 8] = rb1;
      *(unsigned int*)&Bl[nxt][4096 + tid * 2] = rb2;
      if (c + 2 <= NC - 2) {
        size_t cid2 = (size_t)bh * NC + c + 2;
        ra0 = *(const bf16x8*)(A_g + cid2 * 2304 + e_a0);
        if (tid < 32) ra1 = *(const bf16x8*)(A_g + cid2 * 2304 + e_a1);
        rb0 = *(const bf16x8*)(B_g + cid2 * 4608 + tid * 16);
        rb1 = *(const bf16x8*)(B_g + cid2 * 4608 + tid * 16 + 8);
        rb2 = *(const unsigned int*)(B_g + cid2 * 4608 + 4096 + tid * 2);
      }
    }
    __syncthreads();
  }
  {
    size_t cid = (size_t)bh * NC + (NC - 1);
    int cur = (NC - 1) & 1;
    int e0 = tid * 8, e1 = 2048 + tid * 8, e2 = 4096 + tid * 2;
    *(bf16x8*)(St_g + cid * 4608 + e0) = *(const bf16x8*)&STl[cur][e0 / 48][e0 % 48];
    *(bf16x8*)(St_g + cid * 4608 + e1) = *(const bf16x8*)&STl[cur][e1 / 48][e1 % 48];
    *(unsigned int*)(St_g + cid * 4608 + e2) = *(const unsigned int*)&STl[cur][e2 / 48][e2 % 48];
  }
}

// ---------------- P2c: per-chunk output + fused gated RMSNorm ----------------
__global__ __launch_bounds__(256) void dn_p2c(const bf16* __restrict__ qkv,
                                              const float* __restrict__ ba,
                                              const float* __restrict__ Gc_g,
                                              const bf16* __restrict__ T_g,
                                              const bf16* __restrict__ Uv_g,
                                              const bf16* __restrict__ St_g,
                                              const bf16* __restrict__ gate,
                                              const float* __restrict__ onw,
                                              bf16* __restrict__ attn) {
  __shared__ bf16 Kl[64][72], Ql[64][72], Tl[64][72], Ml[64][72];
  __shared__ bf16 G1T[96][72], UT[96][72], STb[96][72];
  __shared__ float Gcl[64], Bl[64];
  __shared__ float onwl[96];
  int cid = blockIdx.x;
  int nc = cid & (NC - 1);
  int bh = cid >> 5;
  int h = bh & 15, b = bh >> 4;
  int t0 = nc * CC;
  int tid = threadIdx.x, lane = tid & 63, w = tid >> 6;
  int l15 = lane & 15, qd = lane >> 4;
  const float scale = 0.14433756729740643f;  // 48^-0.5
  bf16 zb = __float2bfloat16(0.f);
  {
    int t = tid >> 2, p = tid & 3;
    size_t grow = (size_t)(b * Tn + t0 + t);
    const bf16* row = qkv + grow * QKVC;
    int c0 = p * 12;
#pragma unroll
    for (int j = 0; j < 12; ++j) {
      int cc = c0 + j;
      Kl[t][cc] = row[HDK + h * DKn + cc];
      Ql[t][cc] = __float2bfloat16(__bfloat162float(row[h * DKn + cc]) * scale);
    }
    if (p == 0) { Gcl[t] = Gc_g[(size_t)bh * Tn + t0 + t]; Bl[t] = ba[grow * 32 + h]; }
  }
  if (tid < 96) onwl[tid] = onw[tid];
  for (int i = tid; i < 64 * 16; i += 256) {
    int t = i >> 4, cc = 48 + (i & 15);
    Kl[t][cc] = zb; Ql[t][cc] = zb;
  }
  for (int i = tid; i < 4096; i += 256)
    (&Tl[0][0])[(i >> 6) * 72 + (i & 63)] = T_g[(size_t)cid * 4096 + i];
  for (int i = tid; i < 4608; i += 256)
    STb[i / 48][i % 48] = St_g[(size_t)cid * 4608 + i];
  for (int i = tid; i < 96 * 16; i += 256)
    STb[i >> 4][48 + (i & 15)] = zb;
  __syncthreads();  // sync1
  f32x4 acc[6];
#pragma unroll
  for (int n = 0; n < 6; n++) acc[n] = (f32x4){0.f, 0.f, 0.f, 0.f};
  {
    int arow = w * 16 + l15;
    bf16x8 a0 = *(const bf16x8*)&Kl[arow][qd * 8];
    bf16x8 a1 = *(const bf16x8*)&Kl[arow][32 + qd * 8];
#pragma unroll
    for (int n = 0; n < 6; n++) {
      int brow = n * 16 + l15;
      bf16x8 b0 = *(const bf16x8*)&STb[brow][qd * 8];
      bf16x8 b1 = *(const bf16x8*)&STb[brow][32 + qd * 8];
      acc[n] = mfma16(a0, b0, acc[n]);
      acc[n] = mfma16(a1, b1, acc[n]);
    }
  }
#pragma unroll
  for (int i = 0; i < 4; i++) {
    int tt = w * 16 + qd * 4 + i;
    float sc = Bl[tt] * __expf(Gcl[tt]);
#pragma unroll
    for (int n = 0; n < 6; n++)
      G1T[n * 16 + l15][tt] = __float2bfloat16(acc[n][i] * sc);
  }
  __syncthreads();  // sync2
#pragma unroll
  for (int n = 0; n < 6; n++) acc[n] = (f32x4){0.f, 0.f, 0.f, 0.f};
  {
    int arow = w * 16 + l15;
    bf16x8 a0 = *(const bf16x8*)&Tl[arow][qd * 8];
    bf16x8 a1 = *(const bf16x8*)&Tl[arow][32 + qd * 8];
#pragma unroll
    for (int n = 0; n < 6; n++) {
      int brow = n * 16 + l15;
      bf16x8 b0 = *(const bf16x8*)&G1T[brow][qd * 8];
      bf16x8 b1 = *(const bf16x8*)&G1T[brow][32 + qd * 8];
      acc[n] = mfma16(a0, b0, acc[n]);
      acc[n] = mfma16(a1, b1, acc[n]);
    }
  }
#pragma unroll
  for (int i = 0; i < 4; i++) {
    int tt = w * 16 + qd * 4 + i;
#pragma unroll
    for (int n = 0; n < 6; n++) {
      int dv = n * 16 + l15;
      float uv = __bfloat162float(Uv_g[(size_t)cid * 6144 + tt * 96 + dv]);
      UT[dv][tt] = __float2bfloat16(uv - acc[n][i]);
    }
  }
  f32x4 qk[4];
#pragma unroll
  for (int n = 0; n < 4; n++) qk[n] = (f32x4){0.f, 0.f, 0.f, 0.f};
  {
    int arow = w * 16 + l15;
    bf16x8 a0 = *(const bf16x8*)&Ql[arow][qd * 8];
    bf16x8 a1 = *(const bf16x8*)&Ql[arow][32 + qd * 8];
#pragma unroll
    for (int n = 0; n < 4; n++) {
      int brow = n * 16 + l15;
      bf16x8 b0 = *(const bf16x8*)&Kl[brow][qd * 8];
      bf16x8 b1 = *(const bf16x8*)&Kl[brow][32 + qd * 8];
      qk[n] = mfma16(a0, b0, qk[n]);
      qk[n] = mfma16(a1, b1, qk[n]);
    }
  }
#pragma unroll
  for (int i = 0; i < 4; i++) {
    int tt = w * 16 + qd * 4 + i;
    float gt = Gcl[tt];
#pragma unroll
    for (int n = 0; n < 4; n++) {
      int ss = n * 16 + l15;
      float m = (ss <= tt) ? qk[n][i] * __expf(gt - Gcl[ss]) : 0.f;
      Ml[tt][ss] = __float2bfloat16(m);
    }
  }
  __syncthreads();  // sync3
#pragma unroll
  for (int n = 0; n < 6; n++) acc[n] = (f32x4){0.f, 0.f, 0.f, 0.f};
  {
    int arow = w * 16 + l15;
    float lam = __expf(Gcl[arow]);
    bf16x8 a0 = scale8(*(const bf16x8*)&Ql[arow][qd * 8], lam);
    bf16x8 a1 = scale8(*(const bf16x8*)&Ql[arow][32 + qd * 8], lam);
    bf16x8 m0 = *(const bf16x8*)&Ml[arow][qd * 8];
    bf16x8 m1 = *(const bf16x8*)&Ml[arow][32 + qd * 8];
#pragma unroll
    for (int n = 0; n < 6; n++) {
      int brow = n * 16 + l15;
      bf16x8 b0 = *(const bf16x8*)&STb[brow][qd * 8];
      bf16x8 b1 = *(const bf16x8*)&STb[brow][32 + qd * 8];
      acc[n] = mfma16(a0, b0, acc[n]);
      acc[n] = mfma16(a1, b1, acc[n]);
      bf16x8 u0 = *(const bf16x8*)&UT[brow][qd * 8];
      bf16x8 u1 = *(const bf16x8*)&UT[brow][32 + qd * 8];
      acc[n] = mfma16(m0, u0, acc[n]);
      acc[n] = mfma16(m1, u1, acc[n]);
    }
  }
  // fused gated RMSNorm: row stats via 16-lane shfl reduce, then write attn
#pragma unroll
  for (int i = 0; i < 4; i++) {
    int tt = w * 16 + qd * 4 + i;
    float ss = 0.f;
#pragma unroll
    for (int n = 0; n < 6; n++) ss += acc[n][i] * acc[n][i];
    ss += __shfl_xor(ss, 1, 64);
    ss += __shfl_xor(ss, 2, 64);
    ss += __shfl_xor(ss, 4, 64);
    ss += __shfl_xor(ss, 8, 64);
    float rs = rsqrtf(ss * (1.f / DVn) + 1e-5f);
    size_t orow = ((size_t)(b * Tn + t0 + tt)) * HDV + h * DVn;
#pragma unroll
    for (int n = 0; n < 6; n++) {
      int dv = n * 16 + l15;
      float g = __bfloat162float(gate[orow + dv]);
      attn[orow + dv] = __float2bfloat16(acc[n][i] * rs * onwl[dv] * siluf(g));
    }
  }
}

extern "C" void kernel_launch(void* const* d_in, const int* in_sizes, int n_in,
                              void* d_out, int out_size, void* d_ws, size_t ws_size,
                              hipStream_t stream) {
  const float* x       = (const float*)d_in[0];
  const float* norm1_w = (const float*)d_in[1];
  const float* q_w     = (const float*)d_in[2];
  const float* k_w     = (const float*)d_in[3];
  const float* v_w     = (const float*)d_in[4];
  const float* cq_w    = (const float*)d_in[5];
  const float* ck_w    = (const float*)d_in[6];
  const float* cv_w    = (const float*)d_in[7];
  const float* b_w     = (const float*)d_in[8];
  const float* a_w     = (const float*)d_in[9];
  const float* A_log   = (const float*)d_in[10];
  const float* dt_bias = (const float*)d_in[11];
  const float* g_w     = (const float*)d_in[12];
  const float* o_norm_w= (const float*)d_in[13];
  const float* o_w     = (const float*)d_in[14];
  const float* norm2_w = (const float*)d_in[15];
  const float* gate_w  = (const float*)d_in[16];
  const float* up_w    = (const float*)d_in[17];
  const float* down_w  = (const float*)d_in[18];
  char* wsb = (char*)d_ws;
  float* out = (float*)d_out;

  bf16*  hbf   = (bf16*)(wsb + WO_HBF);
  bf16*  qkvr  = (bf16*)(wsb + WO_QKVR);
  bf16*  qkvc  = (bf16*)(wsb + WO_QKVC);
  bf16*  attn  = (bf16*)(wsb + WO_OSC);    // attn in old osc slot (no St overlap)
  bf16*  actb  = (bf16*)(wsb + WO_ACT);
  bf16*  gateb = (bf16*)(wsb + WO_GATE);
  float* x1    = (float*)(wsb + WO_X1);
  float* ba    = (float*)(wsb + WO_BA);
  float* Gc    = (float*)(wsb + WO_GC);
  bf16*  Tg    = (bf16*)(wsb + WO_T);
  bf16*  Uvg   = (bf16*)(wsb + WO_UV);
  bf16*  A_g   = (bf16*)(wsb + WO_A);
  bf16*  B_g   = (bf16*)(wsb + WO_B);
  bf16*  St_g  = (bf16*)(wsb + WO_ST);
  bf16*  wb    = (bf16*)(wsb + WO_WB);

  // 0. merged transpose-cast of all 10 weights (one launch)
  {
    TcastArgs ta;
    const float* srcs[10] = {q_w, k_w, v_w, g_w, o_w, gate_w, up_w, down_w, b_w, a_w};
    bf16* dsts[10] = {wb + WB_QKVT, wb + WB_QKVT + 768 * 1024, wb + WB_QKVT + 1536 * 1024,
                      wb + WB_GT, wb + WB_OT, wb + WB_GATET, wb + WB_UPT, wb + WB_DOWNT,
                      wb + WB_ABT, wb + WB_ABT + 16 * 1024};
    int Rs[10] = {1024, 1024, 1024, 1024, 1536, 1024, 1024, 3072, 1024, 1024};
    int Cs[10] = {768, 768, 1536, 1536, 1024, 3072, 3072, 1024, 16, 16};
    int off = 0;
    for (int i = 0; i < 10; i++) {
      ta.src[i] = srcs[i]; ta.dst[i] = dsts[i];
      ta.R[i] = Rs[i]; ta.C[i] = Cs[i];
      ta.gxw[i] = (Cs[i] + 31) / 32;
      ta.t0[i] = off;
      off += ta.gxw[i] * (Rs[i] / 32);
    }
    tcast_all<<<off, dim3(32, 8), 0, stream>>>(ta);
  }

  // 1. h_bf = rmsnorm(x)
  rmsnorm_bf_k<<<BT, 256, 0, stream>>>(x, norm1_w, hbf);
  // 2. fused qkv+gate projection; ba on small kernel
  gemm256<<<576, 1024, 0, stream>>>(hbf, wb + WB_QKVT, qkvr, gateb, 18, 4608, 1024, 10);
  gemm_mfma<<<64, 1024, 0, stream>>>(hbf, wb + WB_ABT, ba, nullptr, 32, 1024, 32, 0, 1, 64);
  // 3. conv+silu, l2norm, beta/g
  convsilu2_k<<<dim3(QKVC / 256, BT / 8), 256, 0, stream>>>(qkvr, qkvc, cq_w, ck_w, cv_w);
  l2norm_k<<<(BT * 32) / 256, 256, 0, stream>>>(qkvc);
  betag_k<<<(BT * Hn) / 256, 256, 0, stream>>>(ba, A_log, dt_bias);
  // 4. chunked gated delta rule (fused WY+affine -> scan -> fused output+gatednorm)
  dn_p1a<<<Bn * Hn * NC, 256, 0, stream>>>(qkvc, ba, Gc, Tg, Uvg, A_g, B_g);
  dn_p2b<<<Bn * Hn, 256, 0, stream>>>(A_g, B_g, St_g);
  dn_p2c<<<Bn * Hn * NC, 256, 0, stream>>>(qkvc, ba, Gc, Tg, Uvg, St_g, gateb, o_norm_w, attn);
  // 5. x1 = x + attn @ o_w
  gemm_mfma<<<512, 1024, 0, stream>>>(attn, wb + WB_OT, x1, x, 1024, 1536, 1024, 0, 8, 64);
  // 6. h2 = rmsnorm(x1)
  rmsnorm_bf_k<<<BT, 256, 0, stream>>>(x1, norm2_w, hbf);
  // 7. fused MLP: act = silu(h2@gate_w) * (h2@up_w)
  gemm_mlp<<<768, 1024, 0, stream>>>(hbf, wb + WB_GATET, actb, 1024);
  // 8. out = x1 + act @ down_w
  gemm_mfma<<<512, 1024, 0, stream>>>(actb, wb + WB_DOWNT, out, x1, 1024, 3072, 1024, 0, 8, 64);
}